// Round 9
// baseline (616.897 us; speedup 1.0000x reference)
//
#include <hip/hip_runtime.h>
#include <hip/hip_bf16.h>

// Round 21: (a) quantm revert to r18-exact (4-wave granularity refuted:
// 68us vs r18's 59us — same 16 waves/CU, 2x per-block fixed costs). (b)
// MFMA hout: the two K=1024 gather-GEMMs feed ONLY `out` (6.6e-4 absmax)
// -> bf16 hi/lo 3-MFMA split (err ~1e-7) is safe with NO cert machinery.
// houtm_rw: 256thr/4-wave blocks, 32px x 64out x K=256 (z-split 4, grid
// 128x2x4); zq gathered straight from the precomputed cbhl hi/lo table
// into LDS shorts (no conversion); W-frag split on the fly (8 scalar
// loads, L2-hot); 6 MFMA/wave/chunk; f32 atomicAdd raw partials into
// zeroed R2/R3 (interface identical to the scalar path it replaces).
// conv_in / z-gemms stay scalar (their perturbations would reach the
// argmin). Everything else identical to r18 (passed, 535us).
// Outputs (f32): out[1048576] | loss[1] | zq_p[4194304].

typedef float f32x4  __attribute__((ext_vector_type(4)));
typedef short bf16x8 __attribute__((ext_vector_type(8)));

__device__ __forceinline__ float silu_rw(float x){ return x / (1.f + expf(-x)); }
__device__ __forceinline__ float b2f_rw(__hip_bfloat16 v){ return __bfloat162float(v); }
__device__ __forceinline__ float ldv_rw(const void* p, int i, int f32m){
  if (f32m) return ((const float*)p)[i];
  return b2f_rw(((const __hip_bfloat16*)p)[i]);
}
__device__ __forceinline__ unsigned short f2bf_rw(float x){   // f32 -> bf16 RNE
  unsigned u = __float_as_uint(x);
  unsigned r = ((u >> 16) & 1u) + 0x7FFFu;
  return (unsigned short)((u + r) >> 16);
}
__device__ __forceinline__ float bf2f_rw(unsigned short h){
  return __uint_as_float(((unsigned)h) << 16);
}

// ---------------- workspace layout (float offsets) ----------------
#define FLAGS_OFF 0
#define LOSS_OFF  4
#define STATS_OFF 8
#define CNT_OFF   72         // 8 ints: fallback counters per chunk
#define CMAX_OFF  80         // max_j |c_j| (f32)
#define CB32_OFF  128        // 1024x32 f32
#define CBN_OFF   32896      // 1024
#define IDXP_OFF  33984      // 131072 int
#define IDXN_OFF  165056     // 131072 int
#define CBHL_OFF  296192     // interleaved hi/lo bf16 table (32768 f32 slots)
#define LIST_OFF  328960     // 131072 int (uncertain list, reused per chunk)
#define R2_OFF    460032     // lnp -> hcat_p accum (524288)
#define R3_OFF    984320     // lnn -> hcat_n accum (524288)
#define R1_OFF    1508608    // h (1048576) / z chunks (CS*262144)

// ---------------- input dtype probe + zero accumulators ----------------
__global__ __launch_bounds__(256) void detect_rw(const void* cbv, float* wsb){
  __shared__ int bad;
  if (threadIdx.x == 0) bad = 0;
  __syncthreads();
  const unsigned short* u = (const unsigned short*)cbv;
  int local = 0;
  for (int i = threadIdx.x; i < 32768; i += 256){
    unsigned e = (u[i] >> 7) & 0xFF;
    if (e >= 126) local = 1;
  }
  if (local) bad = 1;
  __syncthreads();
  if (threadIdx.x == 0){
    wsb[FLAGS_OFF] = bad ? 1.f : 0.f;   // 1.0 => inputs are f32
    wsb[LOSS_OFF] = 0.f; wsb[LOSS_OFF + 1] = 0.f;
    int* c = (int*)(wsb + CNT_OFF);
    #pragma unroll
    for (int k = 0; k < 8; ++k) c[k] = 0;
    wsb[CMAX_OFF] = 0.f;
  }
}

// ------ codebook -> f32 + |c|^2 + interleaved bf16 hi/lo tile table ------
// Tile T = j>>4 occupies shorts [T*1024, T*1024+1024): hi of code j elem e
// at T*1024 + (j&15)*32 + e, lo at +512.
__global__ __launch_bounds__(256) void cbprep_rw(const void* cbv, const float* flags,
                                                 float* cb32, float* cbn,
                                                 short* cbhl, float* cmaxp){
  const int f32m = (flags[0] != 0.f);
  int j = blockIdx.x * 256 + threadIdx.x;
  if (j < 1024){
    float s = 0.f;
    const int tb = ((j >> 4) << 10) + ((j & 15) << 5);
    for (int e = 0; e < 32; ++e){
      float v = ldv_rw(cbv, j*32 + e, f32m);
      cb32[j*32 + e] = v;
      unsigned short h = f2bf_rw(v);
      cbhl[tb + e]       = (short)h;
      cbhl[tb + e + 512] = (short)f2bf_rw(v - bf2f_rw(h));
      s += v*v;
    }
    cbn[j] = s;
    atomicMax((int*)cmaxp, __float_as_int(sqrtf(s)));  // positive floats: int-bit monotone
  }
}

// ---------------- gemm2 (r11, verified): 32px x 64out tiles ----------------
template<int KCH, int INMODE, bool OUTSILU, bool ATOMIC, int LEVELS>
__global__ __launch_bounds__(256) void gemm2_rw(
    const float* __restrict__ inF, const float* __restrict__ inF2,
    const void* __restrict__ inV,
    const void* __restrict__ W, const void* __restrict__ biasO,
    const void* __restrict__ sbA, const void* __restrict__ sbB,
    const int* __restrict__ idxin, const float* __restrict__ cb32,
    float* __restrict__ outF, const float* __restrict__ flags,
    int KDIM, int OUTC, int o_off, int b_base, int ib_sub, int ob_sub)
{
  __shared__ float As[32][32];
  __shared__ float Bs[32][68];

  const int f32m = (flags[0] != 0.f);
  const int t  = threadIdx.x;
  const int q0 = (blockIdx.x << 5) + (b_base << 8);
  const int b  = q0 >> 8;
  const int p0 = q0 & 255;
  const int o0 = blockIdx.y << 6;
  const int k0base = blockIdx.z * KCH;
  const int tx = t & 15, ty = t >> 4;
  float acc[4][2] = {};

  const int sch = t >> 3, spx = (t & 7) << 2;

  for (int kc = 0; kc < KCH; kc += 32){
    const int k0 = k0base + kc;
    if constexpr (INMODE == 0){
      const float4 v = *reinterpret_cast<const float4*>(
          &inF[(((b - ib_sub)*KDIM + k0 + sch) << 8) + p0 + spx]);
      *reinterpret_cast<float4*>(&As[sch][spx]) = v;
    } else if constexpr (INMODE == 2){
      if (f32m){
        const float* xf = (const float*)inV;
        float4 v = *reinterpret_cast<const float4*>(&xf[((b*KDIM + k0 + sch) << 8) + p0 + spx]);
        v.x = silu_rw(v.x); v.y = silu_rw(v.y); v.z = silu_rw(v.z); v.w = silu_rw(v.w);
        *reinterpret_cast<float4*>(&As[sch][spx]) = v;
      } else {
        const __hip_bfloat16* xb = (const __hip_bfloat16*)inV;
        const int off = ((b*KDIM + k0 + sch) << 8) + p0 + spx;
        #pragma unroll
        for (int j = 0; j < 4; ++j) As[sch][spx + j] = silu_rw(b2f_rw(xb[off + j]));
      }
    } else { // INMODE 5
      const float* src = (k0 < 128) ? inF : inF2;
      const void* sb   = (k0 < 128) ? sbA : sbB;
      const int kh = k0 & 127;
      const float bb = ldv_rw(sb, kh + sch, f32m);
      float4 v = *reinterpret_cast<const float4*>(&src[((b*128 + kh + sch) << 8) + p0 + spx]);
      v.x = silu_rw(v.x + bb); v.y = silu_rw(v.y + bb);
      v.z = silu_rw(v.z + bb); v.w = silu_rw(v.w + bb);
      *reinterpret_cast<float4*>(&As[sch][spx]) = v;
    }
    if (f32m){
      const float* Wf = (const float*)W;
      #pragma unroll
      for (int r = 0; r < 8; ++r){
        int ii = t + (r << 8); int oo = ii >> 5, cc = ii & 31;
        Bs[cc][oo] = Wf[(o0 + oo)*KDIM + k0 + cc];
      }
    } else {
      const __hip_bfloat16* Wb = (const __hip_bfloat16*)W;
      #pragma unroll
      for (int r = 0; r < 8; ++r){
        int ii = t + (r << 8); int oo = ii >> 5, cc = ii & 31;
        Bs[cc][oo] = b2f_rw(Wb[(o0 + oo)*KDIM + k0 + cc]);
      }
    }
    __syncthreads();
    #pragma unroll
    for (int kk = 0; kk < 32; ++kk){
      const float2 a = *reinterpret_cast<const float2*>(&As[kk][tx << 1]);
      const float4 w = *reinterpret_cast<const float4*>(&Bs[kk][ty << 2]);
      acc[0][0] += w.x*a.x; acc[0][1] += w.x*a.y;
      acc[1][0] += w.y*a.x; acc[1][1] += w.y*a.y;
      acc[2][0] += w.z*a.x; acc[2][1] += w.z*a.y;
      acc[3][0] += w.w*a.x; acc[3][1] += w.w*a.y;
    }
    __syncthreads();
  }
  #pragma unroll
  for (int i = 0; i < 4; ++i){
    const int o = o0 + (ty << 2) + i;
    const int base = (((b - ob_sub)*OUTC + o_off + o) << 8) + p0 + (tx << 1);
    if constexpr (ATOMIC){
      atomicAdd(&outF[base + 0], acc[i][0]);
      atomicAdd(&outF[base + 1], acc[i][1]);
    } else {
      const float bb = ldv_rw(biasO, o, f32m);
      float v0 = acc[i][0] + bb, v1 = acc[i][1] + bb;
      if constexpr (OUTSILU){ v0 = silu_rw(v0); v1 = silu_rw(v1); }
      *reinterpret_cast<float2*>(&outF[base]) = make_float2(v0, v1);
    }
  }
}

// ------------- houtm: MFMA gather-GEMM for hout_p / hout_n -------------
// out-raw[b][o][p] (+)= W[o][:1024] . zq[:1024][p], accumulated via f32
// atomics into zeroed R2/R3 (same interface as the scalar path). Block:
// 256thr/4 waves, 32px x 64out, K=256 (z-slice kz of 4: e in kz*8..+7).
// zq channel c = e*32 + sch; code idx depends on (sch,px) only -> hoisted
// to regs. Per e: gather hi/lo from cbhl -> LDS As_h/As_l[px][sch]; wave
// w (out o0+w*16+lc): A-frags 2x ds_read_b128 pairs, W-frag split on the
// fly, 3-MFMA hi/lo (err ~2^-16, vs out threshold 6.6e-4). D mapping
// (col=lane&15=out, row=(lane>>4)*4+r=px) is the quantm-verified one.
template<int LEVELS>
__global__ __launch_bounds__(256, 4) void houtm_rw(
    const int* __restrict__ idxin, const short* __restrict__ cbhl,
    const void* __restrict__ W, float* __restrict__ outF,
    const float* __restrict__ flags)
{
  __shared__ short As_h[32][32];
  __shared__ short As_l[32][32];

  const int f32m = (flags[0] != 0.f);
  const int t = threadIdx.x;
  const int lane = t & 63, wid = t >> 6;
  const int lc = lane & 15, gq = lane >> 4;
  const int b   = blockIdx.x >> 3;
  const int p0  = (blockIdx.x & 7) << 5;
  const int o0  = (blockIdx.y << 6) + (wid << 4);
  const int kz  = blockIdx.z;               // e octet

  const int sch_t = t >> 3, pxj = (t & 7) << 2;

  // hoist the 4 code indices this thread stages (independent of e)
  int idx_r[4];
  #pragma unroll
  for (int j = 0; j < 4; ++j){
    const int px = p0 + pxj + j;
    if (LEVELS == 4){
      const int l = sch_t >> 3, kp = sch_t & 7;
      idx_r[j] = idxin[b*8192 + (((kp << 8) + px) << 2) + l] & 1023;
    } else {
      idx_r[j] = idxin[b*8192 + (sch_t << 8) + px] & 1023;
    }
  }

  const int o = o0 + lc;
  f32x4 acc0 = {0.f, 0.f, 0.f, 0.f};
  f32x4 acc1 = {0.f, 0.f, 0.f, 0.f};

  const unsigned short* cbu = (const unsigned short*)cbhl;

  for (int el = 0; el < 8; ++el){
    const int e = (kz << 3) + el;
    // stage zq hi/lo for this e
    #pragma unroll
    for (int j = 0; j < 4; ++j){
      const int id = idx_r[j];
      const int a  = ((id >> 4) << 10) + ((id & 15) << 5) + e;
      As_h[pxj + j][sch_t] = (short)cbu[a];
      As_l[pxj + j][sch_t] = (short)cbu[a + 512];
    }
    __syncthreads();

    const bf16x8 ah0 = *reinterpret_cast<const bf16x8*>(&As_h[lc][gq << 3]);
    const bf16x8 al0 = *reinterpret_cast<const bf16x8*>(&As_l[lc][gq << 3]);
    const bf16x8 ah1 = *reinterpret_cast<const bf16x8*>(&As_h[16 + lc][gq << 3]);
    const bf16x8 al1 = *reinterpret_cast<const bf16x8*>(&As_l[16 + lc][gq << 3]);

    // W fragment: k = kz*256 + el*32 + gq*8 + i, split hi/lo on the fly
    const int kb = (kz << 8) + (el << 5) + (gq << 3);
    bf16x8 bh, bl;
    #pragma unroll
    for (int i = 0; i < 8; ++i){
      const float wv = ldv_rw(W, o*1024 + kb + i, f32m);
      const unsigned short h = f2bf_rw(wv);
      bh[i] = (short)h;
      bl[i] = (short)f2bf_rw(wv - bf2f_rw(h));
    }

    acc0 = __builtin_amdgcn_mfma_f32_16x16x32_bf16(ah0, bh, acc0, 0, 0, 0);
    acc0 = __builtin_amdgcn_mfma_f32_16x16x32_bf16(ah0, bl, acc0, 0, 0, 0);
    acc0 = __builtin_amdgcn_mfma_f32_16x16x32_bf16(al0, bh, acc0, 0, 0, 0);
    acc1 = __builtin_amdgcn_mfma_f32_16x16x32_bf16(ah1, bh, acc1, 0, 0, 0);
    acc1 = __builtin_amdgcn_mfma_f32_16x16x32_bf16(ah1, bl, acc1, 0, 0, 0);
    acc1 = __builtin_amdgcn_mfma_f32_16x16x32_bf16(al1, bh, acc1, 0, 0, 0);
    __syncthreads();
  }

  // epilogue: atomic accumulate raw partials (D col=out, row=px)
  const int obase = ((b*128 + o) << 8) + p0 + (gq << 2);
  #pragma unroll
  for (int r = 0; r < 4; ++r){
    atomicAdd(&outF[obase + r],      acc0[r]);
    atomicAdd(&outF[obase + 16 + r], acc1[r]);
  }
}

// ---------------- per-sample LN stats over silu(h_half) ----------------
__global__ __launch_bounds__(256) void stats_rw(const float* __restrict__ h, float* __restrict__ stats){
  const int b = blockIdx.x >> 1, half = blockIdx.x & 1;
  const float* base = h + ((b*256 + half*128) << 8);
  float s = 0.f, s2 = 0.f;
  for (int i = threadIdx.x; i < 32768; i += 256){
    float a = silu_rw(base[i]);
    s += a; s2 += a*a;
  }
  __shared__ float sh[2][256];
  sh[0][threadIdx.x] = s; sh[1][threadIdx.x] = s2;
  __syncthreads();
  for (int st = 128; st > 0; st >>= 1){
    if (threadIdx.x < st){
      sh[0][threadIdx.x] += sh[0][threadIdx.x + st];
      sh[1][threadIdx.x] += sh[1][threadIdx.x + st];
    }
    __syncthreads();
  }
  if (threadIdx.x == 0){
    float mu  = sh[0][0] * (1.f/32768.f);
    float var = sh[1][0] * (1.f/32768.f) - mu*mu;
    stats[half*32 + b]      = mu;
    stats[half*32 + 16 + b] = 1.f / sqrtf(var + 1e-5f);
  }
}

// ---------------- LN apply ----------------
__global__ __launch_bounds__(256) void ln_rw(const float* __restrict__ h,
    const void* lwp, const void* lbp, const void* lwn, const void* lbn,
    const float* __restrict__ stats, const float* __restrict__ flags,
    float* __restrict__ lnp, float* __restrict__ lnn){
  const int f32m = (flags[0] != 0.f);
  int i = blockIdx.x * 256 + threadIdx.x;
  int b = i >> 16, c = (i >> 8) & 255, p = i & 255;
  float a = silu_rw(h[i]);
  if (c < 128){
    float v = (a - stats[b]) * stats[16 + b] * ldv_rw(lwp, (c << 8) + p, f32m) + ldv_rw(lbp, (c << 8) + p, f32m);
    lnp[((b*128 + c) << 8) + p] = v;
  } else {
    int cc = c - 128;
    float v = (a - stats[32 + b]) * stats[48 + b] * ldv_rw(lwn, (cc << 8) + p, f32m) + ldv_rw(lbn, (cc << 8) + p, f32m);
    lnn[((b*128 + cc) << 8) + p] = v;
  }
}

// ---------------- VQ search v6b (r18-exact, proven 59us) ------------------
// 512 thr = 8 waves; wave = (pg = wid&3 pixel group, ch = wid>>2 code
// half, 32 tiles of 16 codes). launch_bounds(512,4): cap 128, no spill.
// Cert eb = 3e-4*sqrt(zn)*cmax + 2e-6*zn, else np-bit-exact fallback.
template<int LEVELS>
__global__ __launch_bounds__(512, 4) void quantm_rw(
    const float* __restrict__ z, const short* __restrict__ cbhl,
    const float* __restrict__ cbn, const float* __restrict__ cmaxp,
    int* __restrict__ idxout, float* __restrict__ lossacc,
    int* __restrict__ cnt, int* __restrict__ list, int b_base)
{
  __shared__ float mgm1[4][4][8], mgm2[4][4][8];
  __shared__ int   mgj [4][4][8];
  __shared__ float red[4];

  const int tid  = threadIdx.x;
  const int lane = tid & 63, wid = tid >> 6;
  const int lc = lane & 15, gq = lane >> 4;
  const int pg = wid & 3, ch = wid >> 2;    // pixel group, code half
  const int bid  = blockIdx.x;
  const int bl   = bid >> 6;                // local batch
  const int rest = bid & 63;
  const int g = rest >> 1, half = rest & 1;
  int cb, wbase, wstep;
  if (LEVELS == 4){ cb = (g & 3)*8 + (g >> 2); wbase = (g >> 2)*1024 + (g & 3); wstep = 4; }
  else            { cb = g;                    wbase = g << 8;                  wstep = 1; }
  const int pb = half*128 + pg*32;

  // ---- load z rows, build -2z hi/lo bf16 A-fragments, partial |z|^2 ----
  bf16x8 ah0, al0, ah1, al1;
  float zn0 = 0.f, zn1 = 0.f;
  const int zoff = (((bl << 10) + cb) << 8) + pb + lc;
  const int e0 = gq << 3;
  #pragma unroll
  for (int i = 0; i < 8; ++i){
    const int zo = zoff + ((e0 + i) << 13);
    const float z0 = z[zo];
    const float z1 = z[zo + 16];
    zn0 += z0*z0; zn1 += z1*z1;
    const float s0 = -2.f*z0, s1 = -2.f*z1;
    const unsigned short h0 = f2bf_rw(s0);
    const unsigned short h1 = f2bf_rw(s1);
    ah0[i] = (short)h0; al0[i] = (short)f2bf_rw(s0 - bf2f_rw(h0));
    ah1[i] = (short)h1; al1[i] = (short)f2bf_rw(s1 - bf2f_rw(h1));
  }
  zn0 += __shfl_xor(zn0, 16); zn0 += __shfl_xor(zn0, 32);   // full zn for row lc
  zn1 += __shfl_xor(zn1, 16); zn1 += __shfl_xor(zn1, 32);

  float m1[8], m2[8]; int j1[8];
  #pragma unroll
  for (int s = 0; s < 8; ++s){ m1[s] = __builtin_inff(); m2[s] = __builtin_inff(); j1[s] = 0; }

  // interleaved table: wave's tiles T = ch*32 + t; shorts base:
  const short* bp  = cbhl + (ch << 15) + (lc << 5) + (gq << 3);
  const float* cnp = cbn + (ch << 9) + lc;

  bf16x8 bh  = *reinterpret_cast<const bf16x8*>(bp);
  bf16x8 blo = *reinterpret_cast<const bf16x8*>(bp + 512);
  float  cnv = cnp[0];

  #pragma unroll 2
  for (int t = 0; t < 32; ++t){
    const int tn = (t < 31) ? t + 1 : 31;      // clamped prefetch index
    const bf16x8 bhn  = *reinterpret_cast<const bf16x8*>(bp + (tn << 10));
    const bf16x8 blon = *reinterpret_cast<const bf16x8*>(bp + (tn << 10) + 512);
    const float  cnn  = cnp[tn << 4];

    f32x4 a0 = {cnv, cnv, cnv, cnv};
    f32x4 a1 = {cnv, cnv, cnv, cnv};
    a0 = __builtin_amdgcn_mfma_f32_16x16x32_bf16(ah0, bh,  a0, 0, 0, 0);
    a0 = __builtin_amdgcn_mfma_f32_16x16x32_bf16(ah0, blo, a0, 0, 0, 0);
    a0 = __builtin_amdgcn_mfma_f32_16x16x32_bf16(al0, bh,  a0, 0, 0, 0);
    a1 = __builtin_amdgcn_mfma_f32_16x16x32_bf16(ah1, bh,  a1, 0, 0, 0);
    a1 = __builtin_amdgcn_mfma_f32_16x16x32_bf16(ah1, blo, a1, 0, 0, 0);
    a1 = __builtin_amdgcn_mfma_f32_16x16x32_bf16(al1, bh,  a1, 0, 0, 0);

    const int jc = (((ch << 5) + t) << 4) + lc;
    #pragma unroll
    for (int r = 0; r < 4; ++r){
      const float d0 = a0[r];
      m2[r] = __builtin_amdgcn_fmed3f(d0, m1[r], m2[r]);
      const bool t0 = d0 < m1[r];
      j1[r] = t0 ? jc : j1[r]; m1[r] = t0 ? d0 : m1[r];
      const float d1 = a1[r];
      m2[4+r] = __builtin_amdgcn_fmed3f(d1, m1[4+r], m2[4+r]);
      const bool t1 = d1 < m1[4+r];
      j1[4+r] = t1 ? jc : j1[4+r]; m1[4+r] = t1 ? d1 : m1[4+r];
    }
    bh = bhn; blo = blon; cnv = cnn;
  }

  // ---- 16-lane top-2 merge (cols of each row live in one 16-lane group) ----
  #pragma unroll
  for (int k = 1; k < 16; k <<= 1){
    #pragma unroll
    for (int s = 0; s < 8; ++s){
      const float om1 = __shfl_xor(m1[s], k);
      const float om2 = __shfl_xor(m2[s], k);
      const int   oj  = __shfl_xor(j1[s], k);
      m2[s] = fminf(fminf(m2[s], om2), fmaxf(m1[s], om1));
      const bool tk = (om1 < m1[s]) || (om1 == m1[s] && oj < j1[s]);
      m1[s] = tk ? om1 : m1[s];
      j1[s] = tk ? oj  : j1[s];
    }
  }

  // ---- cross-wave merge: upper code-half -> LDS, lower merges ----
  if (wid >= 4 && lc == 0){
    #pragma unroll
    for (int s = 0; s < 8; ++s){
      mgm1[wid-4][gq][s] = m1[s];
      mgm2[wid-4][gq][s] = m2[s];
      mgj [wid-4][gq][s] = j1[s];
    }
  }
  __syncthreads();
  if (wid < 4){
    #pragma unroll
    for (int s = 0; s < 8; ++s){
      const float om1 = mgm1[wid][gq][s];
      const float om2 = mgm2[wid][gq][s];
      const int   oj  = mgj [wid][gq][s];
      m2[s] = fminf(fminf(m2[s], om2), fmaxf(m1[s], om1));
      const bool tk = om1 < m1[s];       // tie keeps lower half (smaller j)
      m1[s] = tk ? om1 : m1[s];
      j1[s] = tk ? oj  : j1[s];
    }

    // ---- finalize: cert test, idx write, loss, uncertain list ----
    const float cmax = cmaxp[0];
    float lossw = 0.f;
    #pragma unroll
    for (int f = 0; f < 2; ++f){
      #pragma unroll
      for (int r = 0; r < 4; ++r){
        const int s = f*4 + r;
        const int vrow = (gq << 2) + r;
        const float znv = __shfl(f == 0 ? zn0 : zn1, vrow);
        if (lc == 0){
          const int p  = pb + f*16 + vrow;
          const int gi = (b_base + bl)*8192 + wbase + p*wstep;
          idxout[gi] = j1[s];                    // provisional if uncertain
          const float eb = fmaf(2.0e-6f, znv, 3.0e-4f * sqrtf(znv) * cmax);
          if (m2[s] - m1[s] > eb){
            lossw += znv + m1[s];
          } else {
            const int pos = atomicAdd(cnt, 1);
            if (pos < 131072) list[pos] = (((bl << 5) | g) << 8) | p;
          }
        }
      }
    }
    lossw += __shfl_xor(lossw, 16);
    lossw += __shfl_xor(lossw, 32);
    if (lane == 0) red[wid] = lossw;
  }
  __syncthreads();
  if (tid == 0) atomicAdd(lossacc, red[0] + red[1] + red[2] + red[3]);
}

// ---------------- np-bit-exact f32 fallback for uncertain vectors ----------
// Replicates the reference rounding exactly: dot via ascending sequential
// fmaf, zn via ascending sequential fmaf, d = (zn - 2*dot) + cn,
// first-min == lexicographic (d,j). 640-block grid, unroll-4 j-loop,
// float4 cb loads, zb[] broadcast hoist. Per-dot fmaf ORDER unchanged.
template<int LEVELS>
__global__ __launch_bounds__(256) void fb_rw(
    const float* __restrict__ z, const float* __restrict__ cb32,
    const float* __restrict__ cbn, const int* __restrict__ cnt,
    const int* __restrict__ list, int* __restrict__ idxout,
    float* __restrict__ lossacc, int b_base)
{
  const int lane = threadIdx.x & 63;
  const int wv = (blockIdx.x << 2) | (threadIdx.x >> 6);
  const int nw = gridDim.x << 2;
  int n = cnt[0];
  if (n > 131072) n = 131072;
  for (int it = wv; it < n; it += nw){
    const int id = list[it];
    const int p = id & 255, g = (id >> 8) & 31, bl = id >> 13;
    int cb, w;
    if (LEVELS == 4){ cb = (g & 3)*8 + (g >> 2); w = (g >> 2)*1024 + (p << 2) + (g & 3); }
    else            { cb = g;                    w = (g << 8) + p; }
    const int zoff = (((bl << 10) + cb) << 8) + p;
    float myz = 0.f;
    if (lane < 32) myz = z[zoff + (lane << 13)];
    // broadcast z to all lanes (register array; compile-time indexed)
    float zb[32];
    #pragma unroll
    for (int e = 0; e < 32; ++e) zb[e] = __shfl(myz, e);
    // zn: sequential ascending fmaf (matches np's accumulation order)
    float zn = 0.f;
    #pragma unroll
    for (int e = 0; e < 32; ++e) zn = fmaf(zb[e], zb[e], zn);
    float bd = __builtin_inff(); int bj = 0;
    #pragma unroll 4
    for (int jj = 0; jj < 16; ++jj){
      const int j = (jj << 6) + lane;
      const float4* c4 = reinterpret_cast<const float4*>(cb32 + (j << 5));
      float dot = 0.f;
      #pragma unroll
      for (int e4 = 0; e4 < 8; ++e4){
        const float4 cv = c4[e4];
        dot = fmaf(zb[(e4 << 2) + 0], cv.x, dot);
        dot = fmaf(zb[(e4 << 2) + 1], cv.y, dot);
        dot = fmaf(zb[(e4 << 2) + 2], cv.z, dot);
        dot = fmaf(zb[(e4 << 2) + 3], cv.w, dot);
      }
      const float d = (zn - 2.f*dot) + cbn[j];   // np's exact formula/rounding
      if (d < bd){ bd = d; bj = j; }
    }
    #pragma unroll
    for (int k = 1; k < 64; k <<= 1){
      const float od = __shfl_xor(bd, k);
      const int   oj = __shfl_xor(bj, k);
      if (od < bd || (od == bd && oj < bj)){ bd = od; bj = oj; }
    }
    if (lane == 0){
      idxout[(b_base + bl)*8192 + w] = bj;
      atomicAdd(lossacc, bd);                    // bd == |z-c|^2 (includes zn)
    }
  }
}

// ---------------- zq_p output (f32) ----------------
__global__ __launch_bounds__(256) void zqout_rw(const int* __restrict__ idxp,
    const float* __restrict__ cb32, float* __restrict__ out){
  int t = blockIdx.x * 256 + threadIdx.x;
  int l = t & 3, n = (t >> 2) & 2047, e = (t >> 13) & 31, b = t >> 18;
  int id = idxp[b*8192 + (n << 2) + l];
  out[t] = cb32[((id & 1023) << 5) + e];
}

// ---------------- zero hcat accum ----------------
__global__ __launch_bounds__(256) void zero_rw(float* __restrict__ p){
  p[blockIdx.x * 256 + threadIdx.x] = 0.f;
}

// ---------------- loss finalize ----------------
__global__ void loss_rw(const float* __restrict__ lossacc, float* __restrict__ out){
  if (threadIdx.x == 0 && blockIdx.x == 0)
    out[0] = 1.25f * (lossacc[0] + lossacc[1]) * (1.f/4194304.f);
}

extern "C" void kernel_launch(void* const* d_in, const int* in_sizes, int n_in,
                              void* d_out, int out_size, void* d_ws, size_t ws_size,
                              hipStream_t stream){
  (void)in_sizes; (void)n_in; (void)out_size;
  const void* x   = d_in[0];
  const void* ciw = d_in[1];
  const void* cib = d_in[2];
  const void* lwp = d_in[3];
  const void* lbp = d_in[4];
  const void* wpi = d_in[5];
  const void* bpi = d_in[6];
  const void* wpo = d_in[7];
  const void* bpo = d_in[8];
  const void* lwn = d_in[9];
  const void* lbn = d_in[10];
  const void* wni = d_in[11];
  const void* bni = d_in[12];
  const void* wno = d_in[13];
  const void* bno = d_in[14];
  const void* cbk = d_in[15];
  const void* cow = d_in[16];
  const void* cob = d_in[17];

  float* ws    = (float*)d_ws;
  float* flags = ws + FLAGS_OFF;
  float* loss  = ws + LOSS_OFF;
  float* stats = ws + STATS_OFF;
  float* cmaxp = ws + CMAX_OFF;
  float* cb32  = ws + CB32_OFF;
  float* cbn   = ws + CBN_OFF;
  int*   cnts  = (int*)(ws + CNT_OFF);
  int*   idxp  = (int*)(ws + IDXP_OFF);
  int*   idxn  = (int*)(ws + IDXN_OFF);
  short* cbhl  = (short*)(ws + CBHL_OFF);
  int*   list  = (int*)(ws + LIST_OFF);
  float* R2    = ws + R2_OFF;
  float* R3    = ws + R3_OFF;
  float* R1    = ws + R1_OFF;

  float* outO = (float*)d_out;
  float* outL = outO + 1048576;
  float* outZ = outO + 1048577;

  const size_t wsf = ws_size / 4;
  int CS = 4;
  if      (wsf >= (size_t)R1_OFF + 16u*262144u) CS = 16;
  else if (wsf >= (size_t)R1_OFF +  8u*262144u) CS = 8;

  detect_rw<<<1, 256, 0, stream>>>(cbk, ws);
  cbprep_rw<<<4, 256, 0, stream>>>(cbk, flags, cb32, cbn, cbhl, cmaxp);
  // h = conv_in(silu(x)) -> R1
  gemm2_rw<256,2,false,false,0><<<dim3(128,4), 256, 0, stream>>>(
      nullptr, nullptr, x, ciw, cib, nullptr, nullptr, nullptr, nullptr,
      R1, flags, 256, 256, 0, 0, 0, 0);
  stats_rw<<<32, 256, 0, stream>>>(R1, stats);
  ln_rw<<<4096, 256, 0, stream>>>(R1, lwp, lbp, lwn, lbn, stats, flags, R2, R3);
  // phylo: z chunks (R2 -> R1), MFMA quantize + np-exact fallback
  {
    int ci = 0;
    for (int c = 0; c < 16; c += CS, ++ci){
      gemm2_rw<128,0,true,false,0><<<dim3(CS*8,16), 256, 0, stream>>>(
          R2, nullptr, nullptr, wpi, bpi, nullptr, nullptr, nullptr, nullptr,
          R1, flags, 128, 1024, 0, c, 0, c);
      quantm_rw<4><<<CS*64, 512, 0, stream>>>(R1, cbhl, cbn, cmaxp,
                                              idxp, loss + 0, cnts + ci, list, c);
      fb_rw<4><<<640, 256, 0, stream>>>(R1, cb32, cbn, cnts + ci, list,
                                        idxp, loss + 0, c);
    }
  }
  // non-phylo
  {
    int ci = 4;
    for (int c = 0; c < 16; c += CS, ++ci){
      gemm2_rw<128,0,true,false,0><<<dim3(CS*8,16), 256, 0, stream>>>(
          R3, nullptr, nullptr, wni, bni, nullptr, nullptr, nullptr, nullptr,
          R1, flags, 128, 1024, 0, c, 0, c);
      quantm_rw<1><<<CS*64, 512, 0, stream>>>(R1, cbhl, cbn, cmaxp,
                                              idxn, loss + 1, cnts + ci, list, c);
      fb_rw<1><<<640, 256, 0, stream>>>(R1, cb32, cbn, cnts + ci, list,
                                        idxn, loss + 1, c);
    }
  }
  zqout_rw<<<16384, 256, 0, stream>>>(idxp, cb32, outZ);
  // hcat accum := 0 (R2 and R3 are contiguous: 4096*256 = 1048576 floats)
  zero_rw<<<4096, 256, 0, stream>>>(R2);
  // hout_p / hout_n: MFMA gather-GEMM, split-K x4, atomic accum
  houtm_rw<4><<<dim3(128, 2, 4), 256, 0, stream>>>(idxp, cbhl, wpo, R2, flags);
  houtm_rw<1><<<dim3(128, 2, 4), 256, 0, stream>>>(idxn, cbhl, wno, R3, flags);
  // out = conv_out(silu(hcat + hout_bias))
  gemm2_rw<256,5,false,false,0><<<dim3(128,4), 256, 0, stream>>>(
      R2, R3, nullptr, cow, cob, bpo, bno, nullptr, nullptr,
      outO, flags, 256, 256, 0, 0, 0, 0);
  loss_rw<<<1, 64, 0, stream>>>(loss, outL);
}

// Round 10
// 568.417 us; speedup vs baseline: 1.0853x; 1.0853x over previous
//
#include <hip/hip_runtime.h>
#include <hip/hip_bf16.h>

// Round 22: houtm redesign. r21 houtm: 81.7us x2, BANK_CONFLICT 4.2M
// (As[px][sch] write: px-stride 64B = 1 bank), Mfma 1.5%, VALU 4.8% --
// latency-dead: 16 scattered u16 gathers/thread + 2 barriers per 6 MFMAs.
// houtm2: k-dim = e (not sch) -> A-frag = ONE b128 gather from cbhl
// (32 consecutive e per code already in that table); B-frag from whl =
// W pre-transposed once (wprep_rw) into [sch][o][e] bf16 hi/lo MFMA
// fragments, stored in the then-dead R1 region. No LDS, no barriers;
// per sch: 6 indep b128 loads + 6 MFMA; 8 idx preloaded. Same zeroed-
// R2/R3 atomic raw-partial interface + r21-verified fragment mappings.
// bounds(256,4) cap 128 (~70 live), unroll-1 sch loop. quantm r18-exact.
// Outputs (f32): out[1048576] | loss[1] | zq_p[4194304].

typedef float f32x4  __attribute__((ext_vector_type(4)));
typedef short bf16x8 __attribute__((ext_vector_type(8)));

__device__ __forceinline__ float silu_rw(float x){ return x / (1.f + expf(-x)); }
__device__ __forceinline__ float b2f_rw(__hip_bfloat16 v){ return __bfloat162float(v); }
__device__ __forceinline__ float ldv_rw(const void* p, int i, int f32m){
  if (f32m) return ((const float*)p)[i];
  return b2f_rw(((const __hip_bfloat16*)p)[i]);
}
__device__ __forceinline__ unsigned short f2bf_rw(float x){   // f32 -> bf16 RNE
  unsigned u = __float_as_uint(x);
  unsigned r = ((u >> 16) & 1u) + 0x7FFFu;
  return (unsigned short)((u + r) >> 16);
}
__device__ __forceinline__ float bf2f_rw(unsigned short h){
  return __uint_as_float(((unsigned)h) << 16);
}

// ---------------- workspace layout (float offsets) ----------------
#define FLAGS_OFF 0
#define LOSS_OFF  4
#define STATS_OFF 8
#define CNT_OFF   72         // 8 ints: fallback counters per chunk
#define CMAX_OFF  80         // max_j |c_j| (f32)
#define CB32_OFF  128        // 1024x32 f32
#define CBN_OFF   32896      // 1024
#define IDXP_OFF  33984      // 131072 int
#define IDXN_OFF  165056     // 131072 int
#define CBHL_OFF  296192     // interleaved hi/lo bf16 table (32768 f32 slots)
#define LIST_OFF  328960     // 131072 int (uncertain list, reused per chunk)
#define R2_OFF    460032     // lnp -> hcat_p accum (524288)
#define R3_OFF    984320     // lnn -> hcat_n accum (524288)
#define R1_OFF    1508608    // h (1048576) / z chunks (CS*262144) / whl tables

// ---------------- input dtype probe + zero accumulators ----------------
__global__ __launch_bounds__(256) void detect_rw(const void* cbv, float* wsb){
  __shared__ int bad;
  if (threadIdx.x == 0) bad = 0;
  __syncthreads();
  const unsigned short* u = (const unsigned short*)cbv;
  int local = 0;
  for (int i = threadIdx.x; i < 32768; i += 256){
    unsigned e = (u[i] >> 7) & 0xFF;
    if (e >= 126) local = 1;
  }
  if (local) bad = 1;
  __syncthreads();
  if (threadIdx.x == 0){
    wsb[FLAGS_OFF] = bad ? 1.f : 0.f;   // 1.0 => inputs are f32
    wsb[LOSS_OFF] = 0.f; wsb[LOSS_OFF + 1] = 0.f;
    int* c = (int*)(wsb + CNT_OFF);
    #pragma unroll
    for (int k = 0; k < 8; ++k) c[k] = 0;
    wsb[CMAX_OFF] = 0.f;
  }
}

// ------ codebook -> f32 + |c|^2 + interleaved bf16 hi/lo tile table ------
// Tile T = j>>4 occupies shorts [T*1024, T*1024+1024): hi of code j elem e
// at T*1024 + (j&15)*32 + e, lo at +512.
__global__ __launch_bounds__(256) void cbprep_rw(const void* cbv, const float* flags,
                                                 float* cb32, float* cbn,
                                                 short* cbhl, float* cmaxp){
  const int f32m = (flags[0] != 0.f);
  int j = blockIdx.x * 256 + threadIdx.x;
  if (j < 1024){
    float s = 0.f;
    const int tb = ((j >> 4) << 10) + ((j & 15) << 5);
    for (int e = 0; e < 32; ++e){
      float v = ldv_rw(cbv, j*32 + e, f32m);
      cb32[j*32 + e] = v;
      unsigned short h = f2bf_rw(v);
      cbhl[tb + e]       = (short)h;
      cbhl[tb + e + 512] = (short)f2bf_rw(v - bf2f_rw(h));
      s += v*v;
    }
    cbn[j] = s;
    atomicMax((int*)cmaxp, __float_as_int(sqrtf(s)));  // positive floats: int-bit monotone
  }
}

// ---------------- gemm2 (r11, verified): 32px x 64out tiles ----------------
template<int KCH, int INMODE, bool OUTSILU, bool ATOMIC, int LEVELS>
__global__ __launch_bounds__(256) void gemm2_rw(
    const float* __restrict__ inF, const float* __restrict__ inF2,
    const void* __restrict__ inV,
    const void* __restrict__ W, const void* __restrict__ biasO,
    const void* __restrict__ sbA, const void* __restrict__ sbB,
    const int* __restrict__ idxin, const float* __restrict__ cb32,
    float* __restrict__ outF, const float* __restrict__ flags,
    int KDIM, int OUTC, int o_off, int b_base, int ib_sub, int ob_sub)
{
  __shared__ float As[32][32];
  __shared__ float Bs[32][68];

  const int f32m = (flags[0] != 0.f);
  const int t  = threadIdx.x;
  const int q0 = (blockIdx.x << 5) + (b_base << 8);
  const int b  = q0 >> 8;
  const int p0 = q0 & 255;
  const int o0 = blockIdx.y << 6;
  const int k0base = blockIdx.z * KCH;
  const int tx = t & 15, ty = t >> 4;
  float acc[4][2] = {};

  const int sch = t >> 3, spx = (t & 7) << 2;

  for (int kc = 0; kc < KCH; kc += 32){
    const int k0 = k0base + kc;
    if constexpr (INMODE == 0){
      const float4 v = *reinterpret_cast<const float4*>(
          &inF[(((b - ib_sub)*KDIM + k0 + sch) << 8) + p0 + spx]);
      *reinterpret_cast<float4*>(&As[sch][spx]) = v;
    } else if constexpr (INMODE == 2){
      if (f32m){
        const float* xf = (const float*)inV;
        float4 v = *reinterpret_cast<const float4*>(&xf[((b*KDIM + k0 + sch) << 8) + p0 + spx]);
        v.x = silu_rw(v.x); v.y = silu_rw(v.y); v.z = silu_rw(v.z); v.w = silu_rw(v.w);
        *reinterpret_cast<float4*>(&As[sch][spx]) = v;
      } else {
        const __hip_bfloat16* xb = (const __hip_bfloat16*)inV;
        const int off = ((b*KDIM + k0 + sch) << 8) + p0 + spx;
        #pragma unroll
        for (int j = 0; j < 4; ++j) As[sch][spx + j] = silu_rw(b2f_rw(xb[off + j]));
      }
    } else { // INMODE 5
      const float* src = (k0 < 128) ? inF : inF2;
      const void* sb   = (k0 < 128) ? sbA : sbB;
      const int kh = k0 & 127;
      const float bb = ldv_rw(sb, kh + sch, f32m);
      float4 v = *reinterpret_cast<const float4*>(&src[((b*128 + kh + sch) << 8) + p0 + spx]);
      v.x = silu_rw(v.x + bb); v.y = silu_rw(v.y + bb);
      v.z = silu_rw(v.z + bb); v.w = silu_rw(v.w + bb);
      *reinterpret_cast<float4*>(&As[sch][spx]) = v;
    }
    if (f32m){
      const float* Wf = (const float*)W;
      #pragma unroll
      for (int r = 0; r < 8; ++r){
        int ii = t + (r << 8); int oo = ii >> 5, cc = ii & 31;
        Bs[cc][oo] = Wf[(o0 + oo)*KDIM + k0 + cc];
      }
    } else {
      const __hip_bfloat16* Wb = (const __hip_bfloat16*)W;
      #pragma unroll
      for (int r = 0; r < 8; ++r){
        int ii = t + (r << 8); int oo = ii >> 5, cc = ii & 31;
        Bs[cc][oo] = b2f_rw(Wb[(o0 + oo)*KDIM + k0 + cc]);
      }
    }
    __syncthreads();
    #pragma unroll
    for (int kk = 0; kk < 32; ++kk){
      const float2 a = *reinterpret_cast<const float2*>(&As[kk][tx << 1]);
      const float4 w = *reinterpret_cast<const float4*>(&Bs[kk][ty << 2]);
      acc[0][0] += w.x*a.x; acc[0][1] += w.x*a.y;
      acc[1][0] += w.y*a.x; acc[1][1] += w.y*a.y;
      acc[2][0] += w.z*a.x; acc[2][1] += w.z*a.y;
      acc[3][0] += w.w*a.x; acc[3][1] += w.w*a.y;
    }
    __syncthreads();
  }
  #pragma unroll
  for (int i = 0; i < 4; ++i){
    const int o = o0 + (ty << 2) + i;
    const int base = (((b - ob_sub)*OUTC + o_off + o) << 8) + p0 + (tx << 1);
    if constexpr (ATOMIC){
      atomicAdd(&outF[base + 0], acc[i][0]);
      atomicAdd(&outF[base + 1], acc[i][1]);
    } else {
      const float bb = ldv_rw(biasO, o, f32m);
      float v0 = acc[i][0] + bb, v1 = acc[i][1] + bb;
      if constexpr (OUTSILU){ v0 = silu_rw(v0); v1 = silu_rw(v1); }
      *reinterpret_cast<float2*>(&outF[base]) = make_float2(v0, v1);
    }
  }
}

// ------- wprep: W[o][e*32+sch] -> whl[sch][o][hi e 0..31 | lo e 0..31] ------
// One-time transpose into MFMA-ready bf16 hi/lo B-fragments (64 shorts per
// (sch,o)). Reads coalesced across sch lanes; runs after R1 is dead.
__global__ __launch_bounds__(256) void wprep_rw(const void* Wp, const void* Wn,
    const float* flags, short* whlp, short* whln){
  const int f32m = (flags[0] != 0.f);
  const void* W = blockIdx.y ? Wn : Wp;
  short* whl = blockIdx.y ? whln : whlp;
  const int t = threadIdx.x;
  const int sch = t & 31, o = (blockIdx.x << 3) + (t >> 5);
  const int ob = ((sch << 7) + o) << 6;   // *64 shorts
  for (int e = 0; e < 32; ++e){
    const float wv = ldv_rw(W, (o << 10) + (e << 5) + sch, f32m);
    const unsigned short h = f2bf_rw(wv);
    whl[ob + e]      = (short)h;
    whl[ob + 32 + e] = (short)f2bf_rw(wv - bf2f_rw(h));
  }
}

// ------------- houtm2: gather-free-fragment MFMA for hout_p/n -------------
// out-raw[b][o][px] (+)= sum_sch sum_e W[o][e*32+sch] * cb[J[sch][px]][e].
// k-dim = e: A-frag row px = lane&15, k-slice = (lane>>4)*8.. -> one b128
// gather per frag from cbhl (code's 32 e are contiguous). B-frag from whl
// (pre-transposed). No LDS, no barriers. Grid (128 pxtile, 2 oblk,
// 4 sch-split); wave = o-subtile (wid*16). Epilogue: r21-verified D map
// (col=o=lane&15, row px=(lane>>4)*4+r; acc1 rows +16), atomic raw adds.
template<int LEVELS>
__global__ __launch_bounds__(256, 4) void houtm2_rw(
    const int* __restrict__ idxin, const short* __restrict__ cbhl,
    const short* __restrict__ whl, float* __restrict__ outF)
{
  const int t = threadIdx.x;
  const int lane = t & 63, wid = t >> 6;
  const int lc = lane & 15, gq = lane >> 4;
  const int b  = blockIdx.x >> 3;
  const int p0 = (blockIdx.x & 7) << 5;
  const int o0 = (blockIdx.y << 6) + (wid << 4);
  const int s0 = blockIdx.z << 3;
  const int ge = gq << 3;

  // preload the 8 sch code indices for both px rows (coalesced-ish)
  int j0[8], j1[8];
  #pragma unroll
  for (int s = 0; s < 8; ++s){
    const int sch = s0 + s;
    int a0, a1;
    if (LEVELS == 4){
      const int l = sch >> 3, kp = sch & 7;
      a0 = b*8192 + (((kp << 8) + p0 + lc) << 2) + l;
      a1 = b*8192 + (((kp << 8) + p0 + 16 + lc) << 2) + l;
    } else {
      a0 = b*8192 + (sch << 8) + p0 + lc;
      a1 = a0 + 16;
    }
    j0[s] = idxin[a0] & 1023;
    j1[s] = idxin[a1] & 1023;
  }

  f32x4 acc0 = {0.f, 0.f, 0.f, 0.f};
  f32x4 acc1 = {0.f, 0.f, 0.f, 0.f};

  #pragma unroll 1
  for (int s = 0; s < 8; ++s){
    const int sch = s0 + s;
    const int ja = j0[s], jb = j1[s];
    const int a0h = ((ja >> 4) << 10) + ((ja & 15) << 5) + ge;
    const int a1h = ((jb >> 4) << 10) + ((jb & 15) << 5) + ge;
    const bf16x8 ah0 = *reinterpret_cast<const bf16x8*>(cbhl + a0h);
    const bf16x8 al0 = *reinterpret_cast<const bf16x8*>(cbhl + a0h + 512);
    const bf16x8 ah1 = *reinterpret_cast<const bf16x8*>(cbhl + a1h);
    const bf16x8 al1 = *reinterpret_cast<const bf16x8*>(cbhl + a1h + 512);
    const int wb = (((sch << 7) + o0 + lc) << 6) + ge;
    const bf16x8 bh = *reinterpret_cast<const bf16x8*>(whl + wb);
    const bf16x8 bl = *reinterpret_cast<const bf16x8*>(whl + wb + 32);

    acc0 = __builtin_amdgcn_mfma_f32_16x16x32_bf16(ah0, bh, acc0, 0, 0, 0);
    acc0 = __builtin_amdgcn_mfma_f32_16x16x32_bf16(ah0, bl, acc0, 0, 0, 0);
    acc0 = __builtin_amdgcn_mfma_f32_16x16x32_bf16(al0, bh, acc0, 0, 0, 0);
    acc1 = __builtin_amdgcn_mfma_f32_16x16x32_bf16(ah1, bh, acc1, 0, 0, 0);
    acc1 = __builtin_amdgcn_mfma_f32_16x16x32_bf16(ah1, bl, acc1, 0, 0, 0);
    acc1 = __builtin_amdgcn_mfma_f32_16x16x32_bf16(al1, bh, acc1, 0, 0, 0);
  }

  const int obase = ((b*128 + o0 + lc) << 8) + p0 + (gq << 2);
  #pragma unroll
  for (int r = 0; r < 4; ++r){
    atomicAdd(&outF[obase + r],      acc0[r]);
    atomicAdd(&outF[obase + 16 + r], acc1[r]);
  }
}

// ---------------- per-sample LN stats over silu(h_half) ----------------
__global__ __launch_bounds__(256) void stats_rw(const float* __restrict__ h, float* __restrict__ stats){
  const int b = blockIdx.x >> 1, half = blockIdx.x & 1;
  const float* base = h + ((b*256 + half*128) << 8);
  float s = 0.f, s2 = 0.f;
  for (int i = threadIdx.x; i < 32768; i += 256){
    float a = silu_rw(base[i]);
    s += a; s2 += a*a;
  }
  __shared__ float sh[2][256];
  sh[0][threadIdx.x] = s; sh[1][threadIdx.x] = s2;
  __syncthreads();
  for (int st = 128; st > 0; st >>= 1){
    if (threadIdx.x < st){
      sh[0][threadIdx.x] += sh[0][threadIdx.x + st];
      sh[1][threadIdx.x] += sh[1][threadIdx.x + st];
    }
    __syncthreads();
  }
  if (threadIdx.x == 0){
    float mu  = sh[0][0] * (1.f/32768.f);
    float var = sh[1][0] * (1.f/32768.f) - mu*mu;
    stats[half*32 + b]      = mu;
    stats[half*32 + 16 + b] = 1.f / sqrtf(var + 1e-5f);
  }
}

// ---------------- LN apply ----------------
__global__ __launch_bounds__(256) void ln_rw(const float* __restrict__ h,
    const void* lwp, const void* lbp, const void* lwn, const void* lbn,
    const float* __restrict__ stats, const float* __restrict__ flags,
    float* __restrict__ lnp, float* __restrict__ lnn){
  const int f32m = (flags[0] != 0.f);
  int i = blockIdx.x * 256 + threadIdx.x;
  int b = i >> 16, c = (i >> 8) & 255, p = i & 255;
  float a = silu_rw(h[i]);
  if (c < 128){
    float v = (a - stats[b]) * stats[16 + b] * ldv_rw(lwp, (c << 8) + p, f32m) + ldv_rw(lbp, (c << 8) + p, f32m);
    lnp[((b*128 + c) << 8) + p] = v;
  } else {
    int cc = c - 128;
    float v = (a - stats[32 + b]) * stats[48 + b] * ldv_rw(lwn, (cc << 8) + p, f32m) + ldv_rw(lbn, (cc << 8) + p, f32m);
    lnn[((b*128 + cc) << 8) + p] = v;
  }
}

// ---------------- VQ search v6b (r18-exact, proven 59us) ------------------
template<int LEVELS>
__global__ __launch_bounds__(512, 4) void quantm_rw(
    const float* __restrict__ z, const short* __restrict__ cbhl,
    const float* __restrict__ cbn, const float* __restrict__ cmaxp,
    int* __restrict__ idxout, float* __restrict__ lossacc,
    int* __restrict__ cnt, int* __restrict__ list, int b_base)
{
  __shared__ float mgm1[4][4][8], mgm2[4][4][8];
  __shared__ int   mgj [4][4][8];
  __shared__ float red[4];

  const int tid  = threadIdx.x;
  const int lane = tid & 63, wid = tid >> 6;
  const int lc = lane & 15, gq = lane >> 4;
  const int pg = wid & 3, ch = wid >> 2;    // pixel group, code half
  const int bid  = blockIdx.x;
  const int bl   = bid >> 6;                // local batch
  const int rest = bid & 63;
  const int g = rest >> 1, half = rest & 1;
  int cb, wbase, wstep;
  if (LEVELS == 4){ cb = (g & 3)*8 + (g >> 2); wbase = (g >> 2)*1024 + (g & 3); wstep = 4; }
  else            { cb = g;                    wbase = g << 8;                  wstep = 1; }
  const int pb = half*128 + pg*32;

  // ---- load z rows, build -2z hi/lo bf16 A-fragments, partial |z|^2 ----
  bf16x8 ah0, al0, ah1, al1;
  float zn0 = 0.f, zn1 = 0.f;
  const int zoff = (((bl << 10) + cb) << 8) + pb + lc;
  const int e0 = gq << 3;
  #pragma unroll
  for (int i = 0; i < 8; ++i){
    const int zo = zoff + ((e0 + i) << 13);
    const float z0 = z[zo];
    const float z1 = z[zo + 16];
    zn0 += z0*z0; zn1 += z1*z1;
    const float s0 = -2.f*z0, s1 = -2.f*z1;
    const unsigned short h0 = f2bf_rw(s0);
    const unsigned short h1 = f2bf_rw(s1);
    ah0[i] = (short)h0; al0[i] = (short)f2bf_rw(s0 - bf2f_rw(h0));
    ah1[i] = (short)h1; al1[i] = (short)f2bf_rw(s1 - bf2f_rw(h1));
  }
  zn0 += __shfl_xor(zn0, 16); zn0 += __shfl_xor(zn0, 32);   // full zn for row lc
  zn1 += __shfl_xor(zn1, 16); zn1 += __shfl_xor(zn1, 32);

  float m1[8], m2[8]; int j1[8];
  #pragma unroll
  for (int s = 0; s < 8; ++s){ m1[s] = __builtin_inff(); m2[s] = __builtin_inff(); j1[s] = 0; }

  // interleaved table: wave's tiles T = ch*32 + t; shorts base:
  const short* bp  = cbhl + (ch << 15) + (lc << 5) + (gq << 3);
  const float* cnp = cbn + (ch << 9) + lc;

  bf16x8 bh  = *reinterpret_cast<const bf16x8*>(bp);
  bf16x8 blo = *reinterpret_cast<const bf16x8*>(bp + 512);
  float  cnv = cnp[0];

  #pragma unroll 2
  for (int t = 0; t < 32; ++t){
    const int tn = (t < 31) ? t + 1 : 31;      // clamped prefetch index
    const bf16x8 bhn  = *reinterpret_cast<const bf16x8*>(bp + (tn << 10));
    const bf16x8 blon = *reinterpret_cast<const bf16x8*>(bp + (tn << 10) + 512);
    const float  cnn  = cnp[tn << 4];

    f32x4 a0 = {cnv, cnv, cnv, cnv};
    f32x4 a1 = {cnv, cnv, cnv, cnv};
    a0 = __builtin_amdgcn_mfma_f32_16x16x32_bf16(ah0, bh,  a0, 0, 0, 0);
    a0 = __builtin_amdgcn_mfma_f32_16x16x32_bf16(ah0, blo, a0, 0, 0, 0);
    a0 = __builtin_amdgcn_mfma_f32_16x16x32_bf16(al0, bh,  a0, 0, 0, 0);
    a1 = __builtin_amdgcn_mfma_f32_16x16x32_bf16(ah1, bh,  a1, 0, 0, 0);
    a1 = __builtin_amdgcn_mfma_f32_16x16x32_bf16(ah1, blo, a1, 0, 0, 0);
    a1 = __builtin_amdgcn_mfma_f32_16x16x32_bf16(al1, bh,  a1, 0, 0, 0);

    const int jc = (((ch << 5) + t) << 4) + lc;
    #pragma unroll
    for (int r = 0; r < 4; ++r){
      const float d0 = a0[r];
      m2[r] = __builtin_amdgcn_fmed3f(d0, m1[r], m2[r]);
      const bool t0 = d0 < m1[r];
      j1[r] = t0 ? jc : j1[r]; m1[r] = t0 ? d0 : m1[r];
      const float d1 = a1[r];
      m2[4+r] = __builtin_amdgcn_fmed3f(d1, m1[4+r], m2[4+r]);
      const bool t1 = d1 < m1[4+r];
      j1[4+r] = t1 ? jc : j1[4+r]; m1[4+r] = t1 ? d1 : m1[4+r];
    }
    bh = bhn; blo = blon; cnv = cnn;
  }

  // ---- 16-lane top-2 merge (cols of each row live in one 16-lane group) ----
  #pragma unroll
  for (int k = 1; k < 16; k <<= 1){
    #pragma unroll
    for (int s = 0; s < 8; ++s){
      const float om1 = __shfl_xor(m1[s], k);
      const float om2 = __shfl_xor(m2[s], k);
      const int   oj  = __shfl_xor(j1[s], k);
      m2[s] = fminf(fminf(m2[s], om2), fmaxf(m1[s], om1));
      const bool tk = (om1 < m1[s]) || (om1 == m1[s] && oj < j1[s]);
      m1[s] = tk ? om1 : m1[s];
      j1[s] = tk ? oj  : j1[s];
    }
  }

  // ---- cross-wave merge: upper code-half -> LDS, lower merges ----
  if (wid >= 4 && lc == 0){
    #pragma unroll
    for (int s = 0; s < 8; ++s){
      mgm1[wid-4][gq][s] = m1[s];
      mgm2[wid-4][gq][s] = m2[s];
      mgj [wid-4][gq][s] = j1[s];
    }
  }
  __syncthreads();
  if (wid < 4){
    #pragma unroll
    for (int s = 0; s < 8; ++s){
      const float om1 = mgm1[wid][gq][s];
      const float om2 = mgm2[wid][gq][s];
      const int   oj  = mgj [wid][gq][s];
      m2[s] = fminf(fminf(m2[s], om2), fmaxf(m1[s], om1));
      const bool tk = om1 < m1[s];       // tie keeps lower half (smaller j)
      m1[s] = tk ? om1 : m1[s];
      j1[s] = tk ? oj  : j1[s];
    }

    // ---- finalize: cert test, idx write, loss, uncertain list ----
    const float cmax = cmaxp[0];
    float lossw = 0.f;
    #pragma unroll
    for (int f = 0; f < 2; ++f){
      #pragma unroll
      for (int r = 0; r < 4; ++r){
        const int s = f*4 + r;
        const int vrow = (gq << 2) + r;
        const float znv = __shfl(f == 0 ? zn0 : zn1, vrow);
        if (lc == 0){
          const int p  = pb + f*16 + vrow;
          const int gi = (b_base + bl)*8192 + wbase + p*wstep;
          idxout[gi] = j1[s];                    // provisional if uncertain
          const float eb = fmaf(2.0e-6f, znv, 3.0e-4f * sqrtf(znv) * cmax);
          if (m2[s] - m1[s] > eb){
            lossw += znv + m1[s];
          } else {
            const int pos = atomicAdd(cnt, 1);
            if (pos < 131072) list[pos] = (((bl << 5) | g) << 8) | p;
          }
        }
      }
    }
    lossw += __shfl_xor(lossw, 16);
    lossw += __shfl_xor(lossw, 32);
    if (lane == 0) red[wid] = lossw;
  }
  __syncthreads();
  if (tid == 0) atomicAdd(lossacc, red[0] + red[1] + red[2] + red[3]);
}

// ---------------- np-bit-exact f32 fallback for uncertain vectors ----------
template<int LEVELS>
__global__ __launch_bounds__(256) void fb_rw(
    const float* __restrict__ z, const float* __restrict__ cb32,
    const float* __restrict__ cbn, const int* __restrict__ cnt,
    const int* __restrict__ list, int* __restrict__ idxout,
    float* __restrict__ lossacc, int b_base)
{
  const int lane = threadIdx.x & 63;
  const int wv = (blockIdx.x << 2) | (threadIdx.x >> 6);
  const int nw = gridDim.x << 2;
  int n = cnt[0];
  if (n > 131072) n = 131072;
  for (int it = wv; it < n; it += nw){
    const int id = list[it];
    const int p = id & 255, g = (id >> 8) & 31, bl = id >> 13;
    int cb, w;
    if (LEVELS == 4){ cb = (g & 3)*8 + (g >> 2); w = (g >> 2)*1024 + (p << 2) + (g & 3); }
    else            { cb = g;                    w = (g << 8) + p; }
    const int zoff = (((bl << 10) + cb) << 8) + p;
    float myz = 0.f;
    if (lane < 32) myz = z[zoff + (lane << 13)];
    // broadcast z to all lanes (register array; compile-time indexed)
    float zb[32];
    #pragma unroll
    for (int e = 0; e < 32; ++e) zb[e] = __shfl(myz, e);
    // zn: sequential ascending fmaf (matches np's accumulation order)
    float zn = 0.f;
    #pragma unroll
    for (int e = 0; e < 32; ++e) zn = fmaf(zb[e], zb[e], zn);
    float bd = __builtin_inff(); int bj = 0;
    #pragma unroll 4
    for (int jj = 0; jj < 16; ++jj){
      const int j = (jj << 6) + lane;
      const float4* c4 = reinterpret_cast<const float4*>(cb32 + (j << 5));
      float dot = 0.f;
      #pragma unroll
      for (int e4 = 0; e4 < 8; ++e4){
        const float4 cv = c4[e4];
        dot = fmaf(zb[(e4 << 2) + 0], cv.x, dot);
        dot = fmaf(zb[(e4 << 2) + 1], cv.y, dot);
        dot = fmaf(zb[(e4 << 2) + 2], cv.z, dot);
        dot = fmaf(zb[(e4 << 2) + 3], cv.w, dot);
      }
      const float d = (zn - 2.f*dot) + cbn[j];   // np's exact formula/rounding
      if (d < bd){ bd = d; bj = j; }
    }
    #pragma unroll
    for (int k = 1; k < 64; k <<= 1){
      const float od = __shfl_xor(bd, k);
      const int   oj = __shfl_xor(bj, k);
      if (od < bd || (od == bd && oj < bj)){ bd = od; bj = oj; }
    }
    if (lane == 0){
      idxout[(b_base + bl)*8192 + w] = bj;
      atomicAdd(lossacc, bd);                    // bd == |z-c|^2 (includes zn)
    }
  }
}

// ---------------- zq_p output (f32) ----------------
__global__ __launch_bounds__(256) void zqout_rw(const int* __restrict__ idxp,
    const float* __restrict__ cb32, float* __restrict__ out){
  int t = blockIdx.x * 256 + threadIdx.x;
  int l = t & 3, n = (t >> 2) & 2047, e = (t >> 13) & 31, b = t >> 18;
  int id = idxp[b*8192 + (n << 2) + l];
  out[t] = cb32[((id & 1023) << 5) + e];
}

// ---------------- zero hcat accum ----------------
__global__ __launch_bounds__(256) void zero_rw(float* __restrict__ p){
  p[blockIdx.x * 256 + threadIdx.x] = 0.f;
}

// ---------------- loss finalize ----------------
__global__ void loss_rw(const float* __restrict__ lossacc, float* __restrict__ out){
  if (threadIdx.x == 0 && blockIdx.x == 0)
    out[0] = 1.25f * (lossacc[0] + lossacc[1]) * (1.f/4194304.f);
}

extern "C" void kernel_launch(void* const* d_in, const int* in_sizes, int n_in,
                              void* d_out, int out_size, void* d_ws, size_t ws_size,
                              hipStream_t stream){
  (void)in_sizes; (void)n_in; (void)out_size;
  const void* x   = d_in[0];
  const void* ciw = d_in[1];
  const void* cib = d_in[2];
  const void* lwp = d_in[3];
  const void* lbp = d_in[4];
  const void* wpi = d_in[5];
  const void* bpi = d_in[6];
  const void* wpo = d_in[7];
  const void* bpo = d_in[8];
  const void* lwn = d_in[9];
  const void* lbn = d_in[10];
  const void* wni = d_in[11];
  const void* bni = d_in[12];
  const void* wno = d_in[13];
  const void* bno = d_in[14];
  const void* cbk = d_in[15];
  const void* cow = d_in[16];
  const void* cob = d_in[17];

  float* ws    = (float*)d_ws;
  float* flags = ws + FLAGS_OFF;
  float* loss  = ws + LOSS_OFF;
  float* stats = ws + STATS_OFF;
  float* cmaxp = ws + CMAX_OFF;
  float* cb32  = ws + CB32_OFF;
  float* cbn   = ws + CBN_OFF;
  int*   cnts  = (int*)(ws + CNT_OFF);
  int*   idxp  = (int*)(ws + IDXP_OFF);
  int*   idxn  = (int*)(ws + IDXN_OFF);
  short* cbhl  = (short*)(ws + CBHL_OFF);
  int*   list  = (int*)(ws + LIST_OFF);
  float* R2    = ws + R2_OFF;
  float* R3    = ws + R3_OFF;
  float* R1    = ws + R1_OFF;
  short* whlp  = (short*)(ws + R1_OFF);            // R1 dead after quant loops
  short* whln  = (short*)(ws + R1_OFF + 131072);

  float* outO = (float*)d_out;
  float* outL = outO + 1048576;
  float* outZ = outO + 1048577;

  const size_t wsf = ws_size / 4;
  int CS = 4;
  if      (wsf >= (size_t)R1_OFF + 16u*262144u) CS = 16;
  else if (wsf >= (size_t)R1_OFF +  8u*262144u) CS = 8;

  detect_rw<<<1, 256, 0, stream>>>(cbk, ws);
  cbprep_rw<<<4, 256, 0, stream>>>(cbk, flags, cb32, cbn, cbhl, cmaxp);
  // h = conv_in(silu(x)) -> R1
  gemm2_rw<256,2,false,false,0><<<dim3(128,4), 256, 0, stream>>>(
      nullptr, nullptr, x, ciw, cib, nullptr, nullptr, nullptr, nullptr,
      R1, flags, 256, 256, 0, 0, 0, 0);
  stats_rw<<<32, 256, 0, stream>>>(R1, stats);
  ln_rw<<<4096, 256, 0, stream>>>(R1, lwp, lbp, lwn, lbn, stats, flags, R2, R3);
  // phylo: z chunks (R2 -> R1), MFMA quantize + np-exact fallback
  {
    int ci = 0;
    for (int c = 0; c < 16; c += CS, ++ci){
      gemm2_rw<128,0,true,false,0><<<dim3(CS*8,16), 256, 0, stream>>>(
          R2, nullptr, nullptr, wpi, bpi, nullptr, nullptr, nullptr, nullptr,
          R1, flags, 128, 1024, 0, c, 0, c);
      quantm_rw<4><<<CS*64, 512, 0, stream>>>(R1, cbhl, cbn, cmaxp,
                                              idxp, loss + 0, cnts + ci, list, c);
      fb_rw<4><<<640, 256, 0, stream>>>(R1, cb32, cbn, cnts + ci, list,
                                        idxp, loss + 0, c);
    }
  }
  // non-phylo
  {
    int ci = 4;
    for (int c = 0; c < 16; c += CS, ++ci){
      gemm2_rw<128,0,true,false,0><<<dim3(CS*8,16), 256, 0, stream>>>(
          R3, nullptr, nullptr, wni, bni, nullptr, nullptr, nullptr, nullptr,
          R1, flags, 128, 1024, 0, c, 0, c);
      quantm_rw<1><<<CS*64, 512, 0, stream>>>(R1, cbhl, cbn, cmaxp,
                                              idxn, loss + 1, cnts + ci, list, c);
      fb_rw<1><<<640, 256, 0, stream>>>(R1, cb32, cbn, cnts + ci, list,
                                        idxn, loss + 1, c);
    }
  }
  zqout_rw<<<16384, 256, 0, stream>>>(idxp, cb32, outZ);
  // hcat accum := 0 (R2 and R3 are contiguous: 4096*256 = 1048576 floats)
  zero_rw<<<4096, 256, 0, stream>>>(R2);
  // W -> MFMA-ready hi/lo fragments (R1 region now dead)
  wprep_rw<<<dim3(16, 2), 256, 0, stream>>>(wpo, wno, flags, whlp, whln);
  // hout_p / hout_n: gather-free-fragment MFMA, sch-split x4, atomic accum
  houtm2_rw<4><<<dim3(128, 2, 4), 256, 0, stream>>>(idxp, cbhl, whlp, R2);
  houtm2_rw<1><<<dim3(128, 2, 4), 256, 0, stream>>>(idxn, cbhl, whln, R3);
  // out = conv_out(silu(hcat + hout_bias))
  gemm2_rw<256,5,false,false,0><<<dim3(128,4), 256, 0, stream>>>(
      R2, R3, nullptr, cow, cob, bpo, bno, nullptr, nullptr,
      outO, flags, 256, 256, 0, 0, 0, 0);
  loss_rw<<<1, 64, 0, stream>>>(loss, outL);
}

// Round 11
// 561.429 us; speedup vs baseline: 1.0988x; 1.0124x over previous
//
#include <hip/hip_runtime.h>
#include <hip/hip_bf16.h>

// Round 23: (1) wprep v2 — r22's wprep was 32 blocks x stride-128B scalar
// reads (latency-dead like r17's fb, est 15-20us); now 256 blocks,
// coalesced reads, ~2us. (2) gemm2 4x4 re-tile: 64px x 64out per block,
// 16 FMA per 32B LDS read (was 8 per 24B), b128 As reads, float4 stores.
// ROUNDING-FREE: per-output ascending-k fmaf chain unchanged -> all gemm
// outputs bit-identical (z bit-match to np BLAS preserved — that match is
// what keeps argmin agreeing with np; r13 lesson). quantm r18-exact,
// houtm2 r22-exact. Predicted 568 -> ~510.
// Outputs (f32): out[1048576] | loss[1] | zq_p[4194304].

typedef float f32x4  __attribute__((ext_vector_type(4)));
typedef short bf16x8 __attribute__((ext_vector_type(8)));

__device__ __forceinline__ float silu_rw(float x){ return x / (1.f + expf(-x)); }
__device__ __forceinline__ float b2f_rw(__hip_bfloat16 v){ return __bfloat162float(v); }
__device__ __forceinline__ float ldv_rw(const void* p, int i, int f32m){
  if (f32m) return ((const float*)p)[i];
  return b2f_rw(((const __hip_bfloat16*)p)[i]);
}
__device__ __forceinline__ unsigned short f2bf_rw(float x){   // f32 -> bf16 RNE
  unsigned u = __float_as_uint(x);
  unsigned r = ((u >> 16) & 1u) + 0x7FFFu;
  return (unsigned short)((u + r) >> 16);
}
__device__ __forceinline__ float bf2f_rw(unsigned short h){
  return __uint_as_float(((unsigned)h) << 16);
}

// ---------------- workspace layout (float offsets) ----------------
#define FLAGS_OFF 0
#define LOSS_OFF  4
#define STATS_OFF 8
#define CNT_OFF   72         // 8 ints: fallback counters per chunk
#define CMAX_OFF  80         // max_j |c_j| (f32)
#define CB32_OFF  128        // 1024x32 f32
#define CBN_OFF   32896      // 1024
#define IDXP_OFF  33984      // 131072 int
#define IDXN_OFF  165056     // 131072 int
#define CBHL_OFF  296192     // interleaved hi/lo bf16 table (32768 f32 slots)
#define LIST_OFF  328960     // 131072 int (uncertain list, reused per chunk)
#define R2_OFF    460032     // lnp -> hcat_p accum (524288)
#define R3_OFF    984320     // lnn -> hcat_n accum (524288)
#define R1_OFF    1508608    // h (1048576) / z chunks (CS*262144) / whl tables

// ---------------- input dtype probe + zero accumulators ----------------
__global__ __launch_bounds__(256) void detect_rw(const void* cbv, float* wsb){
  __shared__ int bad;
  if (threadIdx.x == 0) bad = 0;
  __syncthreads();
  const unsigned short* u = (const unsigned short*)cbv;
  int local = 0;
  for (int i = threadIdx.x; i < 32768; i += 256){
    unsigned e = (u[i] >> 7) & 0xFF;
    if (e >= 126) local = 1;
  }
  if (local) bad = 1;
  __syncthreads();
  if (threadIdx.x == 0){
    wsb[FLAGS_OFF] = bad ? 1.f : 0.f;   // 1.0 => inputs are f32
    wsb[LOSS_OFF] = 0.f; wsb[LOSS_OFF + 1] = 0.f;
    int* c = (int*)(wsb + CNT_OFF);
    #pragma unroll
    for (int k = 0; k < 8; ++k) c[k] = 0;
    wsb[CMAX_OFF] = 0.f;
  }
}

// ------ codebook -> f32 + |c|^2 + interleaved bf16 hi/lo tile table ------
// Tile T = j>>4 occupies shorts [T*1024, T*1024+1024): hi of code j elem e
// at T*1024 + (j&15)*32 + e, lo at +512.
__global__ __launch_bounds__(256) void cbprep_rw(const void* cbv, const float* flags,
                                                 float* cb32, float* cbn,
                                                 short* cbhl, float* cmaxp){
  const int f32m = (flags[0] != 0.f);
  int j = blockIdx.x * 256 + threadIdx.x;
  if (j < 1024){
    float s = 0.f;
    const int tb = ((j >> 4) << 10) + ((j & 15) << 5);
    for (int e = 0; e < 32; ++e){
      float v = ldv_rw(cbv, j*32 + e, f32m);
      cb32[j*32 + e] = v;
      unsigned short h = f2bf_rw(v);
      cbhl[tb + e]       = (short)h;
      cbhl[tb + e + 512] = (short)f2bf_rw(v - bf2f_rw(h));
      s += v*v;
    }
    cbn[j] = s;
    atomicMax((int*)cmaxp, __float_as_int(sqrtf(s)));  // positive floats: int-bit monotone
  }
}

// -------- gemm2 v2 (4x4 re-tile): 64px x 64out tiles, bit-identical --------
// Per-output accumulation: ascending-k sequential fmaf (UNCHANGED order vs
// r11 — outputs bit-identical; only the schedule/tiling changed).
template<int KCH, int INMODE, bool OUTSILU, int LEVELS>
__global__ __launch_bounds__(256) void gemm2_rw(
    const float* __restrict__ inF, const float* __restrict__ inF2,
    const void* __restrict__ inV,
    const void* __restrict__ W, const void* __restrict__ biasO,
    const void* __restrict__ sbA, const void* __restrict__ sbB,
    float* __restrict__ outF, const float* __restrict__ flags,
    int KDIM, int OUTC, int o_off, int b_base, int ib_sub, int ob_sub)
{
  __shared__ float As[32][64];
  __shared__ float Bs[32][68];

  const int f32m = (flags[0] != 0.f);
  const int t  = threadIdx.x;
  const int q0 = (blockIdx.x << 6) + (b_base << 8);
  const int b  = q0 >> 8;
  const int p0 = q0 & 255;              // 64-aligned pixel tile
  const int o0 = blockIdx.y << 6;
  const int k0base = blockIdx.z * KCH;
  const int tx = t & 15, ty = t >> 4;
  float acc[4][4] = {};

  const int sch = t >> 3, spx = (t & 7) << 3;   // 8 px per staging thread

  for (int kc = 0; kc < KCH; kc += 32){
    const int k0 = k0base + kc;
    if constexpr (INMODE == 0){
      const float4* src = reinterpret_cast<const float4*>(
          &inF[(((b - ib_sub)*KDIM + k0 + sch) << 8) + p0 + spx]);
      *reinterpret_cast<float4*>(&As[sch][spx])     = src[0];
      *reinterpret_cast<float4*>(&As[sch][spx + 4]) = src[1];
    } else if constexpr (INMODE == 2){
      if (f32m){
        const float* xf = (const float*)inV;
        const float4* src = reinterpret_cast<const float4*>(
            &xf[((b*KDIM + k0 + sch) << 8) + p0 + spx]);
        float4 v0 = src[0], v1 = src[1];
        v0.x = silu_rw(v0.x); v0.y = silu_rw(v0.y); v0.z = silu_rw(v0.z); v0.w = silu_rw(v0.w);
        v1.x = silu_rw(v1.x); v1.y = silu_rw(v1.y); v1.z = silu_rw(v1.z); v1.w = silu_rw(v1.w);
        *reinterpret_cast<float4*>(&As[sch][spx])     = v0;
        *reinterpret_cast<float4*>(&As[sch][spx + 4]) = v1;
      } else {
        const __hip_bfloat16* xb = (const __hip_bfloat16*)inV;
        const int off = ((b*KDIM + k0 + sch) << 8) + p0 + spx;
        #pragma unroll
        for (int j = 0; j < 8; ++j) As[sch][spx + j] = silu_rw(b2f_rw(xb[off + j]));
      }
    } else { // INMODE 5
      const float* src = (k0 < 128) ? inF : inF2;
      const void* sb   = (k0 < 128) ? sbA : sbB;
      const int kh = k0 & 127;
      const float bb = ldv_rw(sb, kh + sch, f32m);
      const float4* sp = reinterpret_cast<const float4*>(
          &src[((b*128 + kh + sch) << 8) + p0 + spx]);
      float4 v0 = sp[0], v1 = sp[1];
      v0.x = silu_rw(v0.x + bb); v0.y = silu_rw(v0.y + bb);
      v0.z = silu_rw(v0.z + bb); v0.w = silu_rw(v0.w + bb);
      v1.x = silu_rw(v1.x + bb); v1.y = silu_rw(v1.y + bb);
      v1.z = silu_rw(v1.z + bb); v1.w = silu_rw(v1.w + bb);
      *reinterpret_cast<float4*>(&As[sch][spx])     = v0;
      *reinterpret_cast<float4*>(&As[sch][spx + 4]) = v1;
    }
    if (f32m){
      const float* Wf = (const float*)W;
      #pragma unroll
      for (int r = 0; r < 8; ++r){
        int ii = t + (r << 8); int oo = ii >> 5, cc = ii & 31;
        Bs[cc][oo] = Wf[(o0 + oo)*KDIM + k0 + cc];
      }
    } else {
      const __hip_bfloat16* Wb = (const __hip_bfloat16*)W;
      #pragma unroll
      for (int r = 0; r < 8; ++r){
        int ii = t + (r << 8); int oo = ii >> 5, cc = ii & 31;
        Bs[cc][oo] = b2f_rw(Wb[(o0 + oo)*KDIM + k0 + cc]);
      }
    }
    __syncthreads();
    #pragma unroll
    for (int kk = 0; kk < 32; ++kk){
      const float4 a = *reinterpret_cast<const float4*>(&As[kk][tx << 2]);
      const float4 w = *reinterpret_cast<const float4*>(&Bs[kk][ty << 2]);
      acc[0][0] = fmaf(w.x, a.x, acc[0][0]); acc[0][1] = fmaf(w.x, a.y, acc[0][1]);
      acc[0][2] = fmaf(w.x, a.z, acc[0][2]); acc[0][3] = fmaf(w.x, a.w, acc[0][3]);
      acc[1][0] = fmaf(w.y, a.x, acc[1][0]); acc[1][1] = fmaf(w.y, a.y, acc[1][1]);
      acc[1][2] = fmaf(w.y, a.z, acc[1][2]); acc[1][3] = fmaf(w.y, a.w, acc[1][3]);
      acc[2][0] = fmaf(w.z, a.x, acc[2][0]); acc[2][1] = fmaf(w.z, a.y, acc[2][1]);
      acc[2][2] = fmaf(w.z, a.z, acc[2][2]); acc[2][3] = fmaf(w.z, a.w, acc[2][3]);
      acc[3][0] = fmaf(w.w, a.x, acc[3][0]); acc[3][1] = fmaf(w.w, a.y, acc[3][1]);
      acc[3][2] = fmaf(w.w, a.z, acc[3][2]); acc[3][3] = fmaf(w.w, a.w, acc[3][3]);
    }
    __syncthreads();
  }
  #pragma unroll
  for (int i = 0; i < 4; ++i){
    const int o = o0 + (ty << 2) + i;
    const int base = (((b - ob_sub)*OUTC + o_off + o) << 8) + p0 + (tx << 2);
    const float bb = ldv_rw(biasO, o, f32m);
    float4 v;
    v.x = acc[i][0] + bb; v.y = acc[i][1] + bb;
    v.z = acc[i][2] + bb; v.w = acc[i][3] + bb;
    if constexpr (OUTSILU){
      v.x = silu_rw(v.x); v.y = silu_rw(v.y);
      v.z = silu_rw(v.z); v.w = silu_rw(v.w);
    }
    *reinterpret_cast<float4*>(&outF[base]) = v;
  }
}

// ------- wprep v2: W[o][e*32+sch] -> whl[sch][o][hi e| lo e], coalesced ----
// Grid (128, 2): block = output channel o (x which W). Thread t covers
// k = ch*256+t (coalesced reads); scattered u16 writes land in L2.
__global__ __launch_bounds__(256) void wprep_rw(const void* Wp, const void* Wn,
    const float* flags, short* whlp, short* whln){
  const int f32m = (flags[0] != 0.f);
  const void* W = blockIdx.y ? Wn : Wp;
  short* whl = blockIdx.y ? whln : whlp;
  const int o = blockIdx.x, t = threadIdx.x;
  #pragma unroll
  for (int ch = 0; ch < 4; ++ch){
    const int k = (ch << 8) + t;
    const int e = k >> 5, sch = k & 31;
    const float wv = ldv_rw(W, (o << 10) + k, f32m);
    const unsigned short h = f2bf_rw(wv);
    const int ob = (((sch << 7) + o) << 6) + e;
    whl[ob]      = (short)h;
    whl[ob + 32] = (short)f2bf_rw(wv - bf2f_rw(h));
  }
}

// ------------- houtm2 (r22-verified): gather-free-fragment MFMA ------------
template<int LEVELS>
__global__ __launch_bounds__(256, 4) void houtm2_rw(
    const int* __restrict__ idxin, const short* __restrict__ cbhl,
    const short* __restrict__ whl, float* __restrict__ outF)
{
  const int t = threadIdx.x;
  const int lane = t & 63, wid = t >> 6;
  const int lc = lane & 15, gq = lane >> 4;
  const int b  = blockIdx.x >> 3;
  const int p0 = (blockIdx.x & 7) << 5;
  const int o0 = (blockIdx.y << 6) + (wid << 4);
  const int s0 = blockIdx.z << 3;
  const int ge = gq << 3;

  int j0[8], j1[8];
  #pragma unroll
  for (int s = 0; s < 8; ++s){
    const int sch = s0 + s;
    int a0, a1;
    if (LEVELS == 4){
      const int l = sch >> 3, kp = sch & 7;
      a0 = b*8192 + (((kp << 8) + p0 + lc) << 2) + l;
      a1 = b*8192 + (((kp << 8) + p0 + 16 + lc) << 2) + l;
    } else {
      a0 = b*8192 + (sch << 8) + p0 + lc;
      a1 = a0 + 16;
    }
    j0[s] = idxin[a0] & 1023;
    j1[s] = idxin[a1] & 1023;
  }

  f32x4 acc0 = {0.f, 0.f, 0.f, 0.f};
  f32x4 acc1 = {0.f, 0.f, 0.f, 0.f};

  #pragma unroll 1
  for (int s = 0; s < 8; ++s){
    const int sch = s0 + s;
    const int ja = j0[s], jb = j1[s];
    const int a0h = ((ja >> 4) << 10) + ((ja & 15) << 5) + ge;
    const int a1h = ((jb >> 4) << 10) + ((jb & 15) << 5) + ge;
    const bf16x8 ah0 = *reinterpret_cast<const bf16x8*>(cbhl + a0h);
    const bf16x8 al0 = *reinterpret_cast<const bf16x8*>(cbhl + a0h + 512);
    const bf16x8 ah1 = *reinterpret_cast<const bf16x8*>(cbhl + a1h);
    const bf16x8 al1 = *reinterpret_cast<const bf16x8*>(cbhl + a1h + 512);
    const int wb = (((sch << 7) + o0 + lc) << 6) + ge;
    const bf16x8 bh = *reinterpret_cast<const bf16x8*>(whl + wb);
    const bf16x8 bl = *reinterpret_cast<const bf16x8*>(whl + wb + 32);

    acc0 = __builtin_amdgcn_mfma_f32_16x16x32_bf16(ah0, bh, acc0, 0, 0, 0);
    acc0 = __builtin_amdgcn_mfma_f32_16x16x32_bf16(ah0, bl, acc0, 0, 0, 0);
    acc0 = __builtin_amdgcn_mfma_f32_16x16x32_bf16(al0, bh, acc0, 0, 0, 0);
    acc1 = __builtin_amdgcn_mfma_f32_16x16x32_bf16(ah1, bh, acc1, 0, 0, 0);
    acc1 = __builtin_amdgcn_mfma_f32_16x16x32_bf16(ah1, bl, acc1, 0, 0, 0);
    acc1 = __builtin_amdgcn_mfma_f32_16x16x32_bf16(al1, bh, acc1, 0, 0, 0);
  }

  const int obase = ((b*128 + o0 + lc) << 8) + p0 + (gq << 2);
  #pragma unroll
  for (int r = 0; r < 4; ++r){
    atomicAdd(&outF[obase + r],      acc0[r]);
    atomicAdd(&outF[obase + 16 + r], acc1[r]);
  }
}

// ---------------- per-sample LN stats over silu(h_half) ----------------
__global__ __launch_bounds__(256) void stats_rw(const float* __restrict__ h, float* __restrict__ stats){
  const int b = blockIdx.x >> 1, half = blockIdx.x & 1;
  const float* base = h + ((b*256 + half*128) << 8);
  float s = 0.f, s2 = 0.f;
  for (int i = threadIdx.x; i < 32768; i += 256){
    float a = silu_rw(base[i]);
    s += a; s2 += a*a;
  }
  __shared__ float sh[2][256];
  sh[0][threadIdx.x] = s; sh[1][threadIdx.x] = s2;
  __syncthreads();
  for (int st = 128; st > 0; st >>= 1){
    if (threadIdx.x < st){
      sh[0][threadIdx.x] += sh[0][threadIdx.x + st];
      sh[1][threadIdx.x] += sh[1][threadIdx.x + st];
    }
    __syncthreads();
  }
  if (threadIdx.x == 0){
    float mu  = sh[0][0] * (1.f/32768.f);
    float var = sh[1][0] * (1.f/32768.f) - mu*mu;
    stats[half*32 + b]      = mu;
    stats[half*32 + 16 + b] = 1.f / sqrtf(var + 1e-5f);
  }
}

// ---------------- LN apply ----------------
__global__ __launch_bounds__(256) void ln_rw(const float* __restrict__ h,
    const void* lwp, const void* lbp, const void* lwn, const void* lbn,
    const float* __restrict__ stats, const float* __restrict__ flags,
    float* __restrict__ lnp, float* __restrict__ lnn){
  const int f32m = (flags[0] != 0.f);
  int i = blockIdx.x * 256 + threadIdx.x;
  int b = i >> 16, c = (i >> 8) & 255, p = i & 255;
  float a = silu_rw(h[i]);
  if (c < 128){
    float v = (a - stats[b]) * stats[16 + b] * ldv_rw(lwp, (c << 8) + p, f32m) + ldv_rw(lbp, (c << 8) + p, f32m);
    lnp[((b*128 + c) << 8) + p] = v;
  } else {
    int cc = c - 128;
    float v = (a - stats[32 + b]) * stats[48 + b] * ldv_rw(lwn, (cc << 8) + p, f32m) + ldv_rw(lbn, (cc << 8) + p, f32m);
    lnn[((b*128 + cc) << 8) + p] = v;
  }
}

// ---------------- VQ search v6b (r18-exact, proven 59us) ------------------
template<int LEVELS>
__global__ __launch_bounds__(512, 4) void quantm_rw(
    const float* __restrict__ z, const short* __restrict__ cbhl,
    const float* __restrict__ cbn, const float* __restrict__ cmaxp,
    int* __restrict__ idxout, float* __restrict__ lossacc,
    int* __restrict__ cnt, int* __restrict__ list, int b_base)
{
  __shared__ float mgm1[4][4][8], mgm2[4][4][8];
  __shared__ int   mgj [4][4][8];
  __shared__ float red[4];

  const int tid  = threadIdx.x;
  const int lane = tid & 63, wid = tid >> 6;
  const int lc = lane & 15, gq = lane >> 4;
  const int pg = wid & 3, ch = wid >> 2;    // pixel group, code half
  const int bid  = blockIdx.x;
  const int bl   = bid >> 6;                // local batch
  const int rest = bid & 63;
  const int g = rest >> 1, half = rest & 1;
  int cb, wbase, wstep;
  if (LEVELS == 4){ cb = (g & 3)*8 + (g >> 2); wbase = (g >> 2)*1024 + (g & 3); wstep = 4; }
  else            { cb = g;                    wbase = g << 8;                  wstep = 1; }
  const int pb = half*128 + pg*32;

  // ---- load z rows, build -2z hi/lo bf16 A-fragments, partial |z|^2 ----
  bf16x8 ah0, al0, ah1, al1;
  float zn0 = 0.f, zn1 = 0.f;
  const int zoff = (((bl << 10) + cb) << 8) + pb + lc;
  const int e0 = gq << 3;
  #pragma unroll
  for (int i = 0; i < 8; ++i){
    const int zo = zoff + ((e0 + i) << 13);
    const float z0 = z[zo];
    const float z1 = z[zo + 16];
    zn0 += z0*z0; zn1 += z1*z1;
    const float s0 = -2.f*z0, s1 = -2.f*z1;
    const unsigned short h0 = f2bf_rw(s0);
    const unsigned short h1 = f2bf_rw(s1);
    ah0[i] = (short)h0; al0[i] = (short)f2bf_rw(s0 - bf2f_rw(h0));
    ah1[i] = (short)h1; al1[i] = (short)f2bf_rw(s1 - bf2f_rw(h1));
  }
  zn0 += __shfl_xor(zn0, 16); zn0 += __shfl_xor(zn0, 32);   // full zn for row lc
  zn1 += __shfl_xor(zn1, 16); zn1 += __shfl_xor(zn1, 32);

  float m1[8], m2[8]; int j1[8];
  #pragma unroll
  for (int s = 0; s < 8; ++s){ m1[s] = __builtin_inff(); m2[s] = __builtin_inff(); j1[s] = 0; }

  // interleaved table: wave's tiles T = ch*32 + t; shorts base:
  const short* bp  = cbhl + (ch << 15) + (lc << 5) + (gq << 3);
  const float* cnp = cbn + (ch << 9) + lc;

  bf16x8 bh  = *reinterpret_cast<const bf16x8*>(bp);
  bf16x8 blo = *reinterpret_cast<const bf16x8*>(bp + 512);
  float  cnv = cnp[0];

  #pragma unroll 2
  for (int t = 0; t < 32; ++t){
    const int tn = (t < 31) ? t + 1 : 31;      // clamped prefetch index
    const bf16x8 bhn  = *reinterpret_cast<const bf16x8*>(bp + (tn << 10));
    const bf16x8 blon = *reinterpret_cast<const bf16x8*>(bp + (tn << 10) + 512);
    const float  cnn  = cnp[tn << 4];

    f32x4 a0 = {cnv, cnv, cnv, cnv};
    f32x4 a1 = {cnv, cnv, cnv, cnv};
    a0 = __builtin_amdgcn_mfma_f32_16x16x32_bf16(ah0, bh,  a0, 0, 0, 0);
    a0 = __builtin_amdgcn_mfma_f32_16x16x32_bf16(ah0, blo, a0, 0, 0, 0);
    a0 = __builtin_amdgcn_mfma_f32_16x16x32_bf16(al0, bh,  a0, 0, 0, 0);
    a1 = __builtin_amdgcn_mfma_f32_16x16x32_bf16(ah1, bh,  a1, 0, 0, 0);
    a1 = __builtin_amdgcn_mfma_f32_16x16x32_bf16(ah1, blo, a1, 0, 0, 0);
    a1 = __builtin_amdgcn_mfma_f32_16x16x32_bf16(al1, bh,  a1, 0, 0, 0);

    const int jc = (((ch << 5) + t) << 4) + lc;
    #pragma unroll
    for (int r = 0; r < 4; ++r){
      const float d0 = a0[r];
      m2[r] = __builtin_amdgcn_fmed3f(d0, m1[r], m2[r]);
      const bool t0 = d0 < m1[r];
      j1[r] = t0 ? jc : j1[r]; m1[r] = t0 ? d0 : m1[r];
      const float d1 = a1[r];
      m2[4+r] = __builtin_amdgcn_fmed3f(d1, m1[4+r], m2[4+r]);
      const bool t1 = d1 < m1[4+r];
      j1[4+r] = t1 ? jc : j1[4+r]; m1[4+r] = t1 ? d1 : m1[4+r];
    }
    bh = bhn; blo = blon; cnv = cnn;
  }

  // ---- 16-lane top-2 merge (cols of each row live in one 16-lane group) ----
  #pragma unroll
  for (int k = 1; k < 16; k <<= 1){
    #pragma unroll
    for (int s = 0; s < 8; ++s){
      const float om1 = __shfl_xor(m1[s], k);
      const float om2 = __shfl_xor(m2[s], k);
      const int   oj  = __shfl_xor(j1[s], k);
      m2[s] = fminf(fminf(m2[s], om2), fmaxf(m1[s], om1));
      const bool tk = (om1 < m1[s]) || (om1 == m1[s] && oj < j1[s]);
      m1[s] = tk ? om1 : m1[s];
      j1[s] = tk ? oj  : j1[s];
    }
  }

  // ---- cross-wave merge: upper code-half -> LDS, lower merges ----
  if (wid >= 4 && lc == 0){
    #pragma unroll
    for (int s = 0; s < 8; ++s){
      mgm1[wid-4][gq][s] = m1[s];
      mgm2[wid-4][gq][s] = m2[s];
      mgj [wid-4][gq][s] = j1[s];
    }
  }
  __syncthreads();
  if (wid < 4){
    #pragma unroll
    for (int s = 0; s < 8; ++s){
      const float om1 = mgm1[wid][gq][s];
      const float om2 = mgm2[wid][gq][s];
      const int   oj  = mgj [wid][gq][s];
      m2[s] = fminf(fminf(m2[s], om2), fmaxf(m1[s], om1));
      const bool tk = om1 < m1[s];       // tie keeps lower half (smaller j)
      m1[s] = tk ? om1 : m1[s];
      j1[s] = tk ? oj  : j1[s];
    }

    // ---- finalize: cert test, idx write, loss, uncertain list ----
    const float cmax = cmaxp[0];
    float lossw = 0.f;
    #pragma unroll
    for (int f = 0; f < 2; ++f){
      #pragma unroll
      for (int r = 0; r < 4; ++r){
        const int s = f*4 + r;
        const int vrow = (gq << 2) + r;
        const float znv = __shfl(f == 0 ? zn0 : zn1, vrow);
        if (lc == 0){
          const int p  = pb + f*16 + vrow;
          const int gi = (b_base + bl)*8192 + wbase + p*wstep;
          idxout[gi] = j1[s];                    // provisional if uncertain
          const float eb = fmaf(2.0e-6f, znv, 3.0e-4f * sqrtf(znv) * cmax);
          if (m2[s] - m1[s] > eb){
            lossw += znv + m1[s];
          } else {
            const int pos = atomicAdd(cnt, 1);
            if (pos < 131072) list[pos] = (((bl << 5) | g) << 8) | p;
          }
        }
      }
    }
    lossw += __shfl_xor(lossw, 16);
    lossw += __shfl_xor(lossw, 32);
    if (lane == 0) red[wid] = lossw;
  }
  __syncthreads();
  if (tid == 0) atomicAdd(lossacc, red[0] + red[1] + red[2] + red[3]);
}

// ---------------- np-bit-exact f32 fallback for uncertain vectors ----------
template<int LEVELS>
__global__ __launch_bounds__(256) void fb_rw(
    const float* __restrict__ z, const float* __restrict__ cb32,
    const float* __restrict__ cbn, const int* __restrict__ cnt,
    const int* __restrict__ list, int* __restrict__ idxout,
    float* __restrict__ lossacc, int b_base)
{
  const int lane = threadIdx.x & 63;
  const int wv = (blockIdx.x << 2) | (threadIdx.x >> 6);
  const int nw = gridDim.x << 2;
  int n = cnt[0];
  if (n > 131072) n = 131072;
  for (int it = wv; it < n; it += nw){
    const int id = list[it];
    const int p = id & 255, g = (id >> 8) & 31, bl = id >> 13;
    int cb, w;
    if (LEVELS == 4){ cb = (g & 3)*8 + (g >> 2); w = (g >> 2)*1024 + (p << 2) + (g & 3); }
    else            { cb = g;                    w = (g << 8) + p; }
    const int zoff = (((bl << 10) + cb) << 8) + p;
    float myz = 0.f;
    if (lane < 32) myz = z[zoff + (lane << 13)];
    // broadcast z to all lanes (register array; compile-time indexed)
    float zb[32];
    #pragma unroll
    for (int e = 0; e < 32; ++e) zb[e] = __shfl(myz, e);
    // zn: sequential ascending fmaf (matches np's accumulation order)
    float zn = 0.f;
    #pragma unroll
    for (int e = 0; e < 32; ++e) zn = fmaf(zb[e], zb[e], zn);
    float bd = __builtin_inff(); int bj = 0;
    #pragma unroll 4
    for (int jj = 0; jj < 16; ++jj){
      const int j = (jj << 6) + lane;
      const float4* c4 = reinterpret_cast<const float4*>(cb32 + (j << 5));
      float dot = 0.f;
      #pragma unroll
      for (int e4 = 0; e4 < 8; ++e4){
        const float4 cv = c4[e4];
        dot = fmaf(zb[(e4 << 2) + 0], cv.x, dot);
        dot = fmaf(zb[(e4 << 2) + 1], cv.y, dot);
        dot = fmaf(zb[(e4 << 2) + 2], cv.z, dot);
        dot = fmaf(zb[(e4 << 2) + 3], cv.w, dot);
      }
      const float d = (zn - 2.f*dot) + cbn[j];   // np's exact formula/rounding
      if (d < bd){ bd = d; bj = j; }
    }
    #pragma unroll
    for (int k = 1; k < 64; k <<= 1){
      const float od = __shfl_xor(bd, k);
      const int   oj = __shfl_xor(bj, k);
      if (od < bd || (od == bd && oj < bj)){ bd = od; bj = oj; }
    }
    if (lane == 0){
      idxout[(b_base + bl)*8192 + w] = bj;
      atomicAdd(lossacc, bd);                    // bd == |z-c|^2 (includes zn)
    }
  }
}

// ---------------- zq_p output (f32) ----------------
__global__ __launch_bounds__(256) void zqout_rw(const int* __restrict__ idxp,
    const float* __restrict__ cb32, float* __restrict__ out){
  int t = blockIdx.x * 256 + threadIdx.x;
  int l = t & 3, n = (t >> 2) & 2047, e = (t >> 13) & 31, b = t >> 18;
  int id = idxp[b*8192 + (n << 2) + l];
  out[t] = cb32[((id & 1023) << 5) + e];
}

// ---------------- zero hcat accum ----------------
__global__ __launch_bounds__(256) void zero_rw(float* __restrict__ p){
  p[blockIdx.x * 256 + threadIdx.x] = 0.f;
}

// ---------------- loss finalize ----------------
__global__ void loss_rw(const float* __restrict__ lossacc, float* __restrict__ out){
  if (threadIdx.x == 0 && blockIdx.x == 0)
    out[0] = 1.25f * (lossacc[0] + lossacc[1]) * (1.f/4194304.f);
}

extern "C" void kernel_launch(void* const* d_in, const int* in_sizes, int n_in,
                              void* d_out, int out_size, void* d_ws, size_t ws_size,
                              hipStream_t stream){
  (void)in_sizes; (void)n_in; (void)out_size;
  const void* x   = d_in[0];
  const void* ciw = d_in[1];
  const void* cib = d_in[2];
  const void* lwp = d_in[3];
  const void* lbp = d_in[4];
  const void* wpi = d_in[5];
  const void* bpi = d_in[6];
  const void* wpo = d_in[7];
  const void* bpo = d_in[8];
  const void* lwn = d_in[9];
  const void* lbn = d_in[10];
  const void* wni = d_in[11];
  const void* bni = d_in[12];
  const void* wno = d_in[13];
  const void* bno = d_in[14];
  const void* cbk = d_in[15];
  const void* cow = d_in[16];
  const void* cob = d_in[17];

  float* ws    = (float*)d_ws;
  float* flags = ws + FLAGS_OFF;
  float* loss  = ws + LOSS_OFF;
  float* stats = ws + STATS_OFF;
  float* cmaxp = ws + CMAX_OFF;
  float* cb32  = ws + CB32_OFF;
  float* cbn   = ws + CBN_OFF;
  int*   cnts  = (int*)(ws + CNT_OFF);
  int*   idxp  = (int*)(ws + IDXP_OFF);
  int*   idxn  = (int*)(ws + IDXN_OFF);
  short* cbhl  = (short*)(ws + CBHL_OFF);
  int*   list  = (int*)(ws + LIST_OFF);
  float* R2    = ws + R2_OFF;
  float* R3    = ws + R3_OFF;
  float* R1    = ws + R1_OFF;
  short* whlp  = (short*)(ws + R1_OFF);            // R1 dead after quant loops
  short* whln  = (short*)(ws + R1_OFF + 131072);

  float* outO = (float*)d_out;
  float* outL = outO + 1048576;
  float* outZ = outO + 1048577;

  const size_t wsf = ws_size / 4;
  int CS = 4;
  if      (wsf >= (size_t)R1_OFF + 16u*262144u) CS = 16;
  else if (wsf >= (size_t)R1_OFF +  8u*262144u) CS = 8;

  detect_rw<<<1, 256, 0, stream>>>(cbk, ws);
  cbprep_rw<<<4, 256, 0, stream>>>(cbk, flags, cb32, cbn, cbhl, cmaxp);
  // h = conv_in(silu(x)) -> R1   (64px x 64out tiles)
  gemm2_rw<256,2,false,0><<<dim3(64,4), 256, 0, stream>>>(
      nullptr, nullptr, x, ciw, cib, nullptr, nullptr,
      R1, flags, 256, 256, 0, 0, 0, 0);
  stats_rw<<<32, 256, 0, stream>>>(R1, stats);
  ln_rw<<<4096, 256, 0, stream>>>(R1, lwp, lbp, lwn, lbn, stats, flags, R2, R3);
  // phylo: z chunks (R2 -> R1), MFMA quantize + np-exact fallback
  {
    int ci = 0;
    for (int c = 0; c < 16; c += CS, ++ci){
      gemm2_rw<128,0,true,0><<<dim3(CS*4,16), 256, 0, stream>>>(
          R2, nullptr, nullptr, wpi, bpi, nullptr, nullptr,
          R1, flags, 128, 1024, 0, c, 0, c);
      quantm_rw<4><<<CS*64, 512, 0, stream>>>(R1, cbhl, cbn, cmaxp,
                                              idxp, loss + 0, cnts + ci, list, c);
      fb_rw<4><<<640, 256, 0, stream>>>(R1, cb32, cbn, cnts + ci, list,
                                        idxp, loss + 0, c);
    }
  }
  // non-phylo
  {
    int ci = 4;
    for (int c = 0; c < 16; c += CS, ++ci){
      gemm2_rw<128,0,true,0><<<dim3(CS*4,16), 256, 0, stream>>>(
          R3, nullptr, nullptr, wni, bni, nullptr, nullptr,
          R1, flags, 128, 1024, 0, c, 0, c);
      quantm_rw<1><<<CS*64, 512, 0, stream>>>(R1, cbhl, cbn, cmaxp,
                                              idxn, loss + 1, cnts + ci, list, c);
      fb_rw<1><<<640, 256, 0, stream>>>(R1, cb32, cbn, cnts + ci, list,
                                        idxn, loss + 1, c);
    }
  }
  zqout_rw<<<16384, 256, 0, stream>>>(idxp, cb32, outZ);
  // hcat accum := 0 (R2 and R3 are contiguous: 4096*256 = 1048576 floats)
  zero_rw<<<4096, 256, 0, stream>>>(R2);
  // W -> MFMA-ready hi/lo fragments (R1 region now dead; coalesced v2)
  wprep_rw<<<dim3(128, 2), 256, 0, stream>>>(wpo, wno, flags, whlp, whln);
  // hout_p / hout_n: gather-free-fragment MFMA, sch-split x4, atomic accum
  houtm2_rw<4><<<dim3(128, 2, 4), 256, 0, stream>>>(idxp, cbhl, whlp, R2);
  houtm2_rw<1><<<dim3(128, 2, 4), 256, 0, stream>>>(idxn, cbhl, whln, R3);
  // out = conv_out(silu(hcat + hout_bias))  (64px x 64out tiles)
  gemm2_rw<256,5,false,0><<<dim3(64,4), 256, 0, stream>>>(
      R2, R3, nullptr, cow, cob, bpo, bno,
      outO, flags, 256, 256, 0, 0, 0, 0);
  loss_rw<<<1, 64, 0, stream>>>(loss, outL);
}

// Round 12
// 561.299 us; speedup vs baseline: 1.0991x; 1.0002x over previous
//
#include <hip/hip_runtime.h>
#include <hip/hip_bf16.h>

// Round 24: accounting-driven fixes. Cross-round fit (quantm const 59):
// houtm2 ~40us each (not 15 — unroll-1 leaves 1 load-set in flight: 8
// serial stages of random-gather(300cy)+6 dep MFMAs); 4x4 retile was +10
// (halved conv grids to 1 block/CU). Changes: (1) gemm2 reverted to r18
// 32px x 64out tile (conv 512 blocks, z-gemm 2048); (2) houtm2 depth-2
// pipeline (next stage's 6 b128 loads issue before current MFMAs, ~90
// VGPR under (256,4) cap); (3) quantm depth-2 B-prefetch (manual x2
// unroll, named P0/P1, clamped). wprep v2 kept (~3us). Cert/fallback/
// merge semantics byte-identical to r18 (passed).
// Outputs (f32): out[1048576] | loss[1] | zq_p[4194304].

typedef float f32x4  __attribute__((ext_vector_type(4)));
typedef short bf16x8 __attribute__((ext_vector_type(8)));

__device__ __forceinline__ float silu_rw(float x){ return x / (1.f + expf(-x)); }
__device__ __forceinline__ float b2f_rw(__hip_bfloat16 v){ return __bfloat162float(v); }
__device__ __forceinline__ float ldv_rw(const void* p, int i, int f32m){
  if (f32m) return ((const float*)p)[i];
  return b2f_rw(((const __hip_bfloat16*)p)[i]);
}
__device__ __forceinline__ unsigned short f2bf_rw(float x){   // f32 -> bf16 RNE
  unsigned u = __float_as_uint(x);
  unsigned r = ((u >> 16) & 1u) + 0x7FFFu;
  return (unsigned short)((u + r) >> 16);
}
__device__ __forceinline__ float bf2f_rw(unsigned short h){
  return __uint_as_float(((unsigned)h) << 16);
}

// ---------------- workspace layout (float offsets) ----------------
#define FLAGS_OFF 0
#define LOSS_OFF  4
#define STATS_OFF 8
#define CNT_OFF   72         // 8 ints: fallback counters per chunk
#define CMAX_OFF  80         // max_j |c_j| (f32)
#define CB32_OFF  128        // 1024x32 f32
#define CBN_OFF   32896      // 1024
#define IDXP_OFF  33984      // 131072 int
#define IDXN_OFF  165056     // 131072 int
#define CBHL_OFF  296192     // interleaved hi/lo bf16 table (32768 f32 slots)
#define LIST_OFF  328960     // 131072 int (uncertain list, reused per chunk)
#define R2_OFF    460032     // lnp -> hcat_p accum (524288)
#define R3_OFF    984320     // lnn -> hcat_n accum (524288)
#define R1_OFF    1508608    // h (1048576) / z chunks (CS*262144) / whl tables

// ---------------- input dtype probe + zero accumulators ----------------
__global__ __launch_bounds__(256) void detect_rw(const void* cbv, float* wsb){
  __shared__ int bad;
  if (threadIdx.x == 0) bad = 0;
  __syncthreads();
  const unsigned short* u = (const unsigned short*)cbv;
  int local = 0;
  for (int i = threadIdx.x; i < 32768; i += 256){
    unsigned e = (u[i] >> 7) & 0xFF;
    if (e >= 126) local = 1;
  }
  if (local) bad = 1;
  __syncthreads();
  if (threadIdx.x == 0){
    wsb[FLAGS_OFF] = bad ? 1.f : 0.f;   // 1.0 => inputs are f32
    wsb[LOSS_OFF] = 0.f; wsb[LOSS_OFF + 1] = 0.f;
    int* c = (int*)(wsb + CNT_OFF);
    #pragma unroll
    for (int k = 0; k < 8; ++k) c[k] = 0;
    wsb[CMAX_OFF] = 0.f;
  }
}

// ------ codebook -> f32 + |c|^2 + interleaved bf16 hi/lo tile table ------
__global__ __launch_bounds__(256) void cbprep_rw(const void* cbv, const float* flags,
                                                 float* cb32, float* cbn,
                                                 short* cbhl, float* cmaxp){
  const int f32m = (flags[0] != 0.f);
  int j = blockIdx.x * 256 + threadIdx.x;
  if (j < 1024){
    float s = 0.f;
    const int tb = ((j >> 4) << 10) + ((j & 15) << 5);
    for (int e = 0; e < 32; ++e){
      float v = ldv_rw(cbv, j*32 + e, f32m);
      cb32[j*32 + e] = v;
      unsigned short h = f2bf_rw(v);
      cbhl[tb + e]       = (short)h;
      cbhl[tb + e + 512] = (short)f2bf_rw(v - bf2f_rw(h));
      s += v*v;
    }
    cbn[j] = s;
    atomicMax((int*)cmaxp, __float_as_int(sqrtf(s)));  // positive floats: int-bit monotone
  }
}

// ------- gemm2 (r18-exact 32px x 64out tile, INMODE 0/2/5, bit-exact) ------
template<int KCH, int INMODE, bool OUTSILU>
__global__ __launch_bounds__(256) void gemm2_rw(
    const float* __restrict__ inF, const float* __restrict__ inF2,
    const void* __restrict__ inV,
    const void* __restrict__ W, const void* __restrict__ biasO,
    const void* __restrict__ sbA, const void* __restrict__ sbB,
    float* __restrict__ outF, const float* __restrict__ flags,
    int KDIM, int OUTC, int o_off, int b_base, int ib_sub, int ob_sub)
{
  __shared__ float As[32][32];
  __shared__ float Bs[32][68];

  const int f32m = (flags[0] != 0.f);
  const int t  = threadIdx.x;
  const int q0 = (blockIdx.x << 5) + (b_base << 8);
  const int b  = q0 >> 8;
  const int p0 = q0 & 255;
  const int o0 = blockIdx.y << 6;
  const int k0base = blockIdx.z * KCH;
  const int tx = t & 15, ty = t >> 4;
  float acc[4][2] = {};

  const int sch = t >> 3, spx = (t & 7) << 2;

  for (int kc = 0; kc < KCH; kc += 32){
    const int k0 = k0base + kc;
    if constexpr (INMODE == 0){
      const float4 v = *reinterpret_cast<const float4*>(
          &inF[(((b - ib_sub)*KDIM + k0 + sch) << 8) + p0 + spx]);
      *reinterpret_cast<float4*>(&As[sch][spx]) = v;
    } else if constexpr (INMODE == 2){
      if (f32m){
        const float* xf = (const float*)inV;
        float4 v = *reinterpret_cast<const float4*>(&xf[((b*KDIM + k0 + sch) << 8) + p0 + spx]);
        v.x = silu_rw(v.x); v.y = silu_rw(v.y); v.z = silu_rw(v.z); v.w = silu_rw(v.w);
        *reinterpret_cast<float4*>(&As[sch][spx]) = v;
      } else {
        const __hip_bfloat16* xb = (const __hip_bfloat16*)inV;
        const int off = ((b*KDIM + k0 + sch) << 8) + p0 + spx;
        #pragma unroll
        for (int j = 0; j < 4; ++j) As[sch][spx + j] = silu_rw(b2f_rw(xb[off + j]));
      }
    } else { // INMODE 5
      const float* src = (k0 < 128) ? inF : inF2;
      const void* sb   = (k0 < 128) ? sbA : sbB;
      const int kh = k0 & 127;
      const float bb = ldv_rw(sb, kh + sch, f32m);
      float4 v = *reinterpret_cast<const float4*>(&src[((b*128 + kh + sch) << 8) + p0 + spx]);
      v.x = silu_rw(v.x + bb); v.y = silu_rw(v.y + bb);
      v.z = silu_rw(v.z + bb); v.w = silu_rw(v.w + bb);
      *reinterpret_cast<float4*>(&As[sch][spx]) = v;
    }
    if (f32m){
      const float* Wf = (const float*)W;
      #pragma unroll
      for (int r = 0; r < 8; ++r){
        int ii = t + (r << 8); int oo = ii >> 5, cc = ii & 31;
        Bs[cc][oo] = Wf[(o0 + oo)*KDIM + k0 + cc];
      }
    } else {
      const __hip_bfloat16* Wb = (const __hip_bfloat16*)W;
      #pragma unroll
      for (int r = 0; r < 8; ++r){
        int ii = t + (r << 8); int oo = ii >> 5, cc = ii & 31;
        Bs[cc][oo] = b2f_rw(Wb[(o0 + oo)*KDIM + k0 + cc]);
      }
    }
    __syncthreads();
    #pragma unroll
    for (int kk = 0; kk < 32; ++kk){
      const float2 a = *reinterpret_cast<const float2*>(&As[kk][tx << 1]);
      const float4 w = *reinterpret_cast<const float4*>(&Bs[kk][ty << 2]);
      acc[0][0] = fmaf(w.x, a.x, acc[0][0]); acc[0][1] = fmaf(w.x, a.y, acc[0][1]);
      acc[1][0] = fmaf(w.y, a.x, acc[1][0]); acc[1][1] = fmaf(w.y, a.y, acc[1][1]);
      acc[2][0] = fmaf(w.z, a.x, acc[2][0]); acc[2][1] = fmaf(w.z, a.y, acc[2][1]);
      acc[3][0] = fmaf(w.w, a.x, acc[3][0]); acc[3][1] = fmaf(w.w, a.y, acc[3][1]);
    }
    __syncthreads();
  }
  #pragma unroll
  for (int i = 0; i < 4; ++i){
    const int o = o0 + (ty << 2) + i;
    const int base = (((b - ob_sub)*OUTC + o_off + o) << 8) + p0 + (tx << 1);
    const float bb = ldv_rw(biasO, o, f32m);
    float v0 = acc[i][0] + bb, v1 = acc[i][1] + bb;
    if constexpr (OUTSILU){ v0 = silu_rw(v0); v1 = silu_rw(v1); }
    *reinterpret_cast<float2*>(&outF[base]) = make_float2(v0, v1);
  }
}

// ------- wprep v2: W[o][e*32+sch] -> whl[sch][o][hi e| lo e], coalesced ----
__global__ __launch_bounds__(256) void wprep_rw(const void* Wp, const void* Wn,
    const float* flags, short* whlp, short* whln){
  const int f32m = (flags[0] != 0.f);
  const void* W = blockIdx.y ? Wn : Wp;
  short* whl = blockIdx.y ? whln : whlp;
  const int o = blockIdx.x, t = threadIdx.x;
  #pragma unroll
  for (int ch = 0; ch < 4; ++ch){
    const int k = (ch << 8) + t;
    const int e = k >> 5, sch = k & 31;
    const float wv = ldv_rw(W, (o << 10) + k, f32m);
    const unsigned short h = f2bf_rw(wv);
    const int ob = (((sch << 7) + o) << 6) + e;
    whl[ob]      = (short)h;
    whl[ob + 32] = (short)f2bf_rw(wv - bf2f_rw(h));
  }
}

// ------- houtm2 v2: gather-free-fragment MFMA, depth-2 load pipeline -------
// Per s stage: next stage's 6 b128 loads issue BEFORE current stage's 6
// MFMAs -> gather latency overlaps matrix work. ~90 VGPR < (256,4) cap.
template<int LEVELS>
__global__ __launch_bounds__(256, 4) void houtm2_rw(
    const int* __restrict__ idxin, const short* __restrict__ cbhl,
    const short* __restrict__ whl, float* __restrict__ outF)
{
  const int t = threadIdx.x;
  const int lane = t & 63, wid = t >> 6;
  const int lc = lane & 15, gq = lane >> 4;
  const int b  = blockIdx.x >> 3;
  const int p0 = (blockIdx.x & 7) << 5;
  const int o0 = (blockIdx.y << 6) + (wid << 4);
  const int s0 = blockIdx.z << 3;
  const int ge = gq << 3;

  int j0[8], j1[8];
  #pragma unroll
  for (int s = 0; s < 8; ++s){
    const int sch = s0 + s;
    int a0, a1;
    if (LEVELS == 4){
      const int l = sch >> 3, kp = sch & 7;
      a0 = b*8192 + (((kp << 8) + p0 + lc) << 2) + l;
      a1 = b*8192 + (((kp << 8) + p0 + 16 + lc) << 2) + l;
    } else {
      a0 = b*8192 + (sch << 8) + p0 + lc;
      a1 = a0 + 16;
    }
    j0[s] = idxin[a0] & 1023;
    j1[s] = idxin[a1] & 1023;
  }

  f32x4 acc0 = {0.f, 0.f, 0.f, 0.f};
  f32x4 acc1 = {0.f, 0.f, 0.f, 0.f};

  // preload stage 0
  int a0h = ((j0[0] >> 4) << 10) + ((j0[0] & 15) << 5) + ge;
  int a1h = ((j1[0] >> 4) << 10) + ((j1[0] & 15) << 5) + ge;
  int wb  = (((s0 << 7) + o0 + lc) << 6) + ge;
  bf16x8 ah0 = *reinterpret_cast<const bf16x8*>(cbhl + a0h);
  bf16x8 al0 = *reinterpret_cast<const bf16x8*>(cbhl + a0h + 512);
  bf16x8 ah1 = *reinterpret_cast<const bf16x8*>(cbhl + a1h);
  bf16x8 al1 = *reinterpret_cast<const bf16x8*>(cbhl + a1h + 512);
  bf16x8 bh  = *reinterpret_cast<const bf16x8*>(whl + wb);
  bf16x8 bl  = *reinterpret_cast<const bf16x8*>(whl + wb + 32);

  #pragma unroll 1
  for (int s = 0; s < 8; ++s){
    const int sn = (s < 7) ? s + 1 : 7;
    const int n0h = ((j0[sn] >> 4) << 10) + ((j0[sn] & 15) << 5) + ge;
    const int n1h = ((j1[sn] >> 4) << 10) + ((j1[sn] & 15) << 5) + ge;
    const int nwb = ((((s0 + sn) << 7) + o0 + lc) << 6) + ge;
    const bf16x8 nah0 = *reinterpret_cast<const bf16x8*>(cbhl + n0h);
    const bf16x8 nal0 = *reinterpret_cast<const bf16x8*>(cbhl + n0h + 512);
    const bf16x8 nah1 = *reinterpret_cast<const bf16x8*>(cbhl + n1h);
    const bf16x8 nal1 = *reinterpret_cast<const bf16x8*>(cbhl + n1h + 512);
    const bf16x8 nbh  = *reinterpret_cast<const bf16x8*>(whl + nwb);
    const bf16x8 nbl  = *reinterpret_cast<const bf16x8*>(whl + nwb + 32);

    acc0 = __builtin_amdgcn_mfma_f32_16x16x32_bf16(ah0, bh, acc0, 0, 0, 0);
    acc0 = __builtin_amdgcn_mfma_f32_16x16x32_bf16(ah0, bl, acc0, 0, 0, 0);
    acc0 = __builtin_amdgcn_mfma_f32_16x16x32_bf16(al0, bh, acc0, 0, 0, 0);
    acc1 = __builtin_amdgcn_mfma_f32_16x16x32_bf16(ah1, bh, acc1, 0, 0, 0);
    acc1 = __builtin_amdgcn_mfma_f32_16x16x32_bf16(ah1, bl, acc1, 0, 0, 0);
    acc1 = __builtin_amdgcn_mfma_f32_16x16x32_bf16(al1, bh, acc1, 0, 0, 0);

    ah0 = nah0; al0 = nal0; ah1 = nah1; al1 = nal1; bh = nbh; bl = nbl;
  }

  const int obase = ((b*128 + o0 + lc) << 8) + p0 + (gq << 2);
  #pragma unroll
  for (int r = 0; r < 4; ++r){
    atomicAdd(&outF[obase + r],      acc0[r]);
    atomicAdd(&outF[obase + 16 + r], acc1[r]);
  }
}

// ---------------- per-sample LN stats over silu(h_half) ----------------
__global__ __launch_bounds__(256) void stats_rw(const float* __restrict__ h, float* __restrict__ stats){
  const int b = blockIdx.x >> 1, half = blockIdx.x & 1;
  const float* base = h + ((b*256 + half*128) << 8);
  float s = 0.f, s2 = 0.f;
  for (int i = threadIdx.x; i < 32768; i += 256){
    float a = silu_rw(base[i]);
    s += a; s2 += a*a;
  }
  __shared__ float sh[2][256];
  sh[0][threadIdx.x] = s; sh[1][threadIdx.x] = s2;
  __syncthreads();
  for (int st = 128; st > 0; st >>= 1){
    if (threadIdx.x < st){
      sh[0][threadIdx.x] += sh[0][threadIdx.x + st];
      sh[1][threadIdx.x] += sh[1][threadIdx.x + st];
    }
    __syncthreads();
  }
  if (threadIdx.x == 0){
    float mu  = sh[0][0] * (1.f/32768.f);
    float var = sh[1][0] * (1.f/32768.f) - mu*mu;
    stats[half*32 + b]      = mu;
    stats[half*32 + 16 + b] = 1.f / sqrtf(var + 1e-5f);
  }
}

// ---------------- LN apply ----------------
__global__ __launch_bounds__(256) void ln_rw(const float* __restrict__ h,
    const void* lwp, const void* lbp, const void* lwn, const void* lbn,
    const float* __restrict__ stats, const float* __restrict__ flags,
    float* __restrict__ lnp, float* __restrict__ lnn){
  const int f32m = (flags[0] != 0.f);
  int i = blockIdx.x * 256 + threadIdx.x;
  int b = i >> 16, c = (i >> 8) & 255, p = i & 255;
  float a = silu_rw(h[i]);
  if (c < 128){
    float v = (a - stats[b]) * stats[16 + b] * ldv_rw(lwp, (c << 8) + p, f32m) + ldv_rw(lbp, (c << 8) + p, f32m);
    lnp[((b*128 + c) << 8) + p] = v;
  } else {
    int cc = c - 128;
    float v = (a - stats[32 + b]) * stats[48 + b] * ldv_rw(lwn, (cc << 8) + p, f32m) + ldv_rw(lbn, (cc << 8) + p, f32m);
    lnn[((b*128 + cc) << 8) + p] = v;
  }
}

// -------- VQ search v6c: r18 structure + depth-2 B prefetch (manual x2) ----
// Semantics identical to r18 (cert, merges, tie rules); only the B-tile
// prefetch distance changed from 1 to 2 (P0 even tiles, P1 odd tiles).
template<int LEVELS>
__global__ __launch_bounds__(512, 4) void quantm_rw(
    const float* __restrict__ z, const short* __restrict__ cbhl,
    const float* __restrict__ cbn, const float* __restrict__ cmaxp,
    int* __restrict__ idxout, float* __restrict__ lossacc,
    int* __restrict__ cnt, int* __restrict__ list, int b_base)
{
  __shared__ float mgm1[4][4][8], mgm2[4][4][8];
  __shared__ int   mgj [4][4][8];
  __shared__ float red[4];

  const int tid  = threadIdx.x;
  const int lane = tid & 63, wid = tid >> 6;
  const int lc = lane & 15, gq = lane >> 4;
  const int pg = wid & 3, ch = wid >> 2;    // pixel group, code half
  const int bid  = blockIdx.x;
  const int bl   = bid >> 6;                // local batch
  const int rest = bid & 63;
  const int g = rest >> 1, half = rest & 1;
  int cb, wbase, wstep;
  if (LEVELS == 4){ cb = (g & 3)*8 + (g >> 2); wbase = (g >> 2)*1024 + (g & 3); wstep = 4; }
  else            { cb = g;                    wbase = g << 8;                  wstep = 1; }
  const int pb = half*128 + pg*32;

  // ---- load z rows, build -2z hi/lo bf16 A-fragments, partial |z|^2 ----
  bf16x8 ah0, al0, ah1, al1;
  float zn0 = 0.f, zn1 = 0.f;
  const int zoff = (((bl << 10) + cb) << 8) + pb + lc;
  const int e0 = gq << 3;
  #pragma unroll
  for (int i = 0; i < 8; ++i){
    const int zo = zoff + ((e0 + i) << 13);
    const float z0 = z[zo];
    const float z1 = z[zo + 16];
    zn0 += z0*z0; zn1 += z1*z1;
    const float s0 = -2.f*z0, s1 = -2.f*z1;
    const unsigned short h0 = f2bf_rw(s0);
    const unsigned short h1 = f2bf_rw(s1);
    ah0[i] = (short)h0; al0[i] = (short)f2bf_rw(s0 - bf2f_rw(h0));
    ah1[i] = (short)h1; al1[i] = (short)f2bf_rw(s1 - bf2f_rw(h1));
  }
  zn0 += __shfl_xor(zn0, 16); zn0 += __shfl_xor(zn0, 32);   // full zn for row lc
  zn1 += __shfl_xor(zn1, 16); zn1 += __shfl_xor(zn1, 32);

  float m1[8], m2[8]; int j1[8];
  #pragma unroll
  for (int s = 0; s < 8; ++s){ m1[s] = __builtin_inff(); m2[s] = __builtin_inff(); j1[s] = 0; }

  const short* bp  = cbhl + (ch << 15) + (lc << 5) + (gq << 3);
  const float* cnp = cbn + (ch << 9) + lc;

  // depth-2: P0 holds even tile, P1 holds odd tile
  bf16x8 p0h = *reinterpret_cast<const bf16x8*>(bp);
  bf16x8 p0l = *reinterpret_cast<const bf16x8*>(bp + 512);
  float  p0c = cnp[0];
  bf16x8 p1h = *reinterpret_cast<const bf16x8*>(bp + 1024);
  bf16x8 p1l = *reinterpret_cast<const bf16x8*>(bp + 1024 + 512);
  float  p1c = cnp[16];

  #pragma unroll 1
  for (int t = 0; t < 32; t += 2){
    // ---- body A: tile t (P0); prefetch tile t+2 -> P0 ----
    {
      const int tn = (t + 2 < 32) ? t + 2 : 31;
      const bf16x8 nh = *reinterpret_cast<const bf16x8*>(bp + (tn << 10));
      const bf16x8 nl = *reinterpret_cast<const bf16x8*>(bp + (tn << 10) + 512);
      const float  nc = cnp[tn << 4];

      f32x4 a0 = {p0c, p0c, p0c, p0c};
      f32x4 a1 = {p0c, p0c, p0c, p0c};
      a0 = __builtin_amdgcn_mfma_f32_16x16x32_bf16(ah0, p0h, a0, 0, 0, 0);
      a0 = __builtin_amdgcn_mfma_f32_16x16x32_bf16(ah0, p0l, a0, 0, 0, 0);
      a0 = __builtin_amdgcn_mfma_f32_16x16x32_bf16(al0, p0h, a0, 0, 0, 0);
      a1 = __builtin_amdgcn_mfma_f32_16x16x32_bf16(ah1, p0h, a1, 0, 0, 0);
      a1 = __builtin_amdgcn_mfma_f32_16x16x32_bf16(ah1, p0l, a1, 0, 0, 0);
      a1 = __builtin_amdgcn_mfma_f32_16x16x32_bf16(al1, p0h, a1, 0, 0, 0);

      const int jc = (((ch << 5) + t) << 4) + lc;
      #pragma unroll
      for (int r = 0; r < 4; ++r){
        const float d0 = a0[r];
        m2[r] = __builtin_amdgcn_fmed3f(d0, m1[r], m2[r]);
        const bool t0 = d0 < m1[r];
        j1[r] = t0 ? jc : j1[r]; m1[r] = t0 ? d0 : m1[r];
        const float d1 = a1[r];
        m2[4+r] = __builtin_amdgcn_fmed3f(d1, m1[4+r], m2[4+r]);
        const bool t1 = d1 < m1[4+r];
        j1[4+r] = t1 ? jc : j1[4+r]; m1[4+r] = t1 ? d1 : m1[4+r];
      }
      p0h = nh; p0l = nl; p0c = nc;
    }
    // ---- body B: tile t+1 (P1); prefetch tile t+3 -> P1 ----
    {
      const int tn = (t + 3 < 32) ? t + 3 : 31;
      const bf16x8 nh = *reinterpret_cast<const bf16x8*>(bp + (tn << 10));
      const bf16x8 nl = *reinterpret_cast<const bf16x8*>(bp + (tn << 10) + 512);
      const float  nc = cnp[tn << 4];

      f32x4 a0 = {p1c, p1c, p1c, p1c};
      f32x4 a1 = {p1c, p1c, p1c, p1c};
      a0 = __builtin_amdgcn_mfma_f32_16x16x32_bf16(ah0, p1h, a0, 0, 0, 0);
      a0 = __builtin_amdgcn_mfma_f32_16x16x32_bf16(ah0, p1l, a0, 0, 0, 0);
      a0 = __builtin_amdgcn_mfma_f32_16x16x32_bf16(al0, p1h, a0, 0, 0, 0);
      a1 = __builtin_amdgcn_mfma_f32_16x16x32_bf16(ah1, p1h, a1, 0, 0, 0);
      a1 = __builtin_amdgcn_mfma_f32_16x16x32_bf16(ah1, p1l, a1, 0, 0, 0);
      a1 = __builtin_amdgcn_mfma_f32_16x16x32_bf16(al1, p1h, a1, 0, 0, 0);

      const int jc = (((ch << 5) + t + 1) << 4) + lc;
      #pragma unroll
      for (int r = 0; r < 4; ++r){
        const float d0 = a0[r];
        m2[r] = __builtin_amdgcn_fmed3f(d0, m1[r], m2[r]);
        const bool t0 = d0 < m1[r];
        j1[r] = t0 ? jc : j1[r]; m1[r] = t0 ? d0 : m1[r];
        const float d1 = a1[r];
        m2[4+r] = __builtin_amdgcn_fmed3f(d1, m1[4+r], m2[4+r]);
        const bool t1 = d1 < m1[4+r];
        j1[4+r] = t1 ? jc : j1[4+r]; m1[4+r] = t1 ? d1 : m1[4+r];
      }
      p1h = nh; p1l = nl; p1c = nc;
    }
  }

  // ---- 16-lane top-2 merge (cols of each row live in one 16-lane group) ----
  #pragma unroll
  for (int k = 1; k < 16; k <<= 1){
    #pragma unroll
    for (int s = 0; s < 8; ++s){
      const float om1 = __shfl_xor(m1[s], k);
      const float om2 = __shfl_xor(m2[s], k);
      const int   oj  = __shfl_xor(j1[s], k);
      m2[s] = fminf(fminf(m2[s], om2), fmaxf(m1[s], om1));
      const bool tk = (om1 < m1[s]) || (om1 == m1[s] && oj < j1[s]);
      m1[s] = tk ? om1 : m1[s];
      j1[s] = tk ? oj  : j1[s];
    }
  }

  // ---- cross-wave merge: upper code-half -> LDS, lower merges ----
  if (wid >= 4 && lc == 0){
    #pragma unroll
    for (int s = 0; s < 8; ++s){
      mgm1[wid-4][gq][s] = m1[s];
      mgm2[wid-4][gq][s] = m2[s];
      mgj [wid-4][gq][s] = j1[s];
    }
  }
  __syncthreads();
  if (wid < 4){
    #pragma unroll
    for (int s = 0; s < 8; ++s){
      const float om1 = mgm1[wid][gq][s];
      const float om2 = mgm2[wid][gq][s];
      const int   oj  = mgj [wid][gq][s];
      m2[s] = fminf(fminf(m2[s], om2), fmaxf(m1[s], om1));
      const bool tk = om1 < m1[s];       // tie keeps lower half (smaller j)
      m1[s] = tk ? om1 : m1[s];
      j1[s] = tk ? oj  : j1[s];
    }

    // ---- finalize: cert test, idx write, loss, uncertain list ----
    const float cmax = cmaxp[0];
    float lossw = 0.f;
    #pragma unroll
    for (int f = 0; f < 2; ++f){
      #pragma unroll
      for (int r = 0; r < 4; ++r){
        const int s = f*4 + r;
        const int vrow = (gq << 2) + r;
        const float znv = __shfl(f == 0 ? zn0 : zn1, vrow);
        if (lc == 0){
          const int p  = pb + f*16 + vrow;
          const int gi = (b_base + bl)*8192 + wbase + p*wstep;
          idxout[gi] = j1[s];                    // provisional if uncertain
          const float eb = fmaf(2.0e-6f, znv, 3.0e-4f * sqrtf(znv) * cmax);
          if (m2[s] - m1[s] > eb){
            lossw += znv + m1[s];
          } else {
            const int pos = atomicAdd(cnt, 1);
            if (pos < 131072) list[pos] = (((bl << 5) | g) << 8) | p;
          }
        }
      }
    }
    lossw += __shfl_xor(lossw, 16);
    lossw += __shfl_xor(lossw, 32);
    if (lane == 0) red[wid] = lossw;
  }
  __syncthreads();
  if (tid == 0) atomicAdd(lossacc, red[0] + red[1] + red[2] + red[3]);
}

// ---------------- np-bit-exact f32 fallback for uncertain vectors ----------
template<int LEVELS>
__global__ __launch_bounds__(256) void fb_rw(
    const float* __restrict__ z, const float* __restrict__ cb32,
    const float* __restrict__ cbn, const int* __restrict__ cnt,
    const int* __restrict__ list, int* __restrict__ idxout,
    float* __restrict__ lossacc, int b_base)
{
  const int lane = threadIdx.x & 63;
  const int wv = (blockIdx.x << 2) | (threadIdx.x >> 6);
  const int nw = gridDim.x << 2;
  int n = cnt[0];
  if (n > 131072) n = 131072;
  for (int it = wv; it < n; it += nw){
    const int id = list[it];
    const int p = id & 255, g = (id >> 8) & 31, bl = id >> 13;
    int cb, w;
    if (LEVELS == 4){ cb = (g & 3)*8 + (g >> 2); w = (g >> 2)*1024 + (p << 2) + (g & 3); }
    else            { cb = g;                    w = (g << 8) + p; }
    const int zoff = (((bl << 10) + cb) << 8) + p;
    float myz = 0.f;
    if (lane < 32) myz = z[zoff + (lane << 13)];
    float zb[32];
    #pragma unroll
    for (int e = 0; e < 32; ++e) zb[e] = __shfl(myz, e);
    float zn = 0.f;
    #pragma unroll
    for (int e = 0; e < 32; ++e) zn = fmaf(zb[e], zb[e], zn);
    float bd = __builtin_inff(); int bj = 0;
    #pragma unroll 4
    for (int jj = 0; jj < 16; ++jj){
      const int j = (jj << 6) + lane;
      const float4* c4 = reinterpret_cast<const float4*>(cb32 + (j << 5));
      float dot = 0.f;
      #pragma unroll
      for (int e4 = 0; e4 < 8; ++e4){
        const float4 cv = c4[e4];
        dot = fmaf(zb[(e4 << 2) + 0], cv.x, dot);
        dot = fmaf(zb[(e4 << 2) + 1], cv.y, dot);
        dot = fmaf(zb[(e4 << 2) + 2], cv.z, dot);
        dot = fmaf(zb[(e4 << 2) + 3], cv.w, dot);
      }
      const float d = (zn - 2.f*dot) + cbn[j];   // np's exact formula/rounding
      if (d < bd){ bd = d; bj = j; }
    }
    #pragma unroll
    for (int k = 1; k < 64; k <<= 1){
      const float od = __shfl_xor(bd, k);
      const int   oj = __shfl_xor(bj, k);
      if (od < bd || (od == bd && oj < bj)){ bd = od; bj = oj; }
    }
    if (lane == 0){
      idxout[(b_base + bl)*8192 + w] = bj;
      atomicAdd(lossacc, bd);                    // bd == |z-c|^2 (includes zn)
    }
  }
}

// ---------------- zq_p output (f32) ----------------
__global__ __launch_bounds__(256) void zqout_rw(const int* __restrict__ idxp,
    const float* __restrict__ cb32, float* __restrict__ out){
  int t = blockIdx.x * 256 + threadIdx.x;
  int l = t & 3, n = (t >> 2) & 2047, e = (t >> 13) & 31, b = t >> 18;
  int id = idxp[b*8192 + (n << 2) + l];
  out[t] = cb32[((id & 1023) << 5) + e];
}

// ---------------- zero hcat accum ----------------
__global__ __launch_bounds__(256) void zero_rw(float* __restrict__ p){
  p[blockIdx.x * 256 + threadIdx.x] = 0.f;
}

// ---------------- loss finalize ----------------
__global__ void loss_rw(const float* __restrict__ lossacc, float* __restrict__ out){
  if (threadIdx.x == 0 && blockIdx.x == 0)
    out[0] = 1.25f * (lossacc[0] + lossacc[1]) * (1.f/4194304.f);
}

extern "C" void kernel_launch(void* const* d_in, const int* in_sizes, int n_in,
                              void* d_out, int out_size, void* d_ws, size_t ws_size,
                              hipStream_t stream){
  (void)in_sizes; (void)n_in; (void)out_size;
  const void* x   = d_in[0];
  const void* ciw = d_in[1];
  const void* cib = d_in[2];
  const void* lwp = d_in[3];
  const void* lbp = d_in[4];
  const void* wpi = d_in[5];
  const void* bpi = d_in[6];
  const void* wpo = d_in[7];
  const void* bpo = d_in[8];
  const void* lwn = d_in[9];
  const void* lbn = d_in[10];
  const void* wni = d_in[11];
  const void* bni = d_in[12];
  const void* wno = d_in[13];
  const void* bno = d_in[14];
  const void* cbk = d_in[15];
  const void* cow = d_in[16];
  const void* cob = d_in[17];

  float* ws    = (float*)d_ws;
  float* flags = ws + FLAGS_OFF;
  float* loss  = ws + LOSS_OFF;
  float* stats = ws + STATS_OFF;
  float* cmaxp = ws + CMAX_OFF;
  float* cb32  = ws + CB32_OFF;
  float* cbn   = ws + CBN_OFF;
  int*   cnts  = (int*)(ws + CNT_OFF);
  int*   idxp  = (int*)(ws + IDXP_OFF);
  int*   idxn  = (int*)(ws + IDXN_OFF);
  short* cbhl  = (short*)(ws + CBHL_OFF);
  int*   list  = (int*)(ws + LIST_OFF);
  float* R2    = ws + R2_OFF;
  float* R3    = ws + R3_OFF;
  float* R1    = ws + R1_OFF;
  short* whlp  = (short*)(ws + R1_OFF);            // R1 dead after quant loops
  short* whln  = (short*)(ws + R1_OFF + 131072);

  float* outO = (float*)d_out;
  float* outL = outO + 1048576;
  float* outZ = outO + 1048577;

  const size_t wsf = ws_size / 4;
  int CS = 4;
  if      (wsf >= (size_t)R1_OFF + 16u*262144u) CS = 16;
  else if (wsf >= (size_t)R1_OFF +  8u*262144u) CS = 8;

  detect_rw<<<1, 256, 0, stream>>>(cbk, ws);
  cbprep_rw<<<4, 256, 0, stream>>>(cbk, flags, cb32, cbn, cbhl, cmaxp);
  // h = conv_in(silu(x)) -> R1   (32px x 64out, r18 geometry)
  gemm2_rw<256,2,false><<<dim3(128,4), 256, 0, stream>>>(
      nullptr, nullptr, x, ciw, cib, nullptr, nullptr,
      R1, flags, 256, 256, 0, 0, 0, 0);
  stats_rw<<<32, 256, 0, stream>>>(R1, stats);
  ln_rw<<<4096, 256, 0, stream>>>(R1, lwp, lbp, lwn, lbn, stats, flags, R2, R3);
  // phylo: z chunks (R2 -> R1), MFMA quantize + np-exact fallback
  {
    int ci = 0;
    for (int c = 0; c < 16; c += CS, ++ci){
      gemm2_rw<128,0,true><<<dim3(CS*8,16), 256, 0, stream>>>(
          R2, nullptr, nullptr, wpi, bpi, nullptr, nullptr,
          R1, flags, 128, 1024, 0, c, 0, c);
      quantm_rw<4><<<CS*64, 512, 0, stream>>>(R1, cbhl, cbn, cmaxp,
                                              idxp, loss + 0, cnts + ci, list, c);
      fb_rw<4><<<640, 256, 0, stream>>>(R1, cb32, cbn, cnts + ci, list,
                                        idxp, loss + 0, c);
    }
  }
  // non-phylo
  {
    int ci = 4;
    for (int c = 0; c < 16; c += CS, ++ci){
      gemm2_rw<128,0,true><<<dim3(CS*8,16), 256, 0, stream>>>(
          R3, nullptr, nullptr, wni, bni, nullptr, nullptr,
          R1, flags, 128, 1024, 0, c, 0, c);
      quantm_rw<1><<<CS*64, 512, 0, stream>>>(R1, cbhl, cbn, cmaxp,
                                              idxn, loss + 1, cnts + ci, list, c);
      fb_rw<1><<<640, 256, 0, stream>>>(R1, cb32, cbn, cnts + ci, list,
                                        idxn, loss + 1, c);
    }
  }
  zqout_rw<<<16384, 256, 0, stream>>>(idxp, cb32, outZ);
  // hcat accum := 0 (R2 and R3 are contiguous: 4096*256 = 1048576 floats)
  zero_rw<<<4096, 256, 0, stream>>>(R2);
  // W -> MFMA-ready hi/lo fragments (R1 region now dead; coalesced)
  wprep_rw<<<dim3(128, 2), 256, 0, stream>>>(wpo, wno, flags, whlp, whln);
  // hout_p / hout_n: gather-free-fragment MFMA, depth-2 pipeline
  houtm2_rw<4><<<dim3(128, 2, 4), 256, 0, stream>>>(idxp, cbhl, whlp, R2);
  houtm2_rw<1><<<dim3(128, 2, 4), 256, 0, stream>>>(idxn, cbhl, whln, R3);
  // out = conv_out(silu(hcat + hout_bias))  (32px x 64out)
  gemm2_rw<256,5,false><<<dim3(128,4), 256, 0, stream>>>(
      R2, R3, nullptr, cow, cob, bpo, bno,
      outO, flags, 256, 256, 0, 0, 0, 0);
  loss_rw<<<1, 64, 0, stream>>>(loss, outL);
}

// Round 13
// 532.824 us; speedup vs baseline: 1.1578x; 1.0534x over previous
//
#include <hip/hip_runtime.h>
#include <hip/hip_bf16.h>

// Round 25: REVERT to r18-exact (best measured: 535.07us, passed).
// r19-r24 post-mortems: (r19) 4-wave quantm +spill 905; (r20) spill fixed
// but 4-wave granularity refuted (68 vs 59); (r21) houtm v1 latency-dead
// (81us, 4.2M bank conflicts); (r22) houtm2 gather-MFMA 40us each — worse
// than the scalar INMODE3 hout it replaced (cross-container fit: +25us
// net); (r23/r24) wprep v2, 4x4 retile, depth-2 pipelines all null
// (561 -> 561; per-tile compute 30-130cy << 300cy gather latency, TLP
// already covers the compute fraction). Non-quantm baseline: r18 417us,
// r20 414us (agreement within 3) vs houtm2-path 441. Conclusion: restore
// the measured optimum verbatim. quantm v6b (512,4) 59us, scalar hout
// INMODE3+atomic, fb v2 640 blocks, cert eb = 3e-4*sqrt(zn)*cmax+2e-6*zn.
// Outputs (f32): out[1048576] | loss[1] | zq_p[4194304].

typedef float f32x4  __attribute__((ext_vector_type(4)));
typedef short bf16x8 __attribute__((ext_vector_type(8)));

__device__ __forceinline__ float silu_rw(float x){ return x / (1.f + expf(-x)); }
__device__ __forceinline__ float b2f_rw(__hip_bfloat16 v){ return __bfloat162float(v); }
__device__ __forceinline__ float ldv_rw(const void* p, int i, int f32m){
  if (f32m) return ((const float*)p)[i];
  return b2f_rw(((const __hip_bfloat16*)p)[i]);
}
__device__ __forceinline__ unsigned short f2bf_rw(float x){   // f32 -> bf16 RNE
  unsigned u = __float_as_uint(x);
  unsigned r = ((u >> 16) & 1u) + 0x7FFFu;
  return (unsigned short)((u + r) >> 16);
}
__device__ __forceinline__ float bf2f_rw(unsigned short h){
  return __uint_as_float(((unsigned)h) << 16);
}

// ---------------- workspace layout (float offsets) ----------------
#define FLAGS_OFF 0
#define LOSS_OFF  4
#define STATS_OFF 8
#define CNT_OFF   72         // 8 ints: fallback counters per chunk
#define CMAX_OFF  80         // max_j |c_j| (f32)
#define CB32_OFF  128        // 1024x32 f32
#define CBN_OFF   32896      // 1024
#define IDXP_OFF  33984      // 131072 int
#define IDXN_OFF  165056     // 131072 int
#define CBHL_OFF  296192     // interleaved hi/lo bf16 table (32768 f32 slots)
#define LIST_OFF  328960     // 131072 int (uncertain list, reused per chunk)
#define R2_OFF    460032     // lnp -> hcat_p accum (524288)
#define R3_OFF    984320     // lnn -> hcat_n accum (524288)
#define R1_OFF    1508608    // h (1048576) / z chunks (CS*262144)

// ---------------- input dtype probe + zero accumulators ----------------
__global__ __launch_bounds__(256) void detect_rw(const void* cbv, float* wsb){
  __shared__ int bad;
  if (threadIdx.x == 0) bad = 0;
  __syncthreads();
  const unsigned short* u = (const unsigned short*)cbv;
  int local = 0;
  for (int i = threadIdx.x; i < 32768; i += 256){
    unsigned e = (u[i] >> 7) & 0xFF;
    if (e >= 126) local = 1;
  }
  if (local) bad = 1;
  __syncthreads();
  if (threadIdx.x == 0){
    wsb[FLAGS_OFF] = bad ? 1.f : 0.f;   // 1.0 => inputs are f32
    wsb[LOSS_OFF] = 0.f; wsb[LOSS_OFF + 1] = 0.f;
    int* c = (int*)(wsb + CNT_OFF);
    #pragma unroll
    for (int k = 0; k < 8; ++k) c[k] = 0;
    wsb[CMAX_OFF] = 0.f;
  }
}

// ------ codebook -> f32 + |c|^2 + interleaved bf16 hi/lo tile table ------
// Tile T = j>>4 occupies shorts [T*1024, T*1024+1024): hi of code j elem e
// at T*1024 + (j&15)*32 + e, lo at +512.
__global__ __launch_bounds__(256) void cbprep_rw(const void* cbv, const float* flags,
                                                 float* cb32, float* cbn,
                                                 short* cbhl, float* cmaxp){
  const int f32m = (flags[0] != 0.f);
  int j = blockIdx.x * 256 + threadIdx.x;
  if (j < 1024){
    float s = 0.f;
    const int tb = ((j >> 4) << 10) + ((j & 15) << 5);
    for (int e = 0; e < 32; ++e){
      float v = ldv_rw(cbv, j*32 + e, f32m);
      cb32[j*32 + e] = v;
      unsigned short h = f2bf_rw(v);
      cbhl[tb + e]       = (short)h;
      cbhl[tb + e + 512] = (short)f2bf_rw(v - bf2f_rw(h));
      s += v*v;
    }
    cbn[j] = s;
    atomicMax((int*)cmaxp, __float_as_int(sqrtf(s)));  // positive floats: int-bit monotone
  }
}

// ---------------- gemm2 (r11, verified): 32px x 64out tiles ----------------
template<int KCH, int INMODE, bool OUTSILU, bool ATOMIC, int LEVELS>
__global__ __launch_bounds__(256) void gemm2_rw(
    const float* __restrict__ inF, const float* __restrict__ inF2,
    const void* __restrict__ inV,
    const void* __restrict__ W, const void* __restrict__ biasO,
    const void* __restrict__ sbA, const void* __restrict__ sbB,
    const int* __restrict__ idxin, const float* __restrict__ cb32,
    float* __restrict__ outF, const float* __restrict__ flags,
    int KDIM, int OUTC, int o_off, int b_base, int ib_sub, int ob_sub)
{
  __shared__ float As[32][32];
  __shared__ float Bs[32][68];
  __shared__ int   IdxS[32][32];

  const int f32m = (flags[0] != 0.f);
  const int t  = threadIdx.x;
  const int q0 = (blockIdx.x << 5) + (b_base << 8);
  const int b  = q0 >> 8;
  const int p0 = q0 & 255;
  const int o0 = blockIdx.y << 6;
  const int k0base = blockIdx.z * KCH;
  const int tx = t & 15, ty = t >> 4;
  float acc[4][2] = {};

  const int sch = t >> 3, spx = (t & 7) << 2;

  if constexpr (INMODE == 3){
    #pragma unroll
    for (int j = 0; j < 4; ++j){
      const int p = p0 + spx + j;
      if constexpr (LEVELS == 4){
        const int l = sch >> 3, kp = sch & 7;
        IdxS[sch][spx + j] = idxin[b*8192 + (((kp << 8) + p) << 2) + l];
      } else {
        IdxS[sch][spx + j] = idxin[b*8192 + (sch << 8) + p];
      }
    }
    __syncthreads();
  }

  for (int kc = 0; kc < KCH; kc += 32){
    const int k0 = k0base + kc;
    if constexpr (INMODE == 0){
      const float4 v = *reinterpret_cast<const float4*>(
          &inF[(((b - ib_sub)*KDIM + k0 + sch) << 8) + p0 + spx]);
      *reinterpret_cast<float4*>(&As[sch][spx]) = v;
    } else if constexpr (INMODE == 2){
      if (f32m){
        const float* xf = (const float*)inV;
        float4 v = *reinterpret_cast<const float4*>(&xf[((b*KDIM + k0 + sch) << 8) + p0 + spx]);
        v.x = silu_rw(v.x); v.y = silu_rw(v.y); v.z = silu_rw(v.z); v.w = silu_rw(v.w);
        *reinterpret_cast<float4*>(&As[sch][spx]) = v;
      } else {
        const __hip_bfloat16* xb = (const __hip_bfloat16*)inV;
        const int off = ((b*KDIM + k0 + sch) << 8) + p0 + spx;
        #pragma unroll
        for (int j = 0; j < 4; ++j) As[sch][spx + j] = silu_rw(b2f_rw(xb[off + j]));
      }
    } else if constexpr (INMODE == 3){
      const int e = k0 >> 5;
      #pragma unroll
      for (int j = 0; j < 4; ++j)
        As[sch][spx + j] = cb32[((IdxS[sch][spx + j] & 1023) << 5) + e];
    } else { // INMODE 5
      const float* src = (k0 < 128) ? inF : inF2;
      const void* sb   = (k0 < 128) ? sbA : sbB;
      const int kh = k0 & 127;
      const float bb = ldv_rw(sb, kh + sch, f32m);
      float4 v = *reinterpret_cast<const float4*>(&src[((b*128 + kh + sch) << 8) + p0 + spx]);
      v.x = silu_rw(v.x + bb); v.y = silu_rw(v.y + bb);
      v.z = silu_rw(v.z + bb); v.w = silu_rw(v.w + bb);
      *reinterpret_cast<float4*>(&As[sch][spx]) = v;
    }
    if (f32m){
      const float* Wf = (const float*)W;
      #pragma unroll
      for (int r = 0; r < 8; ++r){
        int ii = t + (r << 8); int oo = ii >> 5, cc = ii & 31;
        Bs[cc][oo] = Wf[(o0 + oo)*KDIM + k0 + cc];
      }
    } else {
      const __hip_bfloat16* Wb = (const __hip_bfloat16*)W;
      #pragma unroll
      for (int r = 0; r < 8; ++r){
        int ii = t + (r << 8); int oo = ii >> 5, cc = ii & 31;
        Bs[cc][oo] = b2f_rw(Wb[(o0 + oo)*KDIM + k0 + cc]);
      }
    }
    __syncthreads();
    #pragma unroll
    for (int kk = 0; kk < 32; ++kk){
      const float2 a = *reinterpret_cast<const float2*>(&As[kk][tx << 1]);
      const float4 w = *reinterpret_cast<const float4*>(&Bs[kk][ty << 2]);
      acc[0][0] += w.x*a.x; acc[0][1] += w.x*a.y;
      acc[1][0] += w.y*a.x; acc[1][1] += w.y*a.y;
      acc[2][0] += w.z*a.x; acc[2][1] += w.z*a.y;
      acc[3][0] += w.w*a.x; acc[3][1] += w.w*a.y;
    }
    __syncthreads();
  }
  #pragma unroll
  for (int i = 0; i < 4; ++i){
    const int o = o0 + (ty << 2) + i;
    const int base = (((b - ob_sub)*OUTC + o_off + o) << 8) + p0 + (tx << 1);
    if constexpr (ATOMIC){
      atomicAdd(&outF[base + 0], acc[i][0]);
      atomicAdd(&outF[base + 1], acc[i][1]);
    } else {
      const float bb = ldv_rw(biasO, o, f32m);
      float v0 = acc[i][0] + bb, v1 = acc[i][1] + bb;
      if constexpr (OUTSILU){ v0 = silu_rw(v0); v1 = silu_rw(v1); }
      *reinterpret_cast<float2*>(&outF[base]) = make_float2(v0, v1);
    }
  }
}

// ---------------- per-sample LN stats over silu(h_half) ----------------
__global__ __launch_bounds__(256) void stats_rw(const float* __restrict__ h, float* __restrict__ stats){
  const int b = blockIdx.x >> 1, half = blockIdx.x & 1;
  const float* base = h + ((b*256 + half*128) << 8);
  float s = 0.f, s2 = 0.f;
  for (int i = threadIdx.x; i < 32768; i += 256){
    float a = silu_rw(base[i]);
    s += a; s2 += a*a;
  }
  __shared__ float sh[2][256];
  sh[0][threadIdx.x] = s; sh[1][threadIdx.x] = s2;
  __syncthreads();
  for (int st = 128; st > 0; st >>= 1){
    if (threadIdx.x < st){
      sh[0][threadIdx.x] += sh[0][threadIdx.x + st];
      sh[1][threadIdx.x] += sh[1][threadIdx.x + st];
    }
    __syncthreads();
  }
  if (threadIdx.x == 0){
    float mu  = sh[0][0] * (1.f/32768.f);
    float var = sh[1][0] * (1.f/32768.f) - mu*mu;
    stats[half*32 + b]      = mu;
    stats[half*32 + 16 + b] = 1.f / sqrtf(var + 1e-5f);
  }
}

// ---------------- LN apply ----------------
__global__ __launch_bounds__(256) void ln_rw(const float* __restrict__ h,
    const void* lwp, const void* lbp, const void* lwn, const void* lbn,
    const float* __restrict__ stats, const float* __restrict__ flags,
    float* __restrict__ lnp, float* __restrict__ lnn){
  const int f32m = (flags[0] != 0.f);
  int i = blockIdx.x * 256 + threadIdx.x;
  int b = i >> 16, c = (i >> 8) & 255, p = i & 255;
  float a = silu_rw(h[i]);
  if (c < 128){
    float v = (a - stats[b]) * stats[16 + b] * ldv_rw(lwp, (c << 8) + p, f32m) + ldv_rw(lbp, (c << 8) + p, f32m);
    lnp[((b*128 + c) << 8) + p] = v;
  } else {
    int cc = c - 128;
    float v = (a - stats[32 + b]) * stats[48 + b] * ldv_rw(lwn, (cc << 8) + p, f32m) + ldv_rw(lbn, (cc << 8) + p, f32m);
    lnn[((b*128 + cc) << 8) + p] = v;
  }
}

// ---------------- VQ search v6b: 8-wave MFMA + prefetch + LDS merge --------
// launch_bounds(512,4): VGPR cap 128 (no spill; r17-verified).
// Block: 512 thr = 8 waves. Wave w: pixel group (w&3), code half (w>>2)
// (32 tiles of 16 codes). Per wave: 2 A-frags (32 px), prefetched B-frags
// from interleaved cbhl (hi +0 / lo +512 shorts per 2KB tile), C init =
// cn[col] -> D = cn - 2 z.c. Top-2 via fmed3; 16-lane shfl merge; cross-
// wave merge via LDS (strict < keeps lower-half j == np first-argmin).
// Cert eb = 3e-4*sqrt(zn)*cmax + 2e-6*zn, else np-bit-exact fallback.
template<int LEVELS>
__global__ __launch_bounds__(512, 4) void quantm_rw(
    const float* __restrict__ z, const short* __restrict__ cbhl,
    const float* __restrict__ cbn, const float* __restrict__ cmaxp,
    int* __restrict__ idxout, float* __restrict__ lossacc,
    int* __restrict__ cnt, int* __restrict__ list, int b_base)
{
  __shared__ float mgm1[4][4][8], mgm2[4][4][8];
  __shared__ int   mgj [4][4][8];
  __shared__ float red[4];

  const int tid  = threadIdx.x;
  const int lane = tid & 63, wid = tid >> 6;
  const int lc = lane & 15, gq = lane >> 4;
  const int pg = wid & 3, ch = wid >> 2;    // pixel group, code half
  const int bid  = blockIdx.x;
  const int bl   = bid >> 6;                // local batch
  const int rest = bid & 63;
  const int g = rest >> 1, half = rest & 1;
  int cb, wbase, wstep;
  if (LEVELS == 4){ cb = (g & 3)*8 + (g >> 2); wbase = (g >> 2)*1024 + (g & 3); wstep = 4; }
  else            { cb = g;                    wbase = g << 8;                  wstep = 1; }
  const int pb = half*128 + pg*32;

  // ---- load z rows, build -2z hi/lo bf16 A-fragments, partial |z|^2 ----
  bf16x8 ah0, al0, ah1, al1;
  float zn0 = 0.f, zn1 = 0.f;
  const int zoff = (((bl << 10) + cb) << 8) + pb + lc;
  const int e0 = gq << 3;
  #pragma unroll
  for (int i = 0; i < 8; ++i){
    const int zo = zoff + ((e0 + i) << 13);
    const float z0 = z[zo];
    const float z1 = z[zo + 16];
    zn0 += z0*z0; zn1 += z1*z1;
    const float s0 = -2.f*z0, s1 = -2.f*z1;
    const unsigned short h0 = f2bf_rw(s0);
    const unsigned short h1 = f2bf_rw(s1);
    ah0[i] = (short)h0; al0[i] = (short)f2bf_rw(s0 - bf2f_rw(h0));
    ah1[i] = (short)h1; al1[i] = (short)f2bf_rw(s1 - bf2f_rw(h1));
  }
  zn0 += __shfl_xor(zn0, 16); zn0 += __shfl_xor(zn0, 32);   // full zn for row lc
  zn1 += __shfl_xor(zn1, 16); zn1 += __shfl_xor(zn1, 32);

  float m1[8], m2[8]; int j1[8];
  #pragma unroll
  for (int s = 0; s < 8; ++s){ m1[s] = __builtin_inff(); m2[s] = __builtin_inff(); j1[s] = 0; }

  // interleaved table: wave's tiles T = ch*32 + t; shorts base:
  const short* bp  = cbhl + (ch << 15) + (lc << 5) + (gq << 3);
  const float* cnp = cbn + (ch << 9) + lc;

  bf16x8 bh  = *reinterpret_cast<const bf16x8*>(bp);
  bf16x8 blo = *reinterpret_cast<const bf16x8*>(bp + 512);
  float  cnv = cnp[0];

  #pragma unroll 2
  for (int t = 0; t < 32; ++t){
    const int tn = (t < 31) ? t + 1 : 31;      // clamped prefetch index
    const bf16x8 bhn  = *reinterpret_cast<const bf16x8*>(bp + (tn << 10));
    const bf16x8 blon = *reinterpret_cast<const bf16x8*>(bp + (tn << 10) + 512);
    const float  cnn  = cnp[tn << 4];

    f32x4 a0 = {cnv, cnv, cnv, cnv};
    f32x4 a1 = {cnv, cnv, cnv, cnv};
    a0 = __builtin_amdgcn_mfma_f32_16x16x32_bf16(ah0, bh,  a0, 0, 0, 0);
    a0 = __builtin_amdgcn_mfma_f32_16x16x32_bf16(ah0, blo, a0, 0, 0, 0);
    a0 = __builtin_amdgcn_mfma_f32_16x16x32_bf16(al0, bh,  a0, 0, 0, 0);
    a1 = __builtin_amdgcn_mfma_f32_16x16x32_bf16(ah1, bh,  a1, 0, 0, 0);
    a1 = __builtin_amdgcn_mfma_f32_16x16x32_bf16(ah1, blo, a1, 0, 0, 0);
    a1 = __builtin_amdgcn_mfma_f32_16x16x32_bf16(al1, bh,  a1, 0, 0, 0);

    const int jc = (((ch << 5) + t) << 4) + lc;
    #pragma unroll
    for (int r = 0; r < 4; ++r){
      const float d0 = a0[r];
      m2[r] = __builtin_amdgcn_fmed3f(d0, m1[r], m2[r]);
      const bool t0 = d0 < m1[r];
      j1[r] = t0 ? jc : j1[r]; m1[r] = t0 ? d0 : m1[r];
      const float d1 = a1[r];
      m2[4+r] = __builtin_amdgcn_fmed3f(d1, m1[4+r], m2[4+r]);
      const bool t1 = d1 < m1[4+r];
      j1[4+r] = t1 ? jc : j1[4+r]; m1[4+r] = t1 ? d1 : m1[4+r];
    }
    bh = bhn; blo = blon; cnv = cnn;
  }

  // ---- 16-lane top-2 merge (cols of each row live in one 16-lane group) ----
  #pragma unroll
  for (int k = 1; k < 16; k <<= 1){
    #pragma unroll
    for (int s = 0; s < 8; ++s){
      const float om1 = __shfl_xor(m1[s], k);
      const float om2 = __shfl_xor(m2[s], k);
      const int   oj  = __shfl_xor(j1[s], k);
      m2[s] = fminf(fminf(m2[s], om2), fmaxf(m1[s], om1));
      const bool tk = (om1 < m1[s]) || (om1 == m1[s] && oj < j1[s]);
      m1[s] = tk ? om1 : m1[s];
      j1[s] = tk ? oj  : j1[s];
    }
  }

  // ---- cross-wave merge: upper code-half -> LDS, lower merges ----
  if (wid >= 4 && lc == 0){
    #pragma unroll
    for (int s = 0; s < 8; ++s){
      mgm1[wid-4][gq][s] = m1[s];
      mgm2[wid-4][gq][s] = m2[s];
      mgj [wid-4][gq][s] = j1[s];
    }
  }
  __syncthreads();
  if (wid < 4){
    #pragma unroll
    for (int s = 0; s < 8; ++s){
      const float om1 = mgm1[wid][gq][s];
      const float om2 = mgm2[wid][gq][s];
      const int   oj  = mgj [wid][gq][s];
      m2[s] = fminf(fminf(m2[s], om2), fmaxf(m1[s], om1));
      const bool tk = om1 < m1[s];       // tie keeps lower half (smaller j)
      m1[s] = tk ? om1 : m1[s];
      j1[s] = tk ? oj  : j1[s];
    }

    // ---- finalize: cert test, idx write, loss, uncertain list ----
    const float cmax = cmaxp[0];
    float lossw = 0.f;
    #pragma unroll
    for (int f = 0; f < 2; ++f){
      #pragma unroll
      for (int r = 0; r < 4; ++r){
        const int s = f*4 + r;
        const int vrow = (gq << 2) + r;
        const float znv = __shfl(f == 0 ? zn0 : zn1, vrow);
        if (lc == 0){
          const int p  = pb + f*16 + vrow;
          const int gi = (b_base + bl)*8192 + wbase + p*wstep;
          idxout[gi] = j1[s];                    // provisional if uncertain
          const float eb = fmaf(2.0e-6f, znv, 3.0e-4f * sqrtf(znv) * cmax);
          if (m2[s] - m1[s] > eb){
            lossw += znv + m1[s];
          } else {
            const int pos = atomicAdd(cnt, 1);
            if (pos < 131072) list[pos] = (((bl << 5) | g) << 8) | p;
          }
        }
      }
    }
    lossw += __shfl_xor(lossw, 16);
    lossw += __shfl_xor(lossw, 32);
    if (lane == 0) red[wid] = lossw;
  }
  __syncthreads();
  if (tid == 0) atomicAdd(lossacc, red[0] + red[1] + red[2] + red[3]);
}

// ---------------- np-bit-exact f32 fallback for uncertain vectors ----------
// Replicates the reference rounding exactly: dot via ascending sequential
// fmaf (matches BLAS k-ascending FMA, r12-proven), zn via ascending
// sequential fmaf, d = (zn - 2*dot) + cn, first-min == lexicographic (d,j).
// 640-block grid, unroll-4 j-loop (4 indep chains), float4 cb loads,
// explicit zb[] broadcast hoist. Per-dot fmaf ORDER unchanged.
template<int LEVELS>
__global__ __launch_bounds__(256) void fb_rw(
    const float* __restrict__ z, const float* __restrict__ cb32,
    const float* __restrict__ cbn, const int* __restrict__ cnt,
    const int* __restrict__ list, int* __restrict__ idxout,
    float* __restrict__ lossacc, int b_base)
{
  const int lane = threadIdx.x & 63;
  const int wv = (blockIdx.x << 2) | (threadIdx.x >> 6);
  const int nw = gridDim.x << 2;
  int n = cnt[0];
  if (n > 131072) n = 131072;
  for (int it = wv; it < n; it += nw){
    const int id = list[it];
    const int p = id & 255, g = (id >> 8) & 31, bl = id >> 13;
    int cb, w;
    if (LEVELS == 4){ cb = (g & 3)*8 + (g >> 2); w = (g >> 2)*1024 + (p << 2) + (g & 3); }
    else            { cb = g;                    w = (g << 8) + p; }
    const int zoff = (((bl << 10) + cb) << 8) + p;
    float myz = 0.f;
    if (lane < 32) myz = z[zoff + (lane << 13)];
    // broadcast z to all lanes (register array; compile-time indexed)
    float zb[32];
    #pragma unroll
    for (int e = 0; e < 32; ++e) zb[e] = __shfl(myz, e);
    // zn: sequential ascending fmaf (matches np's accumulation order)
    float zn = 0.f;
    #pragma unroll
    for (int e = 0; e < 32; ++e) zn = fmaf(zb[e], zb[e], zn);
    float bd = __builtin_inff(); int bj = 0;
    #pragma unroll 4
    for (int jj = 0; jj < 16; ++jj){
      const int j = (jj << 6) + lane;
      const float4* c4 = reinterpret_cast<const float4*>(cb32 + (j << 5));
      float dot = 0.f;
      #pragma unroll
      for (int e4 = 0; e4 < 8; ++e4){
        const float4 cv = c4[e4];
        dot = fmaf(zb[(e4 << 2) + 0], cv.x, dot);
        dot = fmaf(zb[(e4 << 2) + 1], cv.y, dot);
        dot = fmaf(zb[(e4 << 2) + 2], cv.z, dot);
        dot = fmaf(zb[(e4 << 2) + 3], cv.w, dot);
      }
      const float d = (zn - 2.f*dot) + cbn[j];   // np's exact formula/rounding
      if (d < bd){ bd = d; bj = j; }
    }
    #pragma unroll
    for (int k = 1; k < 64; k <<= 1){
      const float od = __shfl_xor(bd, k);
      const int   oj = __shfl_xor(bj, k);
      if (od < bd || (od == bd && oj < bj)){ bd = od; bj = oj; }
    }
    if (lane == 0){
      idxout[(b_base + bl)*8192 + w] = bj;
      atomicAdd(lossacc, bd);                    // bd == |z-c|^2 (includes zn)
    }
  }
}

// ---------------- zq_p output (f32) ----------------
__global__ __launch_bounds__(256) void zqout_rw(const int* __restrict__ idxp,
    const float* __restrict__ cb32, float* __restrict__ out){
  int t = blockIdx.x * 256 + threadIdx.x;
  int l = t & 3, n = (t >> 2) & 2047, e = (t >> 13) & 31, b = t >> 18;
  int id = idxp[b*8192 + (n << 2) + l];
  out[t] = cb32[((id & 1023) << 5) + e];
}

// ---------------- zero hcat accum ----------------
__global__ __launch_bounds__(256) void zero_rw(float* __restrict__ p){
  p[blockIdx.x * 256 + threadIdx.x] = 0.f;
}

// ---------------- loss finalize ----------------
__global__ void loss_rw(const float* __restrict__ lossacc, float* __restrict__ out){
  if (threadIdx.x == 0 && blockIdx.x == 0)
    out[0] = 1.25f * (lossacc[0] + lossacc[1]) * (1.f/4194304.f);
}

extern "C" void kernel_launch(void* const* d_in, const int* in_sizes, int n_in,
                              void* d_out, int out_size, void* d_ws, size_t ws_size,
                              hipStream_t stream){
  (void)in_sizes; (void)n_in; (void)out_size;
  const void* x   = d_in[0];
  const void* ciw = d_in[1];
  const void* cib = d_in[2];
  const void* lwp = d_in[3];
  const void* lbp = d_in[4];
  const void* wpi = d_in[5];
  const void* bpi = d_in[6];
  const void* wpo = d_in[7];
  const void* bpo = d_in[8];
  const void* lwn = d_in[9];
  const void* lbn = d_in[10];
  const void* wni = d_in[11];
  const void* bni = d_in[12];
  const void* wno = d_in[13];
  const void* bno = d_in[14];
  const void* cbk = d_in[15];
  const void* cow = d_in[16];
  const void* cob = d_in[17];

  float* ws    = (float*)d_ws;
  float* flags = ws + FLAGS_OFF;
  float* loss  = ws + LOSS_OFF;
  float* stats = ws + STATS_OFF;
  float* cmaxp = ws + CMAX_OFF;
  float* cb32  = ws + CB32_OFF;
  float* cbn   = ws + CBN_OFF;
  int*   cnts  = (int*)(ws + CNT_OFF);
  int*   idxp  = (int*)(ws + IDXP_OFF);
  int*   idxn  = (int*)(ws + IDXN_OFF);
  short* cbhl  = (short*)(ws + CBHL_OFF);
  int*   list  = (int*)(ws + LIST_OFF);
  float* R2    = ws + R2_OFF;
  float* R3    = ws + R3_OFF;
  float* R1    = ws + R1_OFF;

  float* outO = (float*)d_out;
  float* outL = outO + 1048576;
  float* outZ = outO + 1048577;

  const size_t wsf = ws_size / 4;
  int CS = 4;
  if      (wsf >= (size_t)R1_OFF + 16u*262144u) CS = 16;
  else if (wsf >= (size_t)R1_OFF +  8u*262144u) CS = 8;

  detect_rw<<<1, 256, 0, stream>>>(cbk, ws);
  cbprep_rw<<<4, 256, 0, stream>>>(cbk, flags, cb32, cbn, cbhl, cmaxp);
  // h = conv_in(silu(x)) -> R1
  gemm2_rw<256,2,false,false,0><<<dim3(128,4), 256, 0, stream>>>(
      nullptr, nullptr, x, ciw, cib, nullptr, nullptr, nullptr, nullptr,
      R1, flags, 256, 256, 0, 0, 0, 0);
  stats_rw<<<32, 256, 0, stream>>>(R1, stats);
  ln_rw<<<4096, 256, 0, stream>>>(R1, lwp, lbp, lwn, lbn, stats, flags, R2, R3);
  // phylo: z chunks (R2 -> R1), MFMA quantize + np-exact fallback
  {
    int ci = 0;
    for (int c = 0; c < 16; c += CS, ++ci){
      gemm2_rw<128,0,true,false,0><<<dim3(CS*8,16), 256, 0, stream>>>(
          R2, nullptr, nullptr, wpi, bpi, nullptr, nullptr, nullptr, nullptr,
          R1, flags, 128, 1024, 0, c, 0, c);
      quantm_rw<4><<<CS*64, 512, 0, stream>>>(R1, cbhl, cbn, cmaxp,
                                              idxp, loss + 0, cnts + ci, list, c);
      fb_rw<4><<<640, 256, 0, stream>>>(R1, cb32, cbn, cnts + ci, list,
                                        idxp, loss + 0, c);
    }
  }
  // non-phylo
  {
    int ci = 4;
    for (int c = 0; c < 16; c += CS, ++ci){
      gemm2_rw<128,0,true,false,0><<<dim3(CS*8,16), 256, 0, stream>>>(
          R3, nullptr, nullptr, wni, bni, nullptr, nullptr, nullptr, nullptr,
          R1, flags, 128, 1024, 0, c, 0, c);
      quantm_rw<1><<<CS*64, 512, 0, stream>>>(R1, cbhl, cbn, cmaxp,
                                              idxn, loss + 1, cnts + ci, list, c);
      fb_rw<1><<<640, 256, 0, stream>>>(R1, cb32, cbn, cnts + ci, list,
                                        idxn, loss + 1, c);
    }
  }
  zqout_rw<<<16384, 256, 0, stream>>>(idxp, cb32, outZ);
  // hcat accum := 0 (R2 and R3 are contiguous: 4096*256 = 1048576 floats)
  zero_rw<<<4096, 256, 0, stream>>>(R2);
  // hout_p / hout_n: fused gather + split-K x4, atomic accum
  gemm2_rw<256,3,false,true,4><<<dim3(128,2,4), 256, 0, stream>>>(
      nullptr, nullptr, nullptr, wpo, nullptr, nullptr, nullptr, idxp, cb32,
      R2, flags, 1024, 128, 0, 0, 0, 0);
  gemm2_rw<256,3,false,true,1><<<dim3(128,2,4), 256, 0, stream>>>(
      nullptr, nullptr, nullptr, wno, nullptr, nullptr, nullptr, idxn, cb32,
      R3, flags, 1024, 128, 0, 0, 0, 0);
  // out = conv_out(silu(hcat + hout_bias))
  gemm2_rw<256,5,false,false,0><<<dim3(128,4), 256, 0, stream>>>(
      R2, R3, nullptr, cow, cob, bpo, bno, nullptr, nullptr,
      outO, flags, 256, 256, 0, 0, 0, 0);
  loss_rw<<<1, 64, 0, stream>>>(loss, outL);
}

// Round 14
// 515.810 us; speedup vs baseline: 1.1960x; 1.0330x over previous
//
#include <hip/hip_runtime.h>
#include <hip/hip_bf16.h>

// Round 26: dispatch-count reduction (17 -> 13), zero numerics changes.
// r25 re-established the r18 optimum (532.8). Honest tail cycle model
// (convs 5-10us, zgemms ~25, hout ~25-30) sums to ~150-200us vs measured
// ~410us tail -> ~200us unexplained == documented ~5-10us launch overhead
// x 17 dispatches. Retro-explains r22-r24: +3 dispatches == the +25us fit.
// Fusions: (1) detect into cbprep (local f32m, idempotent flags write;
// cmax as 4 per-block partials, quantm takes max-of-4 == same value;
// block0 zeroes loss/cnts); (2) zqout+zero (independent); (3) hout p+n
// one dispatch grid (128,2,8), runtime group branch (block-uniform), 2x
// resident blocks; (4) loss folded into conv_out. All retained kernels
// byte-identical to r25.
// Outputs (f32): out[1048576] | loss[1] | zq_p[4194304].

typedef float f32x4  __attribute__((ext_vector_type(4)));
typedef short bf16x8 __attribute__((ext_vector_type(8)));

__device__ __forceinline__ float silu_rw(float x){ return x / (1.f + expf(-x)); }
__device__ __forceinline__ float b2f_rw(__hip_bfloat16 v){ return __bfloat162float(v); }
__device__ __forceinline__ float ldv_rw(const void* p, int i, int f32m){
  if (f32m) return ((const float*)p)[i];
  return b2f_rw(((const __hip_bfloat16*)p)[i]);
}
__device__ __forceinline__ unsigned short f2bf_rw(float x){   // f32 -> bf16 RNE
  unsigned u = __float_as_uint(x);
  unsigned r = ((u >> 16) & 1u) + 0x7FFFu;
  return (unsigned short)((u + r) >> 16);
}
__device__ __forceinline__ float bf2f_rw(unsigned short h){
  return __uint_as_float(((unsigned)h) << 16);
}

// ---------------- workspace layout (float offsets) ----------------
#define FLAGS_OFF 0
#define LOSS_OFF  4
#define STATS_OFF 8
#define CNT_OFF   72         // 8 ints: fallback counters per chunk
#define CMAX_OFF  80         // cmaxp[0..3]: per-cbprep-block max |c|
#define CB32_OFF  128        // 1024x32 f32
#define CBN_OFF   32896      // 1024
#define IDXP_OFF  33984      // 131072 int
#define IDXN_OFF  165056     // 131072 int
#define CBHL_OFF  296192     // interleaved hi/lo bf16 table (32768 f32 slots)
#define LIST_OFF  328960     // 131072 int (uncertain list, reused per chunk)
#define R2_OFF    460032     // lnp -> hcat_p accum (524288)
#define R3_OFF    984320     // lnn -> hcat_n accum (524288)
#define R1_OFF    1508608    // h (1048576) / z chunks (CS*262144)

// ------ cbprep v3: fused dtype-detect + codebook prep + accumulator init ---
// Each block derives f32m locally (same 32768-u16 scan as old detect_rw);
// flags written idempotently by every block. Per-block |c| max partial to
// cmaxp[blockIdx.x] (quantm takes max of 4 == old atomicMax value).
// Block 0 zeroes loss[0..1] and cnts[0..7].
__global__ __launch_bounds__(256) void cbprep_rw(const void* cbv,
    float* cb32, float* cbn, short* cbhl, float* wsb){
  __shared__ int bad_s;
  __shared__ float mx[256];
  const int tid = threadIdx.x;
  if (tid == 0) bad_s = 0;
  __syncthreads();
  const unsigned short* u = (const unsigned short*)cbv;
  int local = 0;
  for (int i = tid; i < 32768; i += 256){
    unsigned e = (u[i] >> 7) & 0xFF;
    if (e >= 126) local = 1;
  }
  if (local) bad_s = 1;
  __syncthreads();
  const int f32m = bad_s;

  const int j = blockIdx.x * 256 + tid;          // grid 4 -> j in [0,1024)
  float s = 0.f;
  const int tb = ((j >> 4) << 10) + ((j & 15) << 5);
  for (int e = 0; e < 32; ++e){
    float v = ldv_rw(cbv, j*32 + e, f32m);
    cb32[j*32 + e] = v;
    unsigned short h = f2bf_rw(v);
    cbhl[tb + e]       = (short)h;
    cbhl[tb + e + 512] = (short)f2bf_rw(v - bf2f_rw(h));
    s += v*v;
  }
  cbn[j] = s;
  mx[tid] = sqrtf(s);
  __syncthreads();
  for (int st = 128; st > 0; st >>= 1){
    if (tid < st) mx[tid] = fmaxf(mx[tid], mx[tid + st]);
    __syncthreads();
  }
  if (tid == 0){
    wsb[CMAX_OFF + blockIdx.x] = mx[0];
    wsb[FLAGS_OFF] = f32m ? 1.f : 0.f;           // idempotent across blocks
    if (blockIdx.x == 0){
      wsb[LOSS_OFF] = 0.f; wsb[LOSS_OFF + 1] = 0.f;
      int* c = (int*)(wsb + CNT_OFF);
      #pragma unroll
      for (int k = 0; k < 8; ++k) c[k] = 0;
    }
  }
}

// ---------------- gemm2 (r11, verified): 32px x 64out tiles ----------------
// Instantiated here only for INMODE 0 (z-gemm) and 2 (conv_in).
template<int KCH, int INMODE, bool OUTSILU, bool ATOMIC, int LEVELS>
__global__ __launch_bounds__(256) void gemm2_rw(
    const float* __restrict__ inF, const float* __restrict__ inF2,
    const void* __restrict__ inV,
    const void* __restrict__ W, const void* __restrict__ biasO,
    const void* __restrict__ sbA, const void* __restrict__ sbB,
    const int* __restrict__ idxin, const float* __restrict__ cb32,
    float* __restrict__ outF, const float* __restrict__ flags,
    int KDIM, int OUTC, int o_off, int b_base, int ib_sub, int ob_sub)
{
  __shared__ float As[32][32];
  __shared__ float Bs[32][68];

  const int f32m = (flags[0] != 0.f);
  const int t  = threadIdx.x;
  const int q0 = (blockIdx.x << 5) + (b_base << 8);
  const int b  = q0 >> 8;
  const int p0 = q0 & 255;
  const int o0 = blockIdx.y << 6;
  const int k0base = blockIdx.z * KCH;
  const int tx = t & 15, ty = t >> 4;
  float acc[4][2] = {};

  const int sch = t >> 3, spx = (t & 7) << 2;

  for (int kc = 0; kc < KCH; kc += 32){
    const int k0 = k0base + kc;
    if constexpr (INMODE == 0){
      const float4 v = *reinterpret_cast<const float4*>(
          &inF[(((b - ib_sub)*KDIM + k0 + sch) << 8) + p0 + spx]);
      *reinterpret_cast<float4*>(&As[sch][spx]) = v;
    } else { // INMODE 2
      if (f32m){
        const float* xf = (const float*)inV;
        float4 v = *reinterpret_cast<const float4*>(&xf[((b*KDIM + k0 + sch) << 8) + p0 + spx]);
        v.x = silu_rw(v.x); v.y = silu_rw(v.y); v.z = silu_rw(v.z); v.w = silu_rw(v.w);
        *reinterpret_cast<float4*>(&As[sch][spx]) = v;
      } else {
        const __hip_bfloat16* xb = (const __hip_bfloat16*)inV;
        const int off = ((b*KDIM + k0 + sch) << 8) + p0 + spx;
        #pragma unroll
        for (int j = 0; j < 4; ++j) As[sch][spx + j] = silu_rw(b2f_rw(xb[off + j]));
      }
    }
    if (f32m){
      const float* Wf = (const float*)W;
      #pragma unroll
      for (int r = 0; r < 8; ++r){
        int ii = t + (r << 8); int oo = ii >> 5, cc = ii & 31;
        Bs[cc][oo] = Wf[(o0 + oo)*KDIM + k0 + cc];
      }
    } else {
      const __hip_bfloat16* Wb = (const __hip_bfloat16*)W;
      #pragma unroll
      for (int r = 0; r < 8; ++r){
        int ii = t + (r << 8); int oo = ii >> 5, cc = ii & 31;
        Bs[cc][oo] = b2f_rw(Wb[(o0 + oo)*KDIM + k0 + cc]);
      }
    }
    __syncthreads();
    #pragma unroll
    for (int kk = 0; kk < 32; ++kk){
      const float2 a = *reinterpret_cast<const float2*>(&As[kk][tx << 1]);
      const float4 w = *reinterpret_cast<const float4*>(&Bs[kk][ty << 2]);
      acc[0][0] += w.x*a.x; acc[0][1] += w.x*a.y;
      acc[1][0] += w.y*a.x; acc[1][1] += w.y*a.y;
      acc[2][0] += w.z*a.x; acc[2][1] += w.z*a.y;
      acc[3][0] += w.w*a.x; acc[3][1] += w.w*a.y;
    }
    __syncthreads();
  }
  #pragma unroll
  for (int i = 0; i < 4; ++i){
    const int o = o0 + (ty << 2) + i;
    const int base = (((b - ob_sub)*OUTC + o_off + o) << 8) + p0 + (tx << 1);
    const float bb = ldv_rw(biasO, o, f32m);
    float v0 = acc[i][0] + bb, v1 = acc[i][1] + bb;
    if constexpr (OUTSILU){ v0 = silu_rw(v0); v1 = silu_rw(v1); }
    *reinterpret_cast<float2*>(&outF[base]) = make_float2(v0, v1);
  }
}

// ------- houtg: merged hout_p + hout_n (r18 INMODE3+ATOMIC semantics) ------
// Grid (128, 2, 8): z>>2 selects group (0=p LEVELS4, 1=n LEVELS1), z&3 is
// the split-K slice (k0 = kz*256 of KDIM 1024). Per-thread work identical
// to the r18/r25 gemm2<256,3,false,true,L> instantiations.
__global__ __launch_bounds__(256) void houtg_rw(
    const int* __restrict__ idxp, const int* __restrict__ idxn,
    const void* __restrict__ Wp, const void* __restrict__ Wn,
    const float* __restrict__ cb32, float* __restrict__ R2,
    float* __restrict__ R3, const float* __restrict__ flags)
{
  __shared__ float As[32][32];
  __shared__ float Bs[32][68];
  __shared__ int   IdxS[32][32];

  const int f32m = (flags[0] != 0.f);
  const int grp = blockIdx.z >> 2;
  const int* __restrict__ idxin = grp ? idxn : idxp;
  const void* __restrict__ W    = grp ? Wn : Wp;
  float* __restrict__ outF      = grp ? R3 : R2;

  const int t  = threadIdx.x;
  const int q0 = blockIdx.x << 5;
  const int b  = q0 >> 8;
  const int p0 = q0 & 255;
  const int o0 = blockIdx.y << 6;
  const int k0base = (blockIdx.z & 3) * 256;
  const int tx = t & 15, ty = t >> 4;
  float acc[4][2] = {};

  const int sch = t >> 3, spx = (t & 7) << 2;

  #pragma unroll
  for (int j = 0; j < 4; ++j){
    const int p = p0 + spx + j;
    if (grp == 0){                      // LEVELS 4 (phylo)
      const int l = sch >> 3, kp = sch & 7;
      IdxS[sch][spx + j] = idxin[b*8192 + (((kp << 8) + p) << 2) + l];
    } else {                            // LEVELS 1
      IdxS[sch][spx + j] = idxin[b*8192 + (sch << 8) + p];
    }
  }
  __syncthreads();

  for (int kc = 0; kc < 256; kc += 32){
    const int k0 = k0base + kc;
    const int e = k0 >> 5;
    #pragma unroll
    for (int j = 0; j < 4; ++j)
      As[sch][spx + j] = cb32[((IdxS[sch][spx + j] & 1023) << 5) + e];
    if (f32m){
      const float* Wf = (const float*)W;
      #pragma unroll
      for (int r = 0; r < 8; ++r){
        int ii = t + (r << 8); int oo = ii >> 5, cc = ii & 31;
        Bs[cc][oo] = Wf[(o0 + oo)*1024 + k0 + cc];
      }
    } else {
      const __hip_bfloat16* Wb = (const __hip_bfloat16*)W;
      #pragma unroll
      for (int r = 0; r < 8; ++r){
        int ii = t + (r << 8); int oo = ii >> 5, cc = ii & 31;
        Bs[cc][oo] = b2f_rw(Wb[(o0 + oo)*1024 + k0 + cc]);
      }
    }
    __syncthreads();
    #pragma unroll
    for (int kk = 0; kk < 32; ++kk){
      const float2 a = *reinterpret_cast<const float2*>(&As[kk][tx << 1]);
      const float4 w = *reinterpret_cast<const float4*>(&Bs[kk][ty << 2]);
      acc[0][0] += w.x*a.x; acc[0][1] += w.x*a.y;
      acc[1][0] += w.y*a.x; acc[1][1] += w.y*a.y;
      acc[2][0] += w.z*a.x; acc[2][1] += w.z*a.y;
      acc[3][0] += w.w*a.x; acc[3][1] += w.w*a.y;
    }
    __syncthreads();
  }
  #pragma unroll
  for (int i = 0; i < 4; ++i){
    const int o = o0 + (ty << 2) + i;
    const int base = ((b*128 + o) << 8) + p0 + (tx << 1);
    atomicAdd(&outF[base + 0], acc[i][0]);
    atomicAdd(&outF[base + 1], acc[i][1]);
  }
}

// ------- coutf: conv_out (r18 INMODE5 semantics) + fused loss finalize -----
__global__ __launch_bounds__(256) void coutf_rw(
    const float* __restrict__ inF, const float* __restrict__ inF2,
    const void* __restrict__ W, const void* __restrict__ biasO,
    const void* __restrict__ sbA, const void* __restrict__ sbB,
    float* __restrict__ outF, const float* __restrict__ flags,
    const float* __restrict__ lossacc, float* __restrict__ outL)
{
  __shared__ float As[32][32];
  __shared__ float Bs[32][68];

  const int f32m = (flags[0] != 0.f);
  const int t  = threadIdx.x;
  const int q0 = blockIdx.x << 5;
  const int b  = q0 >> 8;
  const int p0 = q0 & 255;
  const int o0 = blockIdx.y << 6;
  const int tx = t & 15, ty = t >> 4;
  float acc[4][2] = {};

  const int sch = t >> 3, spx = (t & 7) << 2;

  if (blockIdx.x == 0 && blockIdx.y == 0 && t == 0)
    outL[0] = 1.25f * (lossacc[0] + lossacc[1]) * (1.f/4194304.f);

  for (int kc = 0; kc < 256; kc += 32){
    const int k0 = kc;
    const float* src = (k0 < 128) ? inF : inF2;
    const void* sb   = (k0 < 128) ? sbA : sbB;
    const int kh = k0 & 127;
    const float bb = ldv_rw(sb, kh + sch, f32m);
    float4 v = *reinterpret_cast<const float4*>(&src[((b*128 + kh + sch) << 8) + p0 + spx]);
    v.x = silu_rw(v.x + bb); v.y = silu_rw(v.y + bb);
    v.z = silu_rw(v.z + bb); v.w = silu_rw(v.w + bb);
    *reinterpret_cast<float4*>(&As[sch][spx]) = v;
    if (f32m){
      const float* Wf = (const float*)W;
      #pragma unroll
      for (int r = 0; r < 8; ++r){
        int ii = t + (r << 8); int oo = ii >> 5, cc = ii & 31;
        Bs[cc][oo] = Wf[(o0 + oo)*256 + k0 + cc];
      }
    } else {
      const __hip_bfloat16* Wb = (const __hip_bfloat16*)W;
      #pragma unroll
      for (int r = 0; r < 8; ++r){
        int ii = t + (r << 8); int oo = ii >> 5, cc = ii & 31;
        Bs[cc][oo] = b2f_rw(Wb[(o0 + oo)*256 + k0 + cc]);
      }
    }
    __syncthreads();
    #pragma unroll
    for (int kk = 0; kk < 32; ++kk){
      const float2 a = *reinterpret_cast<const float2*>(&As[kk][tx << 1]);
      const float4 w = *reinterpret_cast<const float4*>(&Bs[kk][ty << 2]);
      acc[0][0] += w.x*a.x; acc[0][1] += w.x*a.y;
      acc[1][0] += w.y*a.x; acc[1][1] += w.y*a.y;
      acc[2][0] += w.z*a.x; acc[2][1] += w.z*a.y;
      acc[3][0] += w.w*a.x; acc[3][1] += w.w*a.y;
    }
    __syncthreads();
  }
  #pragma unroll
  for (int i = 0; i < 4; ++i){
    const int o = o0 + (ty << 2) + i;
    const int base = ((b*256 + o) << 8) + p0 + (tx << 1);
    const float bb = ldv_rw(biasO, o, f32m);
    *reinterpret_cast<float2*>(&outF[base]) =
        make_float2(acc[i][0] + bb, acc[i][1] + bb);
  }
}

// ---------------- per-sample LN stats over silu(h_half) ----------------
__global__ __launch_bounds__(256) void stats_rw(const float* __restrict__ h, float* __restrict__ stats){
  const int b = blockIdx.x >> 1, half = blockIdx.x & 1;
  const float* base = h + ((b*256 + half*128) << 8);
  float s = 0.f, s2 = 0.f;
  for (int i = threadIdx.x; i < 32768; i += 256){
    float a = silu_rw(base[i]);
    s += a; s2 += a*a;
  }
  __shared__ float sh[2][256];
  sh[0][threadIdx.x] = s; sh[1][threadIdx.x] = s2;
  __syncthreads();
  for (int st = 128; st > 0; st >>= 1){
    if (threadIdx.x < st){
      sh[0][threadIdx.x] += sh[0][threadIdx.x + st];
      sh[1][threadIdx.x] += sh[1][threadIdx.x + st];
    }
    __syncthreads();
  }
  if (threadIdx.x == 0){
    float mu  = sh[0][0] * (1.f/32768.f);
    float var = sh[1][0] * (1.f/32768.f) - mu*mu;
    stats[half*32 + b]      = mu;
    stats[half*32 + 16 + b] = 1.f / sqrtf(var + 1e-5f);
  }
}

// ---------------- LN apply ----------------
__global__ __launch_bounds__(256) void ln_rw(const float* __restrict__ h,
    const void* lwp, const void* lbp, const void* lwn, const void* lbn,
    const float* __restrict__ stats, const float* __restrict__ flags,
    float* __restrict__ lnp, float* __restrict__ lnn){
  const int f32m = (flags[0] != 0.f);
  int i = blockIdx.x * 256 + threadIdx.x;
  int b = i >> 16, c = (i >> 8) & 255, p = i & 255;
  float a = silu_rw(h[i]);
  if (c < 128){
    float v = (a - stats[b]) * stats[16 + b] * ldv_rw(lwp, (c << 8) + p, f32m) + ldv_rw(lbp, (c << 8) + p, f32m);
    lnp[((b*128 + c) << 8) + p] = v;
  } else {
    int cc = c - 128;
    float v = (a - stats[32 + b]) * stats[48 + b] * ldv_rw(lwn, (cc << 8) + p, f32m) + ldv_rw(lbn, (cc << 8) + p, f32m);
    lnn[((b*128 + cc) << 8) + p] = v;
  }
}

// ---------------- VQ search v6b (r18-exact; cmax = max of 4 partials) ------
template<int LEVELS>
__global__ __launch_bounds__(512, 4) void quantm_rw(
    const float* __restrict__ z, const short* __restrict__ cbhl,
    const float* __restrict__ cbn, const float* __restrict__ cmaxp,
    int* __restrict__ idxout, float* __restrict__ lossacc,
    int* __restrict__ cnt, int* __restrict__ list, int b_base)
{
  __shared__ float mgm1[4][4][8], mgm2[4][4][8];
  __shared__ int   mgj [4][4][8];
  __shared__ float red[4];

  const int tid  = threadIdx.x;
  const int lane = tid & 63, wid = tid >> 6;
  const int lc = lane & 15, gq = lane >> 4;
  const int pg = wid & 3, ch = wid >> 2;    // pixel group, code half
  const int bid  = blockIdx.x;
  const int bl   = bid >> 6;                // local batch
  const int rest = bid & 63;
  const int g = rest >> 1, half = rest & 1;
  int cb, wbase, wstep;
  if (LEVELS == 4){ cb = (g & 3)*8 + (g >> 2); wbase = (g >> 2)*1024 + (g & 3); wstep = 4; }
  else            { cb = g;                    wbase = g << 8;                  wstep = 1; }
  const int pb = half*128 + pg*32;

  // ---- load z rows, build -2z hi/lo bf16 A-fragments, partial |z|^2 ----
  bf16x8 ah0, al0, ah1, al1;
  float zn0 = 0.f, zn1 = 0.f;
  const int zoff = (((bl << 10) + cb) << 8) + pb + lc;
  const int e0 = gq << 3;
  #pragma unroll
  for (int i = 0; i < 8; ++i){
    const int zo = zoff + ((e0 + i) << 13);
    const float z0 = z[zo];
    const float z1 = z[zo + 16];
    zn0 += z0*z0; zn1 += z1*z1;
    const float s0 = -2.f*z0, s1 = -2.f*z1;
    const unsigned short h0 = f2bf_rw(s0);
    const unsigned short h1 = f2bf_rw(s1);
    ah0[i] = (short)h0; al0[i] = (short)f2bf_rw(s0 - bf2f_rw(h0));
    ah1[i] = (short)h1; al1[i] = (short)f2bf_rw(s1 - bf2f_rw(h1));
  }
  zn0 += __shfl_xor(zn0, 16); zn0 += __shfl_xor(zn0, 32);   // full zn for row lc
  zn1 += __shfl_xor(zn1, 16); zn1 += __shfl_xor(zn1, 32);

  float m1[8], m2[8]; int j1[8];
  #pragma unroll
  for (int s = 0; s < 8; ++s){ m1[s] = __builtin_inff(); m2[s] = __builtin_inff(); j1[s] = 0; }

  // interleaved table: wave's tiles T = ch*32 + t; shorts base:
  const short* bp  = cbhl + (ch << 15) + (lc << 5) + (gq << 3);
  const float* cnp = cbn + (ch << 9) + lc;

  bf16x8 bh  = *reinterpret_cast<const bf16x8*>(bp);
  bf16x8 blo = *reinterpret_cast<const bf16x8*>(bp + 512);
  float  cnv = cnp[0];

  #pragma unroll 2
  for (int t = 0; t < 32; ++t){
    const int tn = (t < 31) ? t + 1 : 31;      // clamped prefetch index
    const bf16x8 bhn  = *reinterpret_cast<const bf16x8*>(bp + (tn << 10));
    const bf16x8 blon = *reinterpret_cast<const bf16x8*>(bp + (tn << 10) + 512);
    const float  cnn  = cnp[tn << 4];

    f32x4 a0 = {cnv, cnv, cnv, cnv};
    f32x4 a1 = {cnv, cnv, cnv, cnv};
    a0 = __builtin_amdgcn_mfma_f32_16x16x32_bf16(ah0, bh,  a0, 0, 0, 0);
    a0 = __builtin_amdgcn_mfma_f32_16x16x32_bf16(ah0, blo, a0, 0, 0, 0);
    a0 = __builtin_amdgcn_mfma_f32_16x16x32_bf16(al0, bh,  a0, 0, 0, 0);
    a1 = __builtin_amdgcn_mfma_f32_16x16x32_bf16(ah1, bh,  a1, 0, 0, 0);
    a1 = __builtin_amdgcn_mfma_f32_16x16x32_bf16(ah1, blo, a1, 0, 0, 0);
    a1 = __builtin_amdgcn_mfma_f32_16x16x32_bf16(al1, bh,  a1, 0, 0, 0);

    const int jc = (((ch << 5) + t) << 4) + lc;
    #pragma unroll
    for (int r = 0; r < 4; ++r){
      const float d0 = a0[r];
      m2[r] = __builtin_amdgcn_fmed3f(d0, m1[r], m2[r]);
      const bool t0 = d0 < m1[r];
      j1[r] = t0 ? jc : j1[r]; m1[r] = t0 ? d0 : m1[r];
      const float d1 = a1[r];
      m2[4+r] = __builtin_amdgcn_fmed3f(d1, m1[4+r], m2[4+r]);
      const bool t1 = d1 < m1[4+r];
      j1[4+r] = t1 ? jc : j1[4+r]; m1[4+r] = t1 ? d1 : m1[4+r];
    }
    bh = bhn; blo = blon; cnv = cnn;
  }

  // ---- 16-lane top-2 merge (cols of each row live in one 16-lane group) ----
  #pragma unroll
  for (int k = 1; k < 16; k <<= 1){
    #pragma unroll
    for (int s = 0; s < 8; ++s){
      const float om1 = __shfl_xor(m1[s], k);
      const float om2 = __shfl_xor(m2[s], k);
      const int   oj  = __shfl_xor(j1[s], k);
      m2[s] = fminf(fminf(m2[s], om2), fmaxf(m1[s], om1));
      const bool tk = (om1 < m1[s]) || (om1 == m1[s] && oj < j1[s]);
      m1[s] = tk ? om1 : m1[s];
      j1[s] = tk ? oj  : j1[s];
    }
  }

  // ---- cross-wave merge: upper code-half -> LDS, lower merges ----
  if (wid >= 4 && lc == 0){
    #pragma unroll
    for (int s = 0; s < 8; ++s){
      mgm1[wid-4][gq][s] = m1[s];
      mgm2[wid-4][gq][s] = m2[s];
      mgj [wid-4][gq][s] = j1[s];
    }
  }
  __syncthreads();
  if (wid < 4){
    #pragma unroll
    for (int s = 0; s < 8; ++s){
      const float om1 = mgm1[wid][gq][s];
      const float om2 = mgm2[wid][gq][s];
      const int   oj  = mgj [wid][gq][s];
      m2[s] = fminf(fminf(m2[s], om2), fmaxf(m1[s], om1));
      const bool tk = om1 < m1[s];       // tie keeps lower half (smaller j)
      m1[s] = tk ? om1 : m1[s];
      j1[s] = tk ? oj  : j1[s];
    }

    // ---- finalize: cert test, idx write, loss, uncertain list ----
    const float cmax = fmaxf(fmaxf(cmaxp[0], cmaxp[1]),
                             fmaxf(cmaxp[2], cmaxp[3]));
    float lossw = 0.f;
    #pragma unroll
    for (int f = 0; f < 2; ++f){
      #pragma unroll
      for (int r = 0; r < 4; ++r){
        const int s = f*4 + r;
        const int vrow = (gq << 2) + r;
        const float znv = __shfl(f == 0 ? zn0 : zn1, vrow);
        if (lc == 0){
          const int p  = pb + f*16 + vrow;
          const int gi = (b_base + bl)*8192 + wbase + p*wstep;
          idxout[gi] = j1[s];                    // provisional if uncertain
          const float eb = fmaf(2.0e-6f, znv, 3.0e-4f * sqrtf(znv) * cmax);
          if (m2[s] - m1[s] > eb){
            lossw += znv + m1[s];
          } else {
            const int pos = atomicAdd(cnt, 1);
            if (pos < 131072) list[pos] = (((bl << 5) | g) << 8) | p;
          }
        }
      }
    }
    lossw += __shfl_xor(lossw, 16);
    lossw += __shfl_xor(lossw, 32);
    if (lane == 0) red[wid] = lossw;
  }
  __syncthreads();
  if (tid == 0) atomicAdd(lossacc, red[0] + red[1] + red[2] + red[3]);
}

// ---------------- np-bit-exact f32 fallback for uncertain vectors ----------
template<int LEVELS>
__global__ __launch_bounds__(256) void fb_rw(
    const float* __restrict__ z, const float* __restrict__ cb32,
    const float* __restrict__ cbn, const int* __restrict__ cnt,
    const int* __restrict__ list, int* __restrict__ idxout,
    float* __restrict__ lossacc, int b_base)
{
  const int lane = threadIdx.x & 63;
  const int wv = (blockIdx.x << 2) | (threadIdx.x >> 6);
  const int nw = gridDim.x << 2;
  int n = cnt[0];
  if (n > 131072) n = 131072;
  for (int it = wv; it < n; it += nw){
    const int id = list[it];
    const int p = id & 255, g = (id >> 8) & 31, bl = id >> 13;
    int cb, w;
    if (LEVELS == 4){ cb = (g & 3)*8 + (g >> 2); w = (g >> 2)*1024 + (p << 2) + (g & 3); }
    else            { cb = g;                    w = (g << 8) + p; }
    const int zoff = (((bl << 10) + cb) << 8) + p;
    float myz = 0.f;
    if (lane < 32) myz = z[zoff + (lane << 13)];
    // broadcast z to all lanes (register array; compile-time indexed)
    float zb[32];
    #pragma unroll
    for (int e = 0; e < 32; ++e) zb[e] = __shfl(myz, e);
    // zn: sequential ascending fmaf (matches np's accumulation order)
    float zn = 0.f;
    #pragma unroll
    for (int e = 0; e < 32; ++e) zn = fmaf(zb[e], zb[e], zn);
    float bd = __builtin_inff(); int bj = 0;
    #pragma unroll 4
    for (int jj = 0; jj < 16; ++jj){
      const int j = (jj << 6) + lane;
      const float4* c4 = reinterpret_cast<const float4*>(cb32 + (j << 5));
      float dot = 0.f;
      #pragma unroll
      for (int e4 = 0; e4 < 8; ++e4){
        const float4 cv = c4[e4];
        dot = fmaf(zb[(e4 << 2) + 0], cv.x, dot);
        dot = fmaf(zb[(e4 << 2) + 1], cv.y, dot);
        dot = fmaf(zb[(e4 << 2) + 2], cv.z, dot);
        dot = fmaf(zb[(e4 << 2) + 3], cv.w, dot);
      }
      const float d = (zn - 2.f*dot) + cbn[j];   // np's exact formula/rounding
      if (d < bd){ bd = d; bj = j; }
    }
    #pragma unroll
    for (int k = 1; k < 64; k <<= 1){
      const float od = __shfl_xor(bd, k);
      const int   oj = __shfl_xor(bj, k);
      if (od < bd || (od == bd && oj < bj)){ bd = od; bj = oj; }
    }
    if (lane == 0){
      idxout[(b_base + bl)*8192 + w] = bj;
      atomicAdd(lossacc, bd);                    // bd == |z-c|^2 (includes zn)
    }
  }
}

// -------- zqz: merged zq_p output + hcat-accum zero (independent work) -----
__global__ __launch_bounds__(256) void zqz_rw(const int* __restrict__ idxp,
    const float* __restrict__ cb32, float* __restrict__ out,
    float* __restrict__ acc0){
  const int bid = blockIdx.x;
  if (bid < 16384){
    int t = bid * 256 + threadIdx.x;
    int l = t & 3, n = (t >> 2) & 2047, e = (t >> 13) & 31, b = t >> 18;
    int id = idxp[b*8192 + (n << 2) + l];
    out[t] = cb32[((id & 1023) << 5) + e];
  } else {
    acc0[(bid - 16384) * 256 + threadIdx.x] = 0.f;
  }
}

extern "C" void kernel_launch(void* const* d_in, const int* in_sizes, int n_in,
                              void* d_out, int out_size, void* d_ws, size_t ws_size,
                              hipStream_t stream){
  (void)in_sizes; (void)n_in; (void)out_size;
  const void* x   = d_in[0];
  const void* ciw = d_in[1];
  const void* cib = d_in[2];
  const void* lwp = d_in[3];
  const void* lbp = d_in[4];
  const void* wpi = d_in[5];
  const void* bpi = d_in[6];
  const void* wpo = d_in[7];
  const void* bpo = d_in[8];
  const void* lwn = d_in[9];
  const void* lbn = d_in[10];
  const void* wni = d_in[11];
  const void* bni = d_in[12];
  const void* wno = d_in[13];
  const void* bno = d_in[14];
  const void* cbk = d_in[15];
  const void* cow = d_in[16];
  const void* cob = d_in[17];

  float* ws    = (float*)d_ws;
  float* flags = ws + FLAGS_OFF;
  float* loss  = ws + LOSS_OFF;
  float* stats = ws + STATS_OFF;
  float* cmaxp = ws + CMAX_OFF;
  float* cb32  = ws + CB32_OFF;
  float* cbn   = ws + CBN_OFF;
  int*   cnts  = (int*)(ws + CNT_OFF);
  int*   idxp  = (int*)(ws + IDXP_OFF);
  int*   idxn  = (int*)(ws + IDXN_OFF);
  short* cbhl  = (short*)(ws + CBHL_OFF);
  int*   list  = (int*)(ws + LIST_OFF);
  float* R2    = ws + R2_OFF;
  float* R3    = ws + R3_OFF;
  float* R1    = ws + R1_OFF;

  float* outO = (float*)d_out;
  float* outL = outO + 1048576;
  float* outZ = outO + 1048577;

  const size_t wsf = ws_size / 4;
  int CS = 4;
  if      (wsf >= (size_t)R1_OFF + 16u*262144u) CS = 16;
  else if (wsf >= (size_t)R1_OFF +  8u*262144u) CS = 8;

  // fused detect + codebook prep + accumulator init
  cbprep_rw<<<4, 256, 0, stream>>>(cbk, cb32, cbn, cbhl, ws);
  // h = conv_in(silu(x)) -> R1
  gemm2_rw<256,2,false,false,0><<<dim3(128,4), 256, 0, stream>>>(
      nullptr, nullptr, x, ciw, cib, nullptr, nullptr, nullptr, nullptr,
      R1, flags, 256, 256, 0, 0, 0, 0);
  stats_rw<<<32, 256, 0, stream>>>(R1, stats);
  ln_rw<<<4096, 256, 0, stream>>>(R1, lwp, lbp, lwn, lbn, stats, flags, R2, R3);
  // phylo: z chunks (R2 -> R1), MFMA quantize + np-exact fallback
  {
    int ci = 0;
    for (int c = 0; c < 16; c += CS, ++ci){
      gemm2_rw<128,0,true,false,0><<<dim3(CS*8,16), 256, 0, stream>>>(
          R2, nullptr, nullptr, wpi, bpi, nullptr, nullptr, nullptr, nullptr,
          R1, flags, 128, 1024, 0, c, 0, c);
      quantm_rw<4><<<CS*64, 512, 0, stream>>>(R1, cbhl, cbn, cmaxp,
                                              idxp, loss + 0, cnts + ci, list, c);
      fb_rw<4><<<640, 256, 0, stream>>>(R1, cb32, cbn, cnts + ci, list,
                                        idxp, loss + 0, c);
    }
  }
  // non-phylo
  {
    int ci = 4;
    for (int c = 0; c < 16; c += CS, ++ci){
      gemm2_rw<128,0,true,false,0><<<dim3(CS*8,16), 256, 0, stream>>>(
          R3, nullptr, nullptr, wni, bni, nullptr, nullptr, nullptr, nullptr,
          R1, flags, 128, 1024, 0, c, 0, c);
      quantm_rw<1><<<CS*64, 512, 0, stream>>>(R1, cbhl, cbn, cmaxp,
                                              idxn, loss + 1, cnts + ci, list, c);
      fb_rw<1><<<640, 256, 0, stream>>>(R1, cb32, cbn, cnts + ci, list,
                                        idxn, loss + 1, c);
    }
  }
  // zq_p output + hcat accum zero (merged; R2/R3 contiguous 1048576 floats)
  zqz_rw<<<20480, 256, 0, stream>>>(idxp, cb32, outZ, R2);
  // hout_p + hout_n merged: fused gather + split-K x4 x 2 groups, atomic
  houtg_rw<<<dim3(128, 2, 8), 256, 0, stream>>>(
      idxp, idxn, wpo, wno, cb32, R2, R3, flags);
  // out = conv_out(silu(hcat + hout_bias)) + fused loss finalize
  coutf_rw<<<dim3(128, 4), 256, 0, stream>>>(
      R2, R3, cow, cob, bpo, bno, outO, flags, loss, outL);
}